// Round 11
// baseline (28458.203 us; speedup 1.0000x reference)
//
#include <hip/hip_runtime.h>

typedef unsigned int u32;
typedef unsigned short u16;
typedef __attribute__((ext_vector_type(8))) short short8;
typedef __attribute__((ext_vector_type(4))) float f4;

#define MFMA16 __builtin_amdgcn_mfma_f32_16x16x32_bf16
#define ALOAD(p)    __hip_atomic_load((p), __ATOMIC_RELAXED, __HIP_MEMORY_SCOPE_AGENT)
#define ASTORE(p,v) __hip_atomic_store((p), (v), __ATOMIC_RELAXED, __HIP_MEMORY_SCOPE_AGENT)

// ---------- workspace layout (bytes) ----------
#define OFF_XB    0LL            // x bf16 (67,108,864)
#define OFF_XD2   67108864LL     // x[::2] bf16 (33,554,432)
#define OFF_XD4   100663296LL    // x[::4] bf16 (16,777,216)
#define OFF_HCAT  117440512LL    // concat bf16 (234,881,024) producers ASTORE, d0ln reads
#define OFF_LNB   352321536LL    // ln0 out bf16 (33,554,432) d0ln -> b0
#define OFF_H0R   385875968LL    // h0 fp32 ring, 512 steps (33,554,432) d0ln -> b1
#define OFF_Y0R   419430400LL    // y0 ring 4 par x 8 g x 16x128 bf16 (131,072) b0 -> b1
#define OFF_HB0   419561472LL    // gru0 h publish 2 par (262,144)
#define OFF_HB1   419823616LL    // gru1 h publish 2 par (131,072)
#define OFF_FLG   419954688LL    // flags (65,536)
#define OFF_D0WF  420020224LL    // folded d0 weight bf16 (229,376)
// flag u32 idx: gru0 g*128+slab*16 | gru1 1024+G*128+slab*16 | gru2 2048+g*16
//               d0f 4096+g*1024+s | y0f 12544+g*16 | b1ack 12800+g*16

__device__ __forceinline__ u16 f2bf(float f) {
  u32 u = __float_as_uint(f);
  return (u16)((u + 0x7fffu + ((u >> 16) & 1u)) >> 16);   // RNE
}
__device__ __forceinline__ float bf2f(u32 b) { return __uint_as_float(b << 16); }
__device__ __forceinline__ float sigm(float x) { return __builtin_amdgcn_rcpf(1.f + __expf(-x)); }
__device__ __forceinline__ float tanh_(float x) { return 1.f - 2.f * __builtin_amdgcn_rcpf(1.f + __expf(2.f * x)); }

__device__ __forceinline__ short8 cvt8(const float* p) {
  short8 r;
#pragma unroll
  for (int j = 0; j < 8; ++j) r[j] = (short)f2bf(p[j]);
  return r;
}

// =====================================================================
// Solo GRU scan (gru2 only; r10-proven). PUB: publish output + flag.
// =====================================================================
template<int KH, int KX, int BT, int CSPAN, int WAVES, int GROUP_WGS, int PUB>
__device__ __forceinline__ void gru_scan(
    const float* __restrict__ wih, const float* __restrict__ whh,
    const float* __restrict__ bih, const float* __restrict__ bhh,
    const u16* __restrict__ xsrc,
    u16* __restrict__ outp, const int outPitch, const int outColBase,
    const int group, const int slab,
    u32* __restrict__ hbA, u32* __restrict__ hbB, u32* __restrict__ flags,
    char* sm)
{
  constexpr int H = KH;
  constexpr int KT = (KH + KX) / 32;
  constexpr int KH32 = KH / 32;
  constexpr int PITCH = (KH + KX) * 2 + 32;
  constexpr int CT_N = CSPAN / 16;
  constexpr int NTILES = (BT / 16) * CT_N;
  constexpr int MAXP = (NTILES + WAVES - 1) / WAVES;
  constexpr int NT = WAVES * 64;
  constexpr int NX = (BT * KX / 2) / NT;
  constexpr bool GH = (GROUP_WGS > 0);

  const int tid = threadIdx.x;
  const int l = tid & 63;
  const int wv = __builtin_amdgcn_readfirstlane(tid >> 6);  // SCALAR wave id
  const int lr = l & 15;
  const int lh = l >> 4;
  const long srow0 = group * BT;

  short8 Br[MAXP][KT], Bz[MAXP][KT], Bn[MAXP][KT];
  float bb0[MAXP], bb1[MAXP], bb2[MAXP], bb3[MAXP];
  float hk[MAXP][4];
#pragma unroll
  for (int p = 0; p < MAXP; ++p) {
    const int tp = wv + WAVES * p;
    const int tpc = (tp < NTILES) ? tp : 0;
    const int ct = tpc % CT_N;
    const int gcol = slab * CSPAN + ct * 16 + lr;
#pragma unroll
    for (int t = 0; t < KT; ++t) {
      const int k = t * 32 + lh * 8;
      if (t < KH32) {
        Br[p][t] = cvt8(whh + (long)(0 * H + gcol) * KH + k);
        Bz[p][t] = cvt8(whh + (long)(1 * H + gcol) * KH + k);
        Bn[p][t] = cvt8(whh + (long)(2 * H + gcol) * KH + k);
      } else {
        const int kx = k - KH;
        Br[p][t] = cvt8(wih + (long)(0 * H + gcol) * KX + kx);
        Bz[p][t] = cvt8(wih + (long)(1 * H + gcol) * KX + kx);
        Bn[p][t] = cvt8(wih + (long)(2 * H + gcol) * KX + kx);
      }
    }
    bb0[p] = bih[0 * H + gcol] + bhh[0 * H + gcol];
    bb1[p] = bih[1 * H + gcol] + bhh[1 * H + gcol];
    bb2[p] = bih[2 * H + gcol];
    bb3[p] = bhh[2 * H + gcol];
    hk[p][0] = hk[p][1] = hk[p][2] = hk[p][3] = 0.f;
  }

  if constexpr (!GH) {
#pragma unroll
    for (int i = 0; i < (BT * KH / 2 + NT - 1) / NT; ++i) {
      const int idx = tid + NT * i;
      if (idx < BT * KH / 2) {
        const int r = idx / (KH / 2), d = idx % (KH / 2);
        *(u32*)(sm + r * PITCH + ((d * 4) ^ ((r & 7) << 4))) = 0u;
      }
    }
  }

  u32 xr[NX];
#pragma unroll
  for (int i = 0; i < NX; ++i) {
    const int idx = tid + NT * i;
    const int r = idx / (KX / 2), d = idx % (KX / 2);
    xr[i] = *(const u32*)(xsrc + (srow0 + r) * KX + d * 2);
  }

  for (int s = 0; s < 1024; ++s) {
#pragma unroll
    for (int i = 0; i < NX; ++i) {
      const int idx = tid + NT * i;
      const int r = idx / (KX / 2), d = idx % (KX / 2);
      *(u32*)(sm + r * PITCH + ((KH * 2 + d * 4) ^ ((r & 7) << 4))) = xr[i];
    }
    __syncthreads();

    u32 hnew[MAXP][4];
#pragma unroll
    for (int p = 0; p < MAXP; ++p) {
      const int tp = wv + WAVES * p;
      if (tp < NTILES) {
        const int mt = tp / CT_N;
        f4 ar = {0.f, 0.f, 0.f, 0.f}; f4 az = ar, anh = ar, anx = ar;
#pragma unroll
        for (int t = 0; t < KT; ++t) {
          const int row = mt * 16 + lr;
          const short8 a = *(const short8*)(sm + row * PITCH +
                              ((t * 64 + lh * 16) ^ ((row & 7) << 4)));
          ar = MFMA16(a, Br[p][t], ar, 0, 0, 0);
          az = MFMA16(a, Bz[p][t], az, 0, 0, 0);
          if (t < KH32) anh = MFMA16(a, Bn[p][t], anh, 0, 0, 0);
          else          anx = MFMA16(a, Bn[p][t], anx, 0, 0, 0);
        }
#pragma unroll
        for (int q = 0; q < 4; ++q) {
          const float rg = sigm(ar[q] + bb0[p]);
          const float zg = sigm(az[q] + bb1[p]);
          const float ng = tanh_(anx[q] + bb2[p] + rg * (anh[q] + bb3[p]));
          const float h = (1.f - zg) * ng + zg * hk[p][q];
          hk[p][q] = h;
          hnew[p][q] = f2bf(h);
        }
      }
    }
    __syncthreads();

#pragma unroll
    for (int p = 0; p < MAXP; ++p) {
      const int tp = wv + WAVES * p;
      if (tp < NTILES) {
        const int mt = tp / CT_N, ct = tp % CT_N;
        const int c = ct * 16 + lr;
#pragma unroll
        for (int q = 0; q < 4; ++q) {
          const u32 nb = (u32)__shfl_xor((int)hnew[p][q], 1);
          if ((l & 1) == 0) {
            const u32 pk = (hnew[p][q] & 0xffffu) | (nb << 16);
            const int b = mt * 16 + lh * 4 + q;
            u32* oa = (u32*)(outp + (s * 128L + srow0 + b) * outPitch + outColBase + c);
            *(u32*)(sm + b * PITCH + ((c * 2) ^ ((b & 7) << 4))) = pk;
            if constexpr (PUB) ASTORE(oa, pk); else *oa = pk;
          }
        }
      }
    }
    if constexpr (PUB) {
      __builtin_amdgcn_sched_barrier(0);
      if (s + 1 < 1024) {
#pragma unroll
        for (int i = 0; i < NX; ++i) {
          const int idx = tid + NT * i;
          const int r = idx / (KX / 2), d = idx % (KX / 2);
          xr[i] = ALOAD((const u32*)(xsrc + ((s + 1) * 128L + srow0 + r) * KX + d * 2));
        }
      }
      asm volatile("s_waitcnt vmcnt(0)" ::: "memory");
      __syncthreads();
      if (tid == 0) ASTORE(flags, (u32)(s + 1));
    } else {
      if (s + 1 < 1024) {
#pragma unroll
        for (int i = 0; i < NX; ++i) {
          const int idx = tid + NT * i;
          const int r = idx / (KX / 2), d = idx % (KX / 2);
          xr[i] = *(const u32*)(xsrc + ((s + 1) * 128L + srow0 + r) * KX + d * 2);
        }
      }
      __syncthreads();
    }
  }
}

// =====================================================================
// gru0 MULTIPLEXED (H=512, Kin=256, gate-split, r10-proven math):
// one WG-set of 8 slabs serves 4 batch groups (set*4 + gi). Sub-steps
// (g0,s)(g1,s)(g2,s)(g3,s)(g0,s+1)... — a group's flag/L3 RTT hides
// under the other 3 groups' sub-steps. h for the NEXT sub-step is
// prefetched into regs right after this sub-step's publish stores, so
// store-ack and load latency overlap inside one syncthreads drain.
// All per-group state statically indexed via unrolled gi (rule #20).
// =====================================================================
__device__ __forceinline__ void gru0m_scan(
    const float* __restrict__ wih, const float* __restrict__ whh,
    const float* __restrict__ bih, const float* __restrict__ bhh,
    const u16* __restrict__ x, u16* __restrict__ outp,
    const int set, const int slab,
    u32* __restrict__ hbuf0, u32* __restrict__ flg, char* sm)
{
  constexpr int PITCH = 1568;
  const int tid = threadIdx.x;
  const int l = tid & 63;
  const int wv = __builtin_amdgcn_readfirstlane(tid >> 6);  // SCALAR
  const int lr = l & 15, lh = l >> 4;
  const int ct = wv & 3, gg = wv >> 2;
  const int gcol = slab * 64 + ct * 16 + lr;
  f4* red = (f4*)(sm + 25088);

  short8 W0[24], W1[16];
#pragma unroll
  for (int t = 0; t < 24; ++t) {
    const int k = t * 32 + lh * 8;
    if (t < 16) W0[t] = cvt8(whh + (long)(gg * 512 + gcol) * 512 + k);
    else        W0[t] = cvt8(wih + (long)(gg * 512 + gcol) * 256 + (k - 512));
  }
  if (gg == 0) {
#pragma unroll
    for (int t = 0; t < 16; ++t)
      W1[t] = cvt8(whh + (long)(2 * 512 + gcol) * 512 + t * 32 + lh * 8);
  } else {
#pragma unroll
    for (int t = 0; t < 8; ++t)
      W1[t] = cvt8(wih + (long)(2 * 512 + gcol) * 256 + t * 32 + lh * 8);
  }
  const float bb0 = bih[0 * 512 + gcol] + bhh[0 * 512 + gcol];
  const float bb1 = bih[1 * 512 + gcol] + bhh[1 * 512 + gcol];
  const float bb2 = bih[2 * 512 + gcol];
  const float bb3 = bhh[2 * 512 + gcol];
  float hk[4][4];
#pragma unroll
  for (int gi = 0; gi < 4; ++gi)
#pragma unroll
    for (int q = 0; q < 4; ++q) hk[gi][q] = 0.f;

  u32 xr4[4][4];
#pragma unroll
  for (int gi = 0; gi < 4; ++gi) {
    const long srow0 = (long)(set * 4 + gi) * 16;
#pragma unroll
    for (int i = 0; i < 4; ++i) {
      const int idx = tid + 512 * i;
      const int r = idx >> 7, d = idx & 127;
      xr4[gi][i] = *(const u32*)(x + (srow0 + r) * 256 + d * 2);
    }
  }
  u32 hreg[8];
  {
    const u32* hb = hbuf0 + (set * 4) * 4096;   // group set*4, s=0, parity A
#pragma unroll
    for (int i = 0; i < 8; ++i) {
      const int idx = tid + 512 * i;
      const int r = idx >> 8, d = idx & 255;
      hreg[i] = ALOAD(hb + r * 256 + d);
    }
  }

  for (int s = 0; s < 1024; ++s) {
#pragma unroll
    for (int gi = 0; gi < 4; ++gi) {
      const int g = set * 4 + gi;
      const long srow0 = (long)g * 16;
      // 1. stage x (regs) + h (hreg, prefetched last sub-step)
#pragma unroll
      for (int i = 0; i < 4; ++i) {
        const int idx = tid + 512 * i;
        const int r = idx >> 7, d = idx & 127;
        *(u32*)(sm + r * PITCH + ((1024 + d * 4) ^ ((r & 7) << 4))) = xr4[gi][i];
      }
#pragma unroll
      for (int i = 0; i < 8; ++i) {
        const int idx = tid + 512 * i;
        const int r = idx >> 8, d = idx & 255;
        *(u32*)(sm + r * PITCH + ((d * 4) ^ ((r & 7) << 4))) = hreg[i];
      }
      // 2. wave0 polls NEXT group's flags (posted ~3 sub-steps ago)
      const int ngi = (gi + 1) & 3;
      const int ns = s + (gi == 3 ? 1 : 0);
      const int ng = set * 4 + ngi;
      if (ns < 1024 && wv == 0) {
        const u32 tgt = (u32)ns;
        const u32* pf = flg + ng * 128;
        for (;;) {
          const u32 f = (l < 8) ? ALOAD(pf + l * 16) : tgt;
          if (__all(f >= tgt)) break;
        }
      }
      __syncthreads();
      // 3. MFMA (gate-split)
      f4 a0 = {0.f, 0.f, 0.f, 0.f}, a1 = a0;
      if (gg == 0) {
#pragma unroll
        for (int t = 0; t < 24; ++t) {
          const short8 a = *(const short8*)(sm + lr * PITCH +
                              ((t * 64 + lh * 16) ^ ((lr & 7) << 4)));
          a0 = MFMA16(a, W0[t], a0, 0, 0, 0);
          if (t < 16) a1 = MFMA16(a, W1[t], a1, 0, 0, 0);
        }
      } else {
#pragma unroll
        for (int t = 0; t < 24; ++t) {
          const short8 a = *(const short8*)(sm + lr * PITCH +
                              ((t * 64 + lh * 16) ^ ((lr & 7) << 4)));
          a0 = MFMA16(a, W0[t], a0, 0, 0, 0);
          if (t >= 16) a1 = MFMA16(a, W1[t - 16], a1, 0, 0, 0);
        }
        red[(ct * 2 + 0) * 64 + l] = a0;        // az
        red[(ct * 2 + 1) * 64 + l] = a1;        // anx
      }
      __syncthreads();
      // 4. gates + publish (gg0)
      if (gg == 0) {
        const f4 paz  = red[(ct * 2 + 0) * 64 + l];
        const f4 panx = red[(ct * 2 + 1) * 64 + l];
        u32 hnew[4];
#pragma unroll
        for (int q = 0; q < 4; ++q) {
          const float rg = sigm(a0[q] + bb0);
          const float zg = sigm(paz[q] + bb1);
          const float ngt = tanh_(panx[q] + bb2 + rg * (a1[q] + bb3));
          const float h = (1.f - zg) * ngt + zg * hk[gi][q];
          hk[gi][q] = h;
          hnew[q] = f2bf(h);
        }
        u32* hbn = hbuf0 + g * 4096 + (((s + 1) & 1) ? 32768 : 0);
#pragma unroll
        for (int q = 0; q < 4; ++q) {
          const u32 nb = (u32)__shfl_xor((int)hnew[q], 1);
          if ((l & 1) == 0) {
            const u32 pk = (hnew[q] & 0xffffu) | (nb << 16);
            const int b = lh * 4 + q;
            const int c = ct * 16 + lr;
            ASTORE(hbn + b * 256 + (slab * 64 + c) / 2, pk);
            ASTORE((u32*)(outp + (s * 128L + srow0 + b) * 896 + slab * 64 + c), pk);
          }
        }
      }
      // 5. prefetch next sub-step's h into regs (overlaps store-ack)
      if (ns < 1024) {
        const u32* hbx = hbuf0 + ng * 4096 + ((ns & 1) ? 32768 : 0);
#pragma unroll
        for (int i = 0; i < 8; ++i) {
          const int idx = tid + 512 * i;
          const int r = idx >> 8, d = idx & 255;
          hreg[i] = ALOAD(hbx + r * 256 + d);
        }
      }
      // 6. prefetch x for (gi, s+1)
      if (s + 1 < 1024) {
#pragma unroll
        for (int i = 0; i < 4; ++i) {
          const int idx = tid + 512 * i;
          const int r = idx >> 7, d = idx & 127;
          xr4[gi][i] = ALOAD((const u32*)(x + ((s + 1) * 128L + srow0 + r) * 256 + d * 2));
        }
      }
      // 7. drain (syncthreads emits vmcnt(0): stores ack'd, loads done)
      __syncthreads();
      if (tid == 0) ASTORE(flg + g * 128 + slab * 16, (u32)(s + 1));
    }
  }
}

// =====================================================================
// gru1 MULTIPLEXED (H=256, Kin=128): one set of 8 slabs serves all 4
// groups (G = gi, batch rows G*32..+31). Active waves wv<4 compute all
// 4 chains for their (mt,ct) tile (r10 template math, MAXP=1).
// =====================================================================
__device__ __forceinline__ void gru1m_scan(
    const float* __restrict__ wih, const float* __restrict__ whh,
    const float* __restrict__ bih, const float* __restrict__ bhh,
    const u16* __restrict__ x, u16* __restrict__ outp,
    const int slab, u32* __restrict__ hbuf1, u32* __restrict__ flg, char* sm)
{
  constexpr int PITCH = 800;
  const int tid = threadIdx.x;
  const int l = tid & 63;
  const int wv = __builtin_amdgcn_readfirstlane(tid >> 6);  // SCALAR
  const int lr = l & 15, lh = l >> 4;
  const int mt = wv >> 1, ctw = wv & 1;
  const int gcol = slab * 32 + ctw * 16 + lr;

  short8 Br[12], Bz[12], Bn[12];
  float bb0 = 0.f, bb1 = 0.f, bb2 = 0.f, bb3 = 0.f;
  if (wv < 4) {
#pragma unroll
    for (int t = 0; t < 12; ++t) {
      const int k = t * 32 + lh * 8;
      if (t < 8) {
        Br[t] = cvt8(whh + (long)(0 * 256 + gcol) * 256 + k);
        Bz[t] = cvt8(whh + (long)(1 * 256 + gcol) * 256 + k);
        Bn[t] = cvt8(whh + (long)(2 * 256 + gcol) * 256 + k);
      } else {
        const int kx = k - 256;
        Br[t] = cvt8(wih + (long)(0 * 256 + gcol) * 128 + kx);
        Bz[t] = cvt8(wih + (long)(1 * 256 + gcol) * 128 + kx);
        Bn[t] = cvt8(wih + (long)(2 * 256 + gcol) * 128 + kx);
      }
    }
    bb0 = bih[gcol] + bhh[gcol];
    bb1 = bih[256 + gcol] + bhh[256 + gcol];
    bb2 = bih[512 + gcol];
    bb3 = bhh[512 + gcol];
  }
  float hk[4][4];
#pragma unroll
  for (int gi = 0; gi < 4; ++gi)
#pragma unroll
    for (int q = 0; q < 4; ++q) hk[gi][q] = 0.f;

  u32 xr4[4][4];
#pragma unroll
  for (int gi = 0; gi < 4; ++gi) {
    const long srow0 = (long)gi * 32;
#pragma unroll
    for (int i = 0; i < 4; ++i) {
      const int idx = tid + 512 * i;
      const int r = idx >> 6, d = idx & 63;
      xr4[gi][i] = *(const u32*)(x + (srow0 + r) * 128 + d * 2);
    }
  }
  u32 hreg[8];
  {
    const u32* hb = hbuf1;                       // group 0, s=0, parity A
#pragma unroll
    for (int i = 0; i < 8; ++i) {
      const int idx = tid + 512 * i;
      const int r = idx >> 7, d = idx & 127;
      hreg[i] = ALOAD(hb + r * 128 + d);
    }
  }

  for (int s = 0; s < 1024; ++s) {
#pragma unroll
    for (int gi = 0; gi < 4; ++gi) {
      const long srow0 = (long)gi * 32;
      // stage x + h
#pragma unroll
      for (int i = 0; i < 4; ++i) {
        const int idx = tid + 512 * i;
        const int r = idx >> 6, d = idx & 63;
        *(u32*)(sm + r * PITCH + ((512 + d * 4) ^ ((r & 7) << 4))) = xr4[gi][i];
      }
#pragma unroll
      for (int i = 0; i < 8; ++i) {
        const int idx = tid + 512 * i;
        const int r = idx >> 7, d = idx & 127;
        *(u32*)(sm + r * PITCH + ((d * 4) ^ ((r & 7) << 4))) = hreg[i];
      }
      const int ngi = (gi + 1) & 3;
      const int ns = s + (gi == 3 ? 1 : 0);
      if (ns < 1024 && wv == 0) {
        const u32 tgt = (u32)ns;
        const u32* pf = flg + 1024 + ngi * 128;
        for (;;) {
          const u32 f = (l < 8) ? ALOAD(pf + l * 16) : tgt;
          if (__all(f >= tgt)) break;
        }
      }
      __syncthreads();
      if (wv < 4) {
        f4 ar = {0.f, 0.f, 0.f, 0.f}; f4 az = ar, anh = ar, anx = ar;
#pragma unroll
        for (int t = 0; t < 12; ++t) {
          const int row = mt * 16 + lr;
          const short8 aa = *(const short8*)(sm + row * PITCH +
                              ((t * 64 + lh * 16) ^ ((row & 7) << 4)));
          ar = MFMA16(aa, Br[t], ar, 0, 0, 0);
          az = MFMA16(aa, Bz[t], az, 0, 0, 0);
          if (t < 8) anh = MFMA16(aa, Bn[t], anh, 0, 0, 0);
          else       anx = MFMA16(aa, Bn[t], anx, 0, 0, 0);
        }
        u32 hnew[4];
#pragma unroll
        for (int q = 0; q < 4; ++q) {
          const float rg = sigm(ar[q] + bb0);
          const float zg = sigm(az[q] + bb1);
          const float ngt = tanh_(anx[q] + bb2 + rg * (anh[q] + bb3));
          const float h = (1.f - zg) * ngt + zg * hk[gi][q];
          hk[gi][q] = h;
          hnew[q] = f2bf(h);
        }
        u32* hbn = hbuf1 + gi * 4096 + (((s + 1) & 1) ? 16384 : 0);
#pragma unroll
        for (int q = 0; q < 4; ++q) {
          const u32 nb = (u32)__shfl_xor((int)hnew[q], 1);
          if ((l & 1) == 0) {
            const u32 pk = (hnew[q] & 0xffffu) | (nb << 16);
            const int b = mt * 16 + lh * 4 + q;
            const int c = ctw * 16 + lr;
            ASTORE(hbn + b * 128 + (slab * 32 + c) / 2, pk);
            ASTORE((u32*)(outp + (s * 128L + srow0 + b) * 896 + 512 + slab * 32 + c), pk);
          }
        }
      }
      if (ns < 1024) {
        const u32* hbx = hbuf1 + ngi * 4096 + ((ns & 1) ? 16384 : 0);
#pragma unroll
        for (int i = 0; i < 8; ++i) {
          const int idx = tid + 512 * i;
          const int r = idx >> 7, d = idx & 127;
          hreg[i] = ALOAD(hbx + r * 128 + d);
        }
      }
      if (s + 1 < 1024) {
#pragma unroll
        for (int i = 0; i < 4; ++i) {
          const int idx = tid + 512 * i;
          const int r = idx >> 6, d = idx & 63;
          xr4[gi][i] = ALOAD((const u32*)(x + ((s + 1) * 128L + srow0 + r) * 128 + d * 2));
        }
      }
      __syncthreads();
      if (tid == 0) ASTORE(flg + 1024 + gi * 128 + slab * 16, (u32)(s + 1));
    }
  }
}

struct MegaArgs {
  const float *w0ih, *w0hh, *b0ih, *b0hh;
  const float *w1ih, *w1hh, *b1ih, *b1hh;
  const float *w2ih, *w2hh, *b2ih, *b2hh;
  const u16 *xb, *xd2, *xd4;
  u16 *hcat, *lnb;
  u32 *h0r, *y0r, *hbuf0, *hbuf1, *flg;
  const u16 *d0wf; const float *d0b;
  const float *ln0g, *ln0b;
  const float *c0wih, *c0whh, *c0bih, *c0bhh;
  const float *ln1g, *ln1b;
  const float *c1wih, *c1whh, *c1bih, *c1bhh;
  const float *dfw, *dfb;
  float* out;
};

// =====================================================================
// d0+LN0 trailing WG (g, p): steps s = p, p+8, ... (r10-proven).
// =====================================================================
__device__ __forceinline__ void d0ln_scan(const MegaArgs& a, const int g,
                                          const int p, char* sm)
{
  const int tid = threadIdx.x;
  const int l = tid & 63;
  const int wv = __builtin_amdgcn_readfirstlane(tid >> 6);
  const int lr = l & 15, lh = l >> 4;
  const int dcol = wv * 16 + lr;
  u16* sA = (u16*)sm;                       // [16][40]
  float* part = (float*)(sm + 1536);        // [16][8][2]
  float* rowstat = (float*)(sm + 3584);     // [16][2]

  short8 Dw[28];
#pragma unroll
  for (int t = 0; t < 28; ++t)
    Dw[t] = *(const short8*)(a.d0wf + (long)dcol * 896 + t * 32 + lh * 8);
  const float dbias = a.d0b[dcol];
  const float lg = a.ln0g[dcol], lb = a.ln0b[dcol];

  const u32* hcat32 = (const u32*)a.hcat;
  u32* lnb32 = (u32*)a.lnb;
  const u32* pollp;
  if (l < 8)        pollp = a.flg + g * 128 + l * 16;
  else if (l < 16)  pollp = a.flg + 1024 + (g >> 1) * 128 + (l - 8) * 16;
  else if (l == 16) pollp = a.flg + 2048 + g * 16;
  else              pollp = a.flg + 12800 + g * 16;   // b1 ack (h0 ring WAR)
  const int stg = (tid < 256);
  const int sr = tid >> 4, sc = tid & 15;

  for (int s = p; s < 1024; s += 8) {
    if (wv == 0) {
      const u32 tgt = (u32)(s + 1);
      for (;;) {
        u32 f = tgt;
        if (l < 17)       f = ALOAD(pollp);
        else if (l == 17) f = ALOAD(pollp) + 512;   // ack >= s-511
        if (__all(f >= tgt)) break;
        __builtin_amdgcn_s_sleep(32);
      }
    }
    __syncthreads();
    const long rowbase = (long)s * 128 + g * 16;
    f4 acc = {0.f, 0.f, 0.f, 0.f};
    u32 vst = 0;
    if (stg) vst = ALOAD(hcat32 + (rowbase + sr) * 448 + sc);
    for (int kt = 0; kt < 28; ++kt) {
      u32 vnext = 0;
      if (kt + 1 < 28 && stg)
        vnext = ALOAD(hcat32 + (rowbase + sr) * 448 + (kt + 1) * 16 + sc);
      __syncthreads();
      if (stg) *(u32*)((char*)sA + sr * 80 + sc * 4) = vst;
      __syncthreads();
      const short8 af = *(const short8*)((char*)sA + lr * 80 + lh * 16);
      acc = MFMA16(af, Dw[kt], acc, 0, 0, 0);
      vst = vnext;
    }
    float v[4];
#pragma unroll
    for (int q = 0; q < 4; ++q) { const float xv = acc[q] + dbias; v[q] = xv > 0.f ? xv : 0.f; }
#pragma unroll
    for (int q = 0; q < 4; ++q) {
      float s1 = v[q], s2 = v[q] * v[q];
#pragma unroll
      for (int o = 1; o < 16; o <<= 1) { s1 += __shfl_xor(s1, o); s2 += __shfl_xor(s2, o); }
      if (lr == 0) {
        const int row = lh * 4 + q;
        part[(row * 8 + wv) * 2] = s1;
        part[(row * 8 + wv) * 2 + 1] = s2;
      }
    }
    __syncthreads();
    if (tid < 16) {
      float S1 = 0.f, S2 = 0.f;
#pragma unroll
      for (int w = 0; w < 8; ++w) { S1 += part[(tid * 8 + w) * 2]; S2 += part[(tid * 8 + w) * 2 + 1]; }
      const float m = S1 * 0.0078125f;
      const float rs = rsqrtf(S2 * 0.0078125f - m * m + 1e-5f);
      rowstat[tid * 2] = m; rowstat[tid * 2 + 1] = rs;
    }
    __syncthreads();
#pragma unroll
    for (int q = 0; q < 4; ++q) {
      const int row = lh * 4 + q;
      const float m = rowstat[row * 2], rs = rowstat[row * 2 + 1];
      const u16 lnq = f2bf((v[q] - m) * rs * lg + lb);
      const u32 nb = (u32)__shfl_xor((int)(u32)lnq, 1);
      if ((l & 1) == 0)
        ASTORE(lnb32 + (rowbase + row) * 64 + (dcol >> 1), ((u32)lnq & 0xffffu) | (nb << 16));
      ASTORE(a.h0r + ((long)(s & 511) * 128 + g * 16 + row) * 128 + dcol,
             __float_as_uint(v[q]));
    }
    asm volatile("s_waitcnt vmcnt(0)" ::: "memory");
    __syncthreads();
    if (tid == 0) ASTORE(a.flg + 4096 + g * 1024 + s, 1u);
  }
}

// ---- b0: trailing serial block-GRU (consumes lnbuf, publishes y0 ring) ----
__device__ __forceinline__ void b0_scan(const MegaArgs& a, const int g, char* sm)
{
  const int tid = threadIdx.x, l = tid & 63;
  const int wv = __builtin_amdgcn_readfirstlane(tid >> 6);
  const int lr = l & 15, lh = l >> 4;
  const int gcol = wv * 16 + lr;
  char* T = sm;
  short8 Br[8], Bz[8], Bn[8];
#pragma unroll
  for (int t = 0; t < 8; ++t) {
    const int k = t * 32 + lh * 8;
    if (t < 4) {
      Br[t] = cvt8(a.c0whh + (long)(0 * 128 + gcol) * 128 + k);
      Bz[t] = cvt8(a.c0whh + (long)(1 * 128 + gcol) * 128 + k);
      Bn[t] = cvt8(a.c0whh + (long)(2 * 128 + gcol) * 128 + k);
    } else {
      const int kx = k - 128;
      Br[t] = cvt8(a.c0wih + (long)(0 * 128 + gcol) * 128 + kx);
      Bz[t] = cvt8(a.c0wih + (long)(1 * 128 + gcol) * 128 + kx);
      Bn[t] = cvt8(a.c0wih + (long)(2 * 128 + gcol) * 128 + kx);
    }
  }
  const float b0v = a.c0bih[gcol] + a.c0bhh[gcol];
  const float b1v = a.c0bih[128 + gcol] + a.c0bhh[128 + gcol];
  const float b2v = a.c0bih[256 + gcol];
  const float b3v = a.c0bhh[256 + gcol];
  float hk[4] = {0.f, 0.f, 0.f, 0.f};
#pragma unroll
  for (int i = 0; i < 2; ++i) {
    const int idx = tid + 512 * i; const int r = idx >> 6, d = idx & 63;
    *(u32*)(T + r * 544 + ((d * 4) ^ ((r & 7) << 4))) = 0u;
  }
  const u32* lnb32 = (const u32*)a.lnb;
  const u32* d0fp = a.flg + 4096 + g * 1024;
  const u32* ackp = a.flg + 12800 + g * 16;
  u32* myf = a.flg + 12544 + g * 16;
  __syncthreads();
  for (int s = 0; s < 1024; ++s) {
    if (wv == 0) {
      for (;;) {
        u32 f = 1u;
        if (l == 0)      f = ALOAD(d0fp + s);
        else if (l == 1) f = (ALOAD(ackp) + 3 >= (u32)s) ? 1u : 0u;  // y0 ring WAR
        if (__all(f >= 1u)) break;
        __builtin_amdgcn_s_sleep(4);
      }
    }
    __syncthreads();
#pragma unroll
    for (int i = 0; i < 2; ++i) {
      const int idx = tid + 512 * i; const int r = idx >> 6, d = idx & 63;
      const u32 xv = ALOAD(lnb32 + ((long)s * 128 + g * 16 + r) * 64 + d);
      *(u32*)(T + r * 544 + ((256 + d * 4) ^ ((r & 7) << 4))) = xv;
    }
    __syncthreads();
    f4 ar = {0.f, 0.f, 0.f, 0.f}; f4 az = ar, anh = ar, anx = ar;
#pragma unroll
    for (int t = 0; t < 8; ++t) {
      const short8 aa = *(const short8*)(T + lr * 544 + ((t * 64 + lh * 16) ^ ((lr & 7) << 4)));
      ar = MFMA16(aa, Br[t], ar, 0, 0, 0);
      az = MFMA16(aa, Bz[t], az, 0, 0, 0);
      if (t < 4) anh = MFMA16(aa, Bn[t], anh, 0, 0, 0);
      else       anx = MFMA16(aa, Bn[t], anx, 0, 0, 0);
    }
    u32 hnew[4];
#pragma unroll
    for (int q = 0; q < 4; ++q) {
      const float rg = sigm(ar[q] + b0v);
      const float zg = sigm(az[q] + b1v);
      const float ng = tanh_(anx[q] + b2v + rg * (anh[q] + b3v));
      const float h = (1.f - zg) * ng + zg * hk[q];
      hk[q] = h; hnew[q] = f2bf(h);
    }
    __syncthreads();
#pragma unroll
    for (int q = 0; q < 4; ++q) {
      const u32 nb = (u32)__shfl_xor((int)hnew[q], 1);
      if ((l & 1) == 0) {
        const u32 pk = (hnew[q] & 0xffffu) | (nb << 16);
        const int b = lh * 4 + q, c = wv * 16 + lr;
        *(u32*)(T + b * 544 + ((c * 2) ^ ((b & 7) << 4))) = pk;
        ASTORE(a.y0r + ((s & 3) * 8 + g) * 1024 + b * 64 + (c >> 1), pk);
      }
    }
    asm volatile("s_waitcnt vmcnt(0)" ::: "memory");
    __syncthreads();
    if (tid == 0) ASTORE(myf, (u32)(s + 1));
  }
}

// ---- b1: LN1(h0+y0) -> GRU -> final dense -> out; acks y0/h0 rings ----
__device__ __forceinline__ void b1_scan(const MegaArgs& a, const int g, char* sm)
{
  const int tid = threadIdx.x, l = tid & 63;
  const int wv = __builtin_amdgcn_readfirstlane(tid >> 6);
  const int lr = l & 15, lh = l >> 4;
  const int gcol = wv * 16 + lr;
  char* T = sm;
  float* SDF = (float*)(sm + 8704);
  float* SDB = (float*)(sm + 10752);
  short8 Br[8], Bz[8], Bn[8];
#pragma unroll
  for (int t = 0; t < 8; ++t) {
    const int k = t * 32 + lh * 8;
    if (t < 4) {
      Br[t] = cvt8(a.c1whh + (long)(0 * 128 + gcol) * 128 + k);
      Bz[t] = cvt8(a.c1whh + (long)(1 * 128 + gcol) * 128 + k);
      Bn[t] = cvt8(a.c1whh + (long)(2 * 128 + gcol) * 128 + k);
    } else {
      const int kx = k - 128;
      Br[t] = cvt8(a.c1wih + (long)(0 * 128 + gcol) * 128 + kx);
      Bz[t] = cvt8(a.c1wih + (long)(1 * 128 + gcol) * 128 + kx);
      Bn[t] = cvt8(a.c1wih + (long)(2 * 128 + gcol) * 128 + kx);
    }
  }
  const float b0v = a.c1bih[gcol] + a.c1bhh[gcol];
  const float b1v = a.c1bih[128 + gcol] + a.c1bhh[128 + gcol];
  const float b2v = a.c1bih[256 + gcol];
  const float b3v = a.c1bhh[256 + gcol];
  float hk[4] = {0.f, 0.f, 0.f, 0.f};
#pragma unroll
  for (int i = 0; i < 2; ++i) {
    const int idx = tid + 512 * i; const int r = idx >> 6, d = idx & 63;
    *(u32*)(T + r * 544 + ((d * 4) ^ ((r & 7) << 4))) = 0u;
  }
  SDF[tid] = a.dfw[tid];
  if (tid < 4) SDB[tid] = a.dfb[tid];
  const int rr = tid >> 5, cq = tid & 31, c4 = cq * 4;
  const float g1a = a.ln1g[c4], g1b = a.ln1g[c4 + 1], g1c = a.ln1g[c4 + 2], g1d = a.ln1g[c4 + 3];
  const float h1a = a.ln1b[c4], h1b = a.ln1b[c4 + 1], h1c = a.ln1b[c4 + 2], h1d = a.ln1b[c4 + 3];
  const u32* y0fp = a.flg + 12544 + g * 16;
  u32* ackp = a.flg + 12800 + g * 16;
  __syncthreads();
  for (int s = 0; s < 1024; ++s) {
    if (wv == 0) {
      const u32 tgt = (u32)(s + 1);
      for (;;) {
        const u32 f = (l == 0) ? ALOAD(y0fp) : tgt;
        if (__all(f >= tgt)) break;
        __builtin_amdgcn_s_sleep(4);
      }
    }
    __syncthreads();
    const u32 ya = ALOAD(a.y0r + ((s & 3) * 8 + g) * 1024 + rr * 64 + cq * 2);
    const u32 yb = ALOAD(a.y0r + ((s & 3) * 8 + g) * 1024 + rr * 64 + cq * 2 + 1);
    const long hbase = ((long)(s & 511) * 128 + g * 16 + rr) * 128 + c4;
    const float p0 = __uint_as_float(ALOAD(a.h0r + hbase));
    const float p1 = __uint_as_float(ALOAD(a.h0r + hbase + 1));
    const float p2 = __uint_as_float(ALOAD(a.h0r + hbase + 2));
    const float p3 = __uint_as_float(ALOAD(a.h0r + hbase + 3));
    const float u0 = p0 + bf2f(ya & 0xffffu);
    const float u1 = p1 + bf2f(ya >> 16);
    const float u2 = p2 + bf2f(yb & 0xffffu);
    const float u3 = p3 + bf2f(yb >> 16);
    float s1 = u0 + u1 + u2 + u3;
    float s2 = u0 * u0 + u1 * u1 + u2 * u2 + u3 * u3;
#pragma unroll
    for (int o = 1; o < 32; o <<= 1) { s1 += __shfl_xor(s1, o); s2 += __shfl_xor(s2, o); }
    const float m = s1 * 0.0078125f;
    const float rs = rsqrtf(s2 * 0.0078125f - m * m + 1e-5f);
    const u32 q0 = (u32)f2bf((u0 - m) * rs * g1a + h1a) |
                   ((u32)f2bf((u1 - m) * rs * g1b + h1b) << 16);
    const u32 q1 = (u32)f2bf((u2 - m) * rs * g1c + h1c) |
                   ((u32)f2bf((u3 - m) * rs * g1d + h1d) << 16);
    char* xa = T + rr * 544 + ((256 + cq * 8) ^ ((rr & 7) << 4));
    *(u32*)xa = q0;
    *(u32*)(xa + 4) = q1;
    __syncthreads();
    if (tid == 0) ASTORE(ackp, (u32)(s + 1));   // y0 + h0[s] consumed
    f4 ar = {0.f, 0.f, 0.f, 0.f}; f4 az = ar, anh = ar, anx = ar;
#pragma unroll
    for (int t = 0; t < 8; ++t) {
      const short8 aa = *(const short8*)(T + lr * 544 + ((t * 64 + lh * 16) ^ ((lr & 7) << 4)));
      ar = MFMA16(aa, Br[t], ar, 0, 0, 0);
      az = MFMA16(aa, Bz[t], az, 0, 0, 0);
      if (t < 4) anh = MFMA16(aa, Bn[t], anh, 0, 0, 0);
      else       anx = MFMA16(aa, Bn[t], anx, 0, 0, 0);
    }
    u32 hnew[4];
#pragma unroll
    for (int q = 0; q < 4; ++q) {
      const float rg = sigm(ar[q] + b0v);
      const float zg = sigm(az[q] + b1v);
      const float ng = tanh_(anx[q] + b2v + rg * (anh[q] + b3v));
      const float h = (1.f - zg) * ng + zg * hk[q];
      hk[q] = h; hnew[q] = f2bf(h);
    }
    __syncthreads();
#pragma unroll
    for (int q = 0; q < 4; ++q) {
      const u32 nb = (u32)__shfl_xor((int)hnew[q], 1);
      if ((l & 1) == 0) {
        const u32 pk = (hnew[q] & 0xffffu) | (nb << 16);
        const int b = lh * 4 + q, c = wv * 16 + lr;
        *(u32*)(T + b * 544 + ((c * 2) ^ ((b & 7) << 4))) = pk;
      }
    }
    __syncthreads();
    const int yo = (c4 * 2) ^ ((rr & 7) << 4);
    const u32 za = *(const u32*)(T + rr * 544 + yo);
    const u32 zb = *(const u32*)(T + rr * 544 + yo + 4);
    const float w0 = u0 + bf2f(za & 0xffffu);
    const float w1 = u1 + bf2f(za >> 16);
    const float w2 = u2 + bf2f(zb & 0xffffu);
    const float w3 = u3 + bf2f(zb >> 16);
    float pp0 = w0 * SDF[c4]       + w1 * SDF[c4 + 1]       + w2 * SDF[c4 + 2]       + w3 * SDF[c4 + 3];
    float pp1 = w0 * SDF[128 + c4] + w1 * SDF[128 + c4 + 1] + w2 * SDF[128 + c4 + 2] + w3 * SDF[128 + c4 + 3];
    float pp2 = w0 * SDF[256 + c4] + w1 * SDF[256 + c4 + 1] + w2 * SDF[256 + c4 + 2] + w3 * SDF[256 + c4 + 3];
    float pp3 = w0 * SDF[384 + c4] + w1 * SDF[384 + c4 + 1] + w2 * SDF[384 + c4 + 2] + w3 * SDF[384 + c4 + 3];
#pragma unroll
    for (int o = 1; o < 32; o <<= 1) {
      pp0 += __shfl_xor(pp0, o); pp1 += __shfl_xor(pp1, o);
      pp2 += __shfl_xor(pp2, o); pp3 += __shfl_xor(pp3, o);
    }
    if (cq == 0) {
      f4 ov = {pp0 + SDB[0], pp1 + SDB[1], pp2 + SDB[2], pp3 + SDB[3]};
      *(f4*)(a.out + ((long)s * 128 + g * 16 + rr) * 4) = ov;
    }
  }
}

// bids: 0-15 gru0m (set=bid&1, slab=bid>>1) | 16-23 gru1m | 24-31 gru2 |
//       32-95 d0ln | 96-103 b0 | 104-111 b1
__global__ void __launch_bounds__(512, 2) mega(MegaArgs a) {
  __shared__ __align__(16) char sm[33280];
  const int bid = blockIdx.x;
  if (bid < 16) {
    gru0m_scan(a.w0ih, a.w0hh, a.b0ih, a.b0hh, a.xb, a.hcat,
               bid & 1, bid >> 1, a.hbuf0, a.flg, sm);
  } else if (bid < 24) {
    gru1m_scan(a.w1ih, a.w1hh, a.b1ih, a.b1hh, a.xd2, a.hcat,
               bid - 16, a.hbuf1, a.flg, sm);
  } else if (bid < 32) {
    const int g = bid - 24;
    gru_scan<128, 64, 16, 128, 8, 0, 1>(a.w2ih, a.w2hh, a.b2ih, a.b2hh, a.xd4,
        a.hcat, 896, 768, g, 0, nullptr, nullptr,
        a.flg + 2048 + g * 16, sm);
  } else if (bid < 96) {
    const int id = bid - 32;
    d0ln_scan(a, id & 7, id >> 3, sm);
  } else if (bid < 104) {
    b0_scan(a, bid - 96, sm);
  } else {
    b1_scan(a, bid - 104, sm);
  }
}

// x -> bf16 full / ::2 / ::4 copies, plus upsample-folded d0 weight
__global__ void __launch_bounds__(256) prep(const float* __restrict__ x,
    u16* __restrict__ xb, u16* __restrict__ xd2, u16* __restrict__ xd4,
    const float* __restrict__ d0w, u16* __restrict__ d0wf) {
  const int b = blockIdx.x;
  if (b < 16384) {
    const long t = b * 256L + threadIdx.x;
    const f4 aa = ((const f4*)x)[t * 2];
    const f4 cc = ((const f4*)x)[t * 2 + 1];
    const u16 u0 = f2bf(aa[0]), u1 = f2bf(aa[1]), u2 = f2bf(aa[2]), u3 = f2bf(aa[3]);
    const u16 u4 = f2bf(cc[0]), u5 = f2bf(cc[1]), u6 = f2bf(cc[2]), u7 = f2bf(cc[3]);
    short8 s8; s8[0]=(short)u0; s8[1]=(short)u1; s8[2]=(short)u2; s8[3]=(short)u3;
    s8[4]=(short)u4; s8[5]=(short)u5; s8[6]=(short)u6; s8[7]=(short)u7;
    *(short8*)(xb + t * 8) = s8;
    const long row = t >> 5; const int ch = (int)(t & 31);
    *(u32*)(xd2 + row * 128 + ch * 4)     = (u32)u0 | ((u32)u2 << 16);
    *(u32*)(xd2 + row * 128 + ch * 4 + 2) = (u32)u4 | ((u32)u6 << 16);
    *(u32*)(xd4 + row * 64 + ch * 2)      = (u32)u0 | ((u32)u4 << 16);
  } else {
    const int idx = (b - 16384) * 256 + threadIdx.x;
    const int o = idx / 896, c = idx % 896;
    float v;
    if (c < 512) v = d0w[o * 1536 + c];
    else if (c < 768) { const int j = c - 512; v = d0w[o * 1536 + 512 + 2 * j] + d0w[o * 1536 + 513 + 2 * j]; }
    else { const int j = c - 768; const float* p = d0w + o * 1536 + 1024 + 4 * j; v = p[0] + p[1] + p[2] + p[3]; }
    d0wf[idx] = f2bf(v);
  }
}

extern "C" void kernel_launch(void* const* d_in, const int* in_sizes, int n_in,
                              void* d_out, int out_size, void* d_ws, size_t ws_size,
                              hipStream_t stream) {
  char* ws = (char*)d_ws;
  const float* x     = (const float*)d_in[0];
  const float* g0wih = (const float*)d_in[1];
  const float* g0whh = (const float*)d_in[2];
  const float* g0bih = (const float*)d_in[3];
  const float* g0bhh = (const float*)d_in[4];
  const float* g1wih = (const float*)d_in[5];
  const float* g1whh = (const float*)d_in[6];
  const float* g1bih = (const float*)d_in[7];
  const float* g1bhh = (const float*)d_in[8];
  const float* g2wih = (const float*)d_in[9];
  const float* g2whh = (const float*)d_in[10];
  const float* g2bih = (const float*)d_in[11];
  const float* g2bhh = (const float*)d_in[12];
  const float* d0w   = (const float*)d_in[13];
  const float* d0b   = (const float*)d_in[14];
  const float* ln0g  = (const float*)d_in[15];
  const float* ln0b  = (const float*)d_in[16];
  const float* b0wih = (const float*)d_in[17];
  const float* b0whh = (const float*)d_in[18];
  const float* b0bih = (const float*)d_in[19];
  const float* b0bhh = (const float*)d_in[20];
  const float* ln1g  = (const float*)d_in[21];
  const float* ln1b  = (const float*)d_in[22];
  const float* b1wih = (const float*)d_in[23];
  const float* b1whh = (const float*)d_in[24];
  const float* b1bih = (const float*)d_in[25];
  const float* b1bhh = (const float*)d_in[26];
  const float* dfw   = (const float*)d_in[27];
  const float* dfb   = (const float*)d_in[28];

  MegaArgs a;
  a.w0ih = g0wih; a.w0hh = g0whh; a.b0ih = g0bih; a.b0hh = g0bhh;
  a.w1ih = g1wih; a.w1hh = g1whh; a.b1ih = g1bih; a.b1hh = g1bhh;
  a.w2ih = g2wih; a.w2hh = g2whh; a.b2ih = g2bih; a.b2hh = g2bhh;
  a.xb  = (u16*)(ws + OFF_XB);
  a.xd2 = (u16*)(ws + OFF_XD2);
  a.xd4 = (u16*)(ws + OFF_XD4);
  a.hcat = (u16*)(ws + OFF_HCAT);
  a.lnb  = (u16*)(ws + OFF_LNB);
  a.h0r  = (u32*)(ws + OFF_H0R);
  a.y0r  = (u32*)(ws + OFF_Y0R);
  a.hbuf0 = (u32*)(ws + OFF_HB0);
  a.hbuf1 = (u32*)(ws + OFF_HB1);
  a.flg   = (u32*)(ws + OFF_FLG);
  a.d0wf  = (u16*)(ws + OFF_D0WF);
  a.d0b = d0b; a.ln0g = ln0g; a.ln0b = ln0b;
  a.c0wih = b0wih; a.c0whh = b0whh; a.c0bih = b0bih; a.c0bhh = b0bhh;
  a.ln1g = ln1g; a.ln1b = ln1b;
  a.c1wih = b1wih; a.c1whh = b1whh; a.c1bih = b1bih; a.c1bhh = b1bhh;
  a.dfw = dfw; a.dfb = dfb;
  a.out = (float*)d_out;

  // zero h publish parities + all flags/acks
  hipMemsetAsync(ws + OFF_HB0, 0, (size_t)(OFF_D0WF - OFF_HB0), stream);

  prep<<<16832, 256, 0, stream>>>(x, (u16*)(ws + OFF_XB), (u16*)(ws + OFF_XD2),
                                  (u16*)(ws + OFF_XD4), d0w, (u16*)(ws + OFF_D0WF));

  mega<<<112, 512, 0, stream>>>(a);
}

// Round 12
// 4952.112 us; speedup vs baseline: 5.7467x; 5.7467x over previous
//
#include <hip/hip_runtime.h>

typedef unsigned int u32;
typedef unsigned short u16;
typedef __attribute__((ext_vector_type(8))) short short8;
typedef __attribute__((ext_vector_type(4))) float f4;

#define MFMA16 __builtin_amdgcn_mfma_f32_16x16x32_bf16
#define ALOAD(p)    __hip_atomic_load((p), __ATOMIC_RELAXED, __HIP_MEMORY_SCOPE_AGENT)
#define ASTORE(p,v) __hip_atomic_store((p), (v), __ATOMIC_RELAXED, __HIP_MEMORY_SCOPE_AGENT)

// ---------- workspace layout (bytes) ----------
#define OFF_XB    0LL            // x bf16 (67,108,864)
#define OFF_XD2   67108864LL     // x[::2] bf16 (33,554,432)
#define OFF_XD4   100663296LL    // x[::4] bf16 (16,777,216)
#define OFF_HCAT  117440512LL    // concat bf16 (234,881,024) producers ASTORE, d0ln reads
#define OFF_LNB   352321536LL    // ln0 out bf16 (33,554,432) d0ln -> b0
#define OFF_H0R   385875968LL    // h0 fp32 ring, 512 steps (33,554,432) d0ln -> b1
#define OFF_Y0R   419430400LL    // y0 ring 4 par x 8 g x 16x128 bf16 (131,072) b0 -> b1
#define OFF_HB0   419561472LL    // gru0 h publish 2 par (262,144)
#define OFF_HB1   419823616LL    // gru1 h publish 2 par (131,072)
#define OFF_FLG   419954688LL    // flags (65,536)
#define OFF_D0WF  420020224LL    // folded d0 weight bf16 (229,376)
// flag u32 idx: gru0 g*128+slab*16 | gru1 1024+G*128+slab*16 | gru2 2048+g*16
//               d0f 4096+g*1024+s | y0f 12544+g*16 | b1ack 12800+g*16

__device__ __forceinline__ u16 f2bf(float f) {
  u32 u = __float_as_uint(f);
  return (u16)((u + 0x7fffu + ((u >> 16) & 1u)) >> 16);   // RNE
}
__device__ __forceinline__ float bf2f(u32 b) { return __uint_as_float(b << 16); }
__device__ __forceinline__ float sigm(float x) { return __builtin_amdgcn_rcpf(1.f + __expf(-x)); }
__device__ __forceinline__ float tanh_(float x) { return 1.f - 2.f * __builtin_amdgcn_rcpf(1.f + __expf(2.f * x)); }

__device__ __forceinline__ short8 cvt8(const float* p) {
  short8 r;
#pragma unroll
  for (int j = 0; j < 8; ++j) r[j] = (short)f2bf(p[j]);
  return r;
}

// =====================================================================
// Generic fused GRU scan. Wave-role branches SCALARIZED (MFMA ignores
// EXEC). GH: column-split group, 2-parity peer publish + flag handshake.
// PUB: solo WG publishing its output. Handshake drain is PRECISE:
//   [publish ASTOREs] sched_barrier [x-prefetch ALOADs] sched_barrier
//   s_waitcnt vmcnt(NX)            // in-order retire: stores ack'd
//   __builtin_amdgcn_s_barrier()   // RAW barrier — no vmcnt(0) re-drain
// (r11 lesson: __syncthreads emits vmcnt(0) and would pull the HBM
// prefetch back onto the producer chain.)
// =====================================================================
template<int KH, int KX, int BT, int CSPAN, int WAVES, int GROUP_WGS, int PUB>
__device__ __forceinline__ void gru_scan(
    const float* __restrict__ wih, const float* __restrict__ whh,
    const float* __restrict__ bih, const float* __restrict__ bhh,
    const u16* __restrict__ xsrc,
    u16* __restrict__ outp, const int outPitch, const int outColBase,
    const int group, const int slab,
    u32* __restrict__ hbA, u32* __restrict__ hbB, u32* __restrict__ flags,
    char* sm)
{
  constexpr int H = KH;
  constexpr int KT = (KH + KX) / 32;
  constexpr int KH32 = KH / 32;
  constexpr int PITCH = (KH + KX) * 2 + 32;
  constexpr int CT_N = CSPAN / 16;
  constexpr int NTILES = (BT / 16) * CT_N;
  constexpr int MAXP = (NTILES + WAVES - 1) / WAVES;
  constexpr int NT = WAVES * 64;
  constexpr int NX = (BT * KX / 2) / NT;
  constexpr int NH = (BT * KH / 2) / NT;
  constexpr bool GH = (GROUP_WGS > 0);

  const int tid = threadIdx.x;
  const int l = tid & 63;
  const int wv = __builtin_amdgcn_readfirstlane(tid >> 6);  // SCALAR wave id
  const int lr = l & 15;
  const int lh = l >> 4;
  const long srow0 = group * BT;

  short8 Br[MAXP][KT], Bz[MAXP][KT], Bn[MAXP][KT];
  float bb0[MAXP], bb1[MAXP], bb2[MAXP], bb3[MAXP];
  float hk[MAXP][4];
#pragma unroll
  for (int p = 0; p < MAXP; ++p) {
    const int tp = wv + WAVES * p;
    const int tpc = (tp < NTILES) ? tp : 0;
    const int ct = tpc % CT_N;
    const int gcol = slab * CSPAN + ct * 16 + lr;
#pragma unroll
    for (int t = 0; t < KT; ++t) {
      const int k = t * 32 + lh * 8;
      if (t < KH32) {
        Br[p][t] = cvt8(whh + (long)(0 * H + gcol) * KH + k);
        Bz[p][t] = cvt8(whh + (long)(1 * H + gcol) * KH + k);
        Bn[p][t] = cvt8(whh + (long)(2 * H + gcol) * KH + k);
      } else {
        const int kx = k - KH;
        Br[p][t] = cvt8(wih + (long)(0 * H + gcol) * KX + kx);
        Bz[p][t] = cvt8(wih + (long)(1 * H + gcol) * KX + kx);
        Bn[p][t] = cvt8(wih + (long)(2 * H + gcol) * KX + kx);
      }
    }
    bb0[p] = bih[0 * H + gcol] + bhh[0 * H + gcol];
    bb1[p] = bih[1 * H + gcol] + bhh[1 * H + gcol];
    bb2[p] = bih[2 * H + gcol];
    bb3[p] = bhh[2 * H + gcol];
    hk[p][0] = hk[p][1] = hk[p][2] = hk[p][3] = 0.f;
  }

  if constexpr (!GH) {
#pragma unroll
    for (int i = 0; i < (BT * KH / 2 + NT - 1) / NT; ++i) {
      const int idx = tid + NT * i;
      if (idx < BT * KH / 2) {
        const int r = idx / (KH / 2), d = idx % (KH / 2);
        *(u32*)(sm + r * PITCH + ((d * 4) ^ ((r & 7) << 4))) = 0u;
      }
    }
  }

  u32 xr[NX];
#pragma unroll
  for (int i = 0; i < NX; ++i) {
    const int idx = tid + NT * i;
    const int r = idx / (KX / 2), d = idx % (KX / 2);
    xr[i] = *(const u32*)(xsrc + (srow0 + r) * KX + d * 2);
  }

  for (int s = 0; s < 1024; ++s) {
    if constexpr (GH) {
      if (wv == 0) {
        const u32 tgt = (u32)s;
        for (;;) {
          const u32 f = (l < GROUP_WGS) ? ALOAD(flags + l * 16) : tgt;
          if (__all(f >= tgt)) break;
        }
      }
      __syncthreads();
    }
#pragma unroll
    for (int i = 0; i < NX; ++i) {
      const int idx = tid + NT * i;
      const int r = idx / (KX / 2), d = idx % (KX / 2);
      *(u32*)(sm + r * PITCH + ((KH * 2 + d * 4) ^ ((r & 7) << 4))) = xr[i];
    }
    if constexpr (GH) {
      const u32* hb = (s & 1) ? hbB : hbA;
#pragma unroll
      for (int i = 0; i < NH; ++i) {
        const int idx = tid + NT * i;
        const int r = idx / (KH / 2), d = idx % (KH / 2);
        const u32 v = ALOAD(hb + r * (KH / 2) + d);
        *(u32*)(sm + r * PITCH + ((d * 4) ^ ((r & 7) << 4))) = v;
      }
    }
    // (x prefetch for s+1 issued in the handshake, post-publish)
    if constexpr (!(GH || PUB)) {
      if (s + 1 < 1024) {
#pragma unroll
        for (int i = 0; i < NX; ++i) {
          const int idx = tid + NT * i;
          const int r = idx / (KX / 2), d = idx % (KX / 2);
          xr[i] = *(const u32*)(xsrc + ((s + 1) * 128L + srow0 + r) * KX + d * 2);
        }
      }
    }
    __syncthreads();

    u32 hnew[MAXP][4];
#pragma unroll
    for (int p = 0; p < MAXP; ++p) {
      const int tp = wv + WAVES * p;
      if (tp < NTILES) {
        const int mt = tp / CT_N;
        f4 ar = {0.f, 0.f, 0.f, 0.f}; f4 az = ar, anh = ar, anx = ar;
#pragma unroll
        for (int t = 0; t < KT; ++t) {
          const int row = mt * 16 + lr;
          const short8 a = *(const short8*)(sm + row * PITCH +
                              ((t * 64 + lh * 16) ^ ((row & 7) << 4)));
          ar = MFMA16(a, Br[p][t], ar, 0, 0, 0);
          az = MFMA16(a, Bz[p][t], az, 0, 0, 0);
          if (t < KH32) anh = MFMA16(a, Bn[p][t], anh, 0, 0, 0);
          else          anx = MFMA16(a, Bn[p][t], anx, 0, 0, 0);
        }
#pragma unroll
        for (int q = 0; q < 4; ++q) {
          const float rg = sigm(ar[q] + bb0[p]);
          const float zg = sigm(az[q] + bb1[p]);
          const float ng = tanh_(anx[q] + bb2[p] + rg * (anh[q] + bb3[p]));
          const float h = (1.f - zg) * ng + zg * hk[p][q];
          hk[p][q] = h;
          hnew[p][q] = f2bf(h);
        }
      }
    }
    if constexpr (!GH) __syncthreads();

#pragma unroll
    for (int p = 0; p < MAXP; ++p) {
      const int tp = wv + WAVES * p;
      if (tp < NTILES) {
        const int mt = tp / CT_N, ct = tp % CT_N;
        const int c = ct * 16 + lr;
#pragma unroll
        for (int q = 0; q < 4; ++q) {
          const u32 nb = (u32)__shfl_xor((int)hnew[p][q], 1);
          if ((l & 1) == 0) {
            const u32 pk = (hnew[p][q] & 0xffffu) | (nb << 16);
            const int b = mt * 16 + lh * 4 + q;
            u32* oa = (u32*)(outp + (s * 128L + srow0 + b) * outPitch + outColBase + c);
            if constexpr (GH) {
              u32* hbn = ((s + 1) & 1) ? hbB : hbA;
              ASTORE(hbn + b * (KH / 2) + (slab * CSPAN + c) / 2, pk);
              ASTORE(oa, pk);
            } else {
              *(u32*)(sm + b * PITCH + ((c * 2) ^ ((b & 7) << 4))) = pk;
              if constexpr (PUB) ASTORE(oa, pk); else *oa = pk;
            }
          }
        }
      }
    }
    if constexpr (GH || PUB) {
      // precise drain: stores first, then prefetch loads, wait vmcnt(NX),
      // RAW s_barrier (no vmcnt(0) re-drain), then flag.
      __builtin_amdgcn_sched_barrier(0);
      if (s + 1 < 1024) {
#pragma unroll
        for (int i = 0; i < NX; ++i) {
          const int idx = tid + NT * i;
          const int r = idx / (KX / 2), d = idx % (KX / 2);
          xr[i] = ALOAD((const u32*)(xsrc + ((s + 1) * 128L + srow0 + r) * KX + d * 2));
        }
        __builtin_amdgcn_sched_barrier(0);
        asm volatile("s_waitcnt vmcnt(%0)" :: "i"(NX) : "memory");
      } else {
        asm volatile("s_waitcnt vmcnt(0)" ::: "memory");
      }
      __builtin_amdgcn_s_barrier();
      if (tid == 0) ASTORE(flags + (GH ? slab * 16 : 0), (u32)(s + 1));
    }
  }
}

// =====================================================================
// gru0 (H=512, Kin=256): GATE-SPLIT scan (r5/r7-proven) + precise drain
// with raw s_barrier (r12 fix).
// =====================================================================
__device__ __forceinline__ void gru0_scan(
    const float* __restrict__ wih, const float* __restrict__ whh,
    const float* __restrict__ bih, const float* __restrict__ bhh,
    const u16* __restrict__ x, u16* __restrict__ outp,
    const int group, const int slab,
    u32* __restrict__ hbA, u32* __restrict__ hbB, u32* __restrict__ flags,
    char* sm)
{
  constexpr int PITCH = 1568;
  const int tid = threadIdx.x;
  const int l = tid & 63;
  const int wv = __builtin_amdgcn_readfirstlane(tid >> 6);
  const int lr = l & 15, lh = l >> 4;
  const int ct = wv & 3, gg = wv >> 2;
  const long srow0 = group * 16;
  const int gcol = slab * 64 + ct * 16 + lr;
  f4* red = (f4*)(sm + 25088);

  short8 W0[24], W1[16];
#pragma unroll
  for (int t = 0; t < 24; ++t) {
    const int k = t * 32 + lh * 8;
    if (t < 16) W0[t] = cvt8(whh + (long)(gg * 512 + gcol) * 512 + k);
    else        W0[t] = cvt8(wih + (long)(gg * 512 + gcol) * 256 + (k - 512));
  }
  if (gg == 0) {
#pragma unroll
    for (int t = 0; t < 16; ++t)
      W1[t] = cvt8(whh + (long)(2 * 512 + gcol) * 512 + t * 32 + lh * 8);
  } else {
#pragma unroll
    for (int t = 0; t < 8; ++t)
      W1[t] = cvt8(wih + (long)(2 * 512 + gcol) * 256 + t * 32 + lh * 8);
  }
  const float bb0 = bih[0 * 512 + gcol] + bhh[0 * 512 + gcol];
  const float bb1 = bih[1 * 512 + gcol] + bhh[1 * 512 + gcol];
  const float bb2 = bih[2 * 512 + gcol];
  const float bb3 = bhh[2 * 512 + gcol];
  float hk[4] = {0.f, 0.f, 0.f, 0.f};

  u32 xr[4];
#pragma unroll
  for (int i = 0; i < 4; ++i) {
    const int idx = tid + 512 * i;
    const int r = idx >> 7, d = idx & 127;
    xr[i] = *(const u32*)(x + (srow0 + r) * 256 + d * 2);
  }

  for (int s = 0; s < 1024; ++s) {
    if (wv == 0) {
      const u32 tgt = (u32)s;
      for (;;) {
        const u32 f = (l < 8) ? ALOAD(flags + l * 16) : tgt;
        if (__all(f >= tgt)) break;
      }
    }
    __syncthreads();
#pragma unroll
    for (int i = 0; i < 4; ++i) {
      const int idx = tid + 512 * i;
      const int r = idx >> 7, d = idx & 127;
      *(u32*)(sm + r * PITCH + ((1024 + d * 4) ^ ((r & 7) << 4))) = xr[i];
    }
    {
      const u32* hb = (s & 1) ? hbB : hbA;
#pragma unroll
      for (int i = 0; i < 8; ++i) {
        const int idx = tid + 512 * i;
        const int r = idx >> 8, d = idx & 255;
        const u32 v = ALOAD(hb + r * 256 + d);
        *(u32*)(sm + r * PITCH + ((d * 4) ^ ((r & 7) << 4))) = v;
      }
    }
    __syncthreads();

    f4 a0 = {0.f, 0.f, 0.f, 0.f}, a1 = a0;
    if (gg == 0) {
#pragma unroll
      for (int t = 0; t < 24; ++t) {
        const short8 a = *(const short8*)(sm + lr * PITCH +
                            ((t * 64 + lh * 16) ^ ((lr & 7) << 4)));
        a0 = MFMA16(a, W0[t], a0, 0, 0, 0);
        if (t < 16) a1 = MFMA16(a, W1[t], a1, 0, 0, 0);
      }
    } else {
#pragma unroll
      for (int t = 0; t < 24; ++t) {
        const short8 a = *(const short8*)(sm + lr * PITCH +
                            ((t * 64 + lh * 16) ^ ((lr & 7) << 4)));
        a0 = MFMA16(a, W0[t], a0, 0, 0, 0);
        if (t >= 16) a1 = MFMA16(a, W1[t - 16], a1, 0, 0, 0);
      }
      red[(ct * 2 + 0) * 64 + l] = a0;
      red[(ct * 2 + 1) * 64 + l] = a1;
    }
    __syncthreads();
    if (gg == 0) {
      const f4 paz  = red[(ct * 2 + 0) * 64 + l];
      const f4 panx = red[(ct * 2 + 1) * 64 + l];
      u32 hnew[4];
#pragma unroll
      for (int q = 0; q < 4; ++q) {
        const float rg = sigm(a0[q] + bb0);
        const float zg = sigm(paz[q] + bb1);
        const float ng = tanh_(panx[q] + bb2 + rg * (a1[q] + bb3));
        const float h = (1.f - zg) * ng + zg * hk[q];
        hk[q] = h;
        hnew[q] = f2bf(h);
      }
      u32* hbn = ((s + 1) & 1) ? hbB : hbA;
#pragma unroll
      for (int q = 0; q < 4; ++q) {
        const u32 nb = (u32)__shfl_xor((int)hnew[q], 1);
        if ((l & 1) == 0) {
          const u32 pk = (hnew[q] & 0xffffu) | (nb << 16);
          const int b = lh * 4 + q;
          const int c = ct * 16 + lr;
          ASTORE(hbn + b * 256 + (slab * 64 + c) / 2, pk);
          ASTORE((u32*)(outp + (s * 128L + srow0 + b) * 896 + slab * 64 + c), pk);
        }
      }
    }
    // precise drain: stores issued above; prefetch after; vmcnt(4);
    // RAW s_barrier (no vmcnt(0) re-drain); then flag.
    __builtin_amdgcn_sched_barrier(0);
    if (s + 1 < 1024) {
#pragma unroll
      for (int i = 0; i < 4; ++i) {
        const int idx = tid + 512 * i;
        const int r = idx >> 7, d = idx & 127;
        xr[i] = ALOAD((const u32*)(x + ((s + 1) * 128L + srow0 + r) * 256 + d * 2));
      }
      __builtin_amdgcn_sched_barrier(0);
      asm volatile("s_waitcnt vmcnt(4)" ::: "memory");
    } else {
      asm volatile("s_waitcnt vmcnt(0)" ::: "memory");
    }
    __builtin_amdgcn_s_barrier();
    if (tid == 0) ASTORE(flags + slab * 16, (u32)(s + 1));
  }
}

struct MegaArgs {
  const float *w0ih, *w0hh, *b0ih, *b0hh;
  const float *w1ih, *w1hh, *b1ih, *b1hh;
  const float *w2ih, *w2hh, *b2ih, *b2hh;
  const u16 *xb, *xd2, *xd4;
  u16 *hcat, *lnb;
  u32 *h0r, *y0r, *hbuf0, *hbuf1, *flg;
  const u16 *d0wf; const float *d0b;
  const float *ln0g, *ln0b;
  const float *c0wih, *c0whh, *c0bih, *c0bhh;
  const float *ln1g, *ln1b;
  const float *c1wih, *c1whh, *c1bih, *c1bhh;
  const float *dfw, *dfb;
  float* out;
};

// =====================================================================
// d0+LN0 trailing WG (g, p): steps s = p, p+8, ... 8-way step-parallel,
// 36 us/step budget; s_sleep poll backoff (r10-proven).
// =====================================================================
__device__ __forceinline__ void d0ln_scan(const MegaArgs& a, const int g,
                                          const int p, char* sm)
{
  const int tid = threadIdx.x;
  const int l = tid & 63;
  const int wv = __builtin_amdgcn_readfirstlane(tid >> 6);
  const int lr = l & 15, lh = l >> 4;
  const int dcol = wv * 16 + lr;
  u16* sA = (u16*)sm;                       // [16][40]
  float* part = (float*)(sm + 1536);        // [16][8][2]
  float* rowstat = (float*)(sm + 3584);     // [16][2]

  short8 Dw[28];
#pragma unroll
  for (int t = 0; t < 28; ++t)
    Dw[t] = *(const short8*)(a.d0wf + (long)dcol * 896 + t * 32 + lh * 8);
  const float dbias = a.d0b[dcol];
  const float lg = a.ln0g[dcol], lb = a.ln0b[dcol];

  const u32* hcat32 = (const u32*)a.hcat;
  u32* lnb32 = (u32*)a.lnb;
  const u32* pollp;
  if (l < 8)        pollp = a.flg + g * 128 + l * 16;
  else if (l < 16)  pollp = a.flg + 1024 + (g >> 1) * 128 + (l - 8) * 16;
  else if (l == 16) pollp = a.flg + 2048 + g * 16;
  else              pollp = a.flg + 12800 + g * 16;   // b1 ack (h0 ring WAR)
  const int stg = (tid < 256);
  const int sr = tid >> 4, sc = tid & 15;

  for (int s = p; s < 1024; s += 8) {
    if (wv == 0) {
      const u32 tgt = (u32)(s + 1);
      for (;;) {
        u32 f = tgt;
        if (l < 17)       f = ALOAD(pollp);
        else if (l == 17) f = ALOAD(pollp) + 512;   // ack >= s-511
        if (__all(f >= tgt)) break;
        __builtin_amdgcn_s_sleep(32);
      }
    }
    __syncthreads();
    const long rowbase = (long)s * 128 + g * 16;
    f4 acc = {0.f, 0.f, 0.f, 0.f};
    u32 vst = 0;
    if (stg) vst = ALOAD(hcat32 + (rowbase + sr) * 448 + sc);
    for (int kt = 0; kt < 28; ++kt) {
      u32 vnext = 0;
      if (kt + 1 < 28 && stg)
        vnext = ALOAD(hcat32 + (rowbase + sr) * 448 + (kt + 1) * 16 + sc);
      __syncthreads();
      if (stg) *(u32*)((char*)sA + sr * 80 + sc * 4) = vst;
      __syncthreads();
      const short8 af = *(const short8*)((char*)sA + lr * 80 + lh * 16);
      acc = MFMA16(af, Dw[kt], acc, 0, 0, 0);
      vst = vnext;
    }
    float v[4];
#pragma unroll
    for (int q = 0; q < 4; ++q) { const float xv = acc[q] + dbias; v[q] = xv > 0.f ? xv : 0.f; }
#pragma unroll
    for (int q = 0; q < 4; ++q) {
      float s1 = v[q], s2 = v[q] * v[q];
#pragma unroll
      for (int o = 1; o < 16; o <<= 1) { s1 += __shfl_xor(s1, o); s2 += __shfl_xor(s2, o); }
      if (lr == 0) {
        const int row = lh * 4 + q;
        part[(row * 8 + wv) * 2] = s1;
        part[(row * 8 + wv) * 2 + 1] = s2;
      }
    }
    __syncthreads();
    if (tid < 16) {
      float S1 = 0.f, S2 = 0.f;
#pragma unroll
      for (int w = 0; w < 8; ++w) { S1 += part[(tid * 8 + w) * 2]; S2 += part[(tid * 8 + w) * 2 + 1]; }
      const float m = S1 * 0.0078125f;
      const float rs = rsqrtf(S2 * 0.0078125f - m * m + 1e-5f);
      rowstat[tid * 2] = m; rowstat[tid * 2 + 1] = rs;
    }
    __syncthreads();
#pragma unroll
    for (int q = 0; q < 4; ++q) {
      const int row = lh * 4 + q;
      const float m = rowstat[row * 2], rs = rowstat[row * 2 + 1];
      const u16 lnq = f2bf((v[q] - m) * rs * lg + lb);
      const u32 nb = (u32)__shfl_xor((int)(u32)lnq, 1);
      if ((l & 1) == 0)
        ASTORE(lnb32 + (rowbase + row) * 64 + (dcol >> 1), ((u32)lnq & 0xffffu) | (nb << 16));
      ASTORE(a.h0r + ((long)(s & 511) * 128 + g * 16 + row) * 128 + dcol,
             __float_as_uint(v[q]));
    }
    asm volatile("s_waitcnt vmcnt(0)" ::: "memory");
    __syncthreads();
    if (tid == 0) ASTORE(a.flg + 4096 + g * 1024 + s, 1u);
  }
}

// ---- b0: trailing serial block-GRU (consumes lnbuf, publishes y0 ring) ----
__device__ __forceinline__ void b0_scan(const MegaArgs& a, const int g, char* sm)
{
  const int tid = threadIdx.x, l = tid & 63;
  const int wv = __builtin_amdgcn_readfirstlane(tid >> 6);
  const int lr = l & 15, lh = l >> 4;
  const int gcol = wv * 16 + lr;
  char* T = sm;
  short8 Br[8], Bz[8], Bn[8];
#pragma unroll
  for (int t = 0; t < 8; ++t) {
    const int k = t * 32 + lh * 8;
    if (t < 4) {
      Br[t] = cvt8(a.c0whh + (long)(0 * 128 + gcol) * 128 + k);
      Bz[t] = cvt8(a.c0whh + (long)(1 * 128 + gcol) * 128 + k);
      Bn[t] = cvt8(a.c0whh + (long)(2 * 128 + gcol) * 128 + k);
    } else {
      const int kx = k - 128;
      Br[t] = cvt8(a.c0wih + (long)(0 * 128 + gcol) * 128 + kx);
      Bz[t] = cvt8(a.c0wih + (long)(1 * 128 + gcol) * 128 + kx);
      Bn[t] = cvt8(a.c0wih + (long)(2 * 128 + gcol) * 128 + kx);
    }
  }
  const float b0v = a.c0bih[gcol] + a.c0bhh[gcol];
  const float b1v = a.c0bih[128 + gcol] + a.c0bhh[128 + gcol];
  const float b2v = a.c0bih[256 + gcol];
  const float b3v = a.c0bhh[256 + gcol];
  float hk[4] = {0.f, 0.f, 0.f, 0.f};
#pragma unroll
  for (int i = 0; i < 2; ++i) {
    const int idx = tid + 512 * i; const int r = idx >> 6, d = idx & 63;
    *(u32*)(T + r * 544 + ((d * 4) ^ ((r & 7) << 4))) = 0u;
  }
  const u32* lnb32 = (const u32*)a.lnb;
  const u32* d0fp = a.flg + 4096 + g * 1024;
  const u32* ackp = a.flg + 12800 + g * 16;
  u32* myf = a.flg + 12544 + g * 16;
  __syncthreads();
  for (int s = 0; s < 1024; ++s) {
    if (wv == 0) {
      for (;;) {
        u32 f = 1u;
        if (l == 0)      f = ALOAD(d0fp + s);
        else if (l == 1) f = (ALOAD(ackp) + 3 >= (u32)s) ? 1u : 0u;  // y0 ring WAR
        if (__all(f >= 1u)) break;
        __builtin_amdgcn_s_sleep(4);
      }
    }
    __syncthreads();
#pragma unroll
    for (int i = 0; i < 2; ++i) {
      const int idx = tid + 512 * i; const int r = idx >> 6, d = idx & 63;
      const u32 xv = ALOAD(lnb32 + ((long)s * 128 + g * 16 + r) * 64 + d);
      *(u32*)(T + r * 544 + ((256 + d * 4) ^ ((r & 7) << 4))) = xv;
    }
    __syncthreads();
    f4 ar = {0.f, 0.f, 0.f, 0.f}; f4 az = ar, anh = ar, anx = ar;
#pragma unroll
    for (int t = 0; t < 8; ++t) {
      const short8 aa = *(const short8*)(T + lr * 544 + ((t * 64 + lh * 16) ^ ((lr & 7) << 4)));
      ar = MFMA16(aa, Br[t], ar, 0, 0, 0);
      az = MFMA16(aa, Bz[t], az, 0, 0, 0);
      if (t < 4) anh = MFMA16(aa, Bn[t], anh, 0, 0, 0);
      else       anx = MFMA16(aa, Bn[t], anx, 0, 0, 0);
    }
    u32 hnew[4];
#pragma unroll
    for (int q = 0; q < 4; ++q) {
      const float rg = sigm(ar[q] + b0v);
      const float zg = sigm(az[q] + b1v);
      const float ng = tanh_(anx[q] + b2v + rg * (anh[q] + b3v));
      const float h = (1.f - zg) * ng + zg * hk[q];
      hk[q] = h; hnew[q] = f2bf(h);
    }
    __syncthreads();
#pragma unroll
    for (int q = 0; q < 4; ++q) {
      const u32 nb = (u32)__shfl_xor((int)hnew[q], 1);
      if ((l & 1) == 0) {
        const u32 pk = (hnew[q] & 0xffffu) | (nb << 16);
        const int b = lh * 4 + q, c = wv * 16 + lr;
        *(u32*)(T + b * 544 + ((c * 2) ^ ((b & 7) << 4))) = pk;
        ASTORE(a.y0r + ((s & 3) * 8 + g) * 1024 + b * 64 + (c >> 1), pk);
      }
    }
    asm volatile("s_waitcnt vmcnt(0)" ::: "memory");
    __syncthreads();
    if (tid == 0) ASTORE(myf, (u32)(s + 1));
  }
}

// ---- b1: LN1(h0+y0) -> GRU -> final dense -> out; acks y0/h0 rings ----
__device__ __forceinline__ void b1_scan(const MegaArgs& a, const int g, char* sm)
{
  const int tid = threadIdx.x, l = tid & 63;
  const int wv = __builtin_amdgcn_readfirstlane(tid >> 6);
  const int lr = l & 15, lh = l >> 4;
  const int gcol = wv * 16 + lr;
  char* T = sm;
  float* SDF = (float*)(sm + 8704);
  float* SDB = (float*)(sm + 10752);
  short8 Br[8], Bz[8], Bn[8];
#pragma unroll
  for (int t = 0; t < 8; ++t) {
    const int k = t * 32 + lh * 8;
    if (t < 4) {
      Br[t] = cvt8(a.c1whh + (long)(0 * 128 + gcol) * 128 + k);
      Bz[t] = cvt8(a.c1whh + (long)(1 * 128 + gcol) * 128 + k);
      Bn[t] = cvt8(a.c1whh + (long)(2 * 128 + gcol) * 128 + k);
    } else {
      const int kx = k - 128;
      Br[t] = cvt8(a.c1wih + (long)(0 * 128 + gcol) * 128 + kx);
      Bz[t] = cvt8(a.c1wih + (long)(1 * 128 + gcol) * 128 + kx);
      Bn[t] = cvt8(a.c1wih + (long)(2 * 128 + gcol) * 128 + kx);
    }
  }
  const float b0v = a.c1bih[gcol] + a.c1bhh[gcol];
  const float b1v = a.c1bih[128 + gcol] + a.c1bhh[128 + gcol];
  const float b2v = a.c1bih[256 + gcol];
  const float b3v = a.c1bhh[256 + gcol];
  float hk[4] = {0.f, 0.f, 0.f, 0.f};
#pragma unroll
  for (int i = 0; i < 2; ++i) {
    const int idx = tid + 512 * i; const int r = idx >> 6, d = idx & 63;
    *(u32*)(T + r * 544 + ((d * 4) ^ ((r & 7) << 4))) = 0u;
  }
  SDF[tid] = a.dfw[tid];
  if (tid < 4) SDB[tid] = a.dfb[tid];
  const int rr = tid >> 5, cq = tid & 31, c4 = cq * 4;
  const float g1a = a.ln1g[c4], g1b = a.ln1g[c4 + 1], g1c = a.ln1g[c4 + 2], g1d = a.ln1g[c4 + 3];
  const float h1a = a.ln1b[c4], h1b = a.ln1b[c4 + 1], h1c = a.ln1b[c4 + 2], h1d = a.ln1b[c4 + 3];
  const u32* y0fp = a.flg + 12544 + g * 16;
  u32* ackp = a.flg + 12800 + g * 16;
  __syncthreads();
  for (int s = 0; s < 1024; ++s) {
    if (wv == 0) {
      const u32 tgt = (u32)(s + 1);
      for (;;) {
        const u32 f = (l == 0) ? ALOAD(y0fp) : tgt;
        if (__all(f >= tgt)) break;
        __builtin_amdgcn_s_sleep(4);
      }
    }
    __syncthreads();
    const u32 ya = ALOAD(a.y0r + ((s & 3) * 8 + g) * 1024 + rr * 64 + cq * 2);
    const u32 yb = ALOAD(a.y0r + ((s & 3) * 8 + g) * 1024 + rr * 64 + cq * 2 + 1);
    const long hbase = ((long)(s & 511) * 128 + g * 16 + rr) * 128 + c4;
    const float p0 = __uint_as_float(ALOAD(a.h0r + hbase));
    const float p1 = __uint_as_float(ALOAD(a.h0r + hbase + 1));
    const float p2 = __uint_as_float(ALOAD(a.h0r + hbase + 2));
    const float p3 = __uint_as_float(ALOAD(a.h0r + hbase + 3));
    const float u0 = p0 + bf2f(ya & 0xffffu);
    const float u1 = p1 + bf2f(ya >> 16);
    const float u2 = p2 + bf2f(yb & 0xffffu);
    const float u3 = p3 + bf2f(yb >> 16);
    float s1 = u0 + u1 + u2 + u3;
    float s2 = u0 * u0 + u1 * u1 + u2 * u2 + u3 * u3;
#pragma unroll
    for (int o = 1; o < 32; o <<= 1) { s1 += __shfl_xor(s1, o); s2 += __shfl_xor(s2, o); }
    const float m = s1 * 0.0078125f;
    const float rs = rsqrtf(s2 * 0.0078125f - m * m + 1e-5f);
    const u32 q0 = (u32)f2bf((u0 - m) * rs * g1a + h1a) |
                   ((u32)f2bf((u1 - m) * rs * g1b + h1b) << 16);
    const u32 q1 = (u32)f2bf((u2 - m) * rs * g1c + h1c) |
                   ((u32)f2bf((u3 - m) * rs * g1d + h1d) << 16);
    char* xa = T + rr * 544 + ((256 + cq * 8) ^ ((rr & 7) << 4));
    *(u32*)xa = q0;
    *(u32*)(xa + 4) = q1;
    __syncthreads();
    if (tid == 0) ASTORE(ackp, (u32)(s + 1));   // y0 + h0[s] consumed
    f4 ar = {0.f, 0.f, 0.f, 0.f}; f4 az = ar, anh = ar, anx = ar;
#pragma unroll
    for (int t = 0; t < 8; ++t) {
      const short8 aa = *(const short8*)(T + lr * 544 + ((t * 64 + lh * 16) ^ ((lr & 7) << 4)));
      ar = MFMA16(aa, Br[t], ar, 0, 0, 0);
      az = MFMA16(aa, Bz[t], az, 0, 0, 0);
      if (t < 4) anh = MFMA16(aa, Bn[t], anh, 0, 0, 0);
      else       anx = MFMA16(aa, Bn[t], anx, 0, 0, 0);
    }
    u32 hnew[4];
#pragma unroll
    for (int q = 0; q < 4; ++q) {
      const float rg = sigm(ar[q] + b0v);
      const float zg = sigm(az[q] + b1v);
      const float ng = tanh_(anx[q] + b2v + rg * (anh[q] + b3v));
      const float h = (1.f - zg) * ng + zg * hk[q];
      hk[q] = h; hnew[q] = f2bf(h);
    }
    __syncthreads();
#pragma unroll
    for (int q = 0; q < 4; ++q) {
      const u32 nb = (u32)__shfl_xor((int)hnew[q], 1);
      if ((l & 1) == 0) {
        const u32 pk = (hnew[q] & 0xffffu) | (nb << 16);
        const int b = lh * 4 + q, c = wv * 16 + lr;
        *(u32*)(T + b * 544 + ((c * 2) ^ ((b & 7) << 4))) = pk;
      }
    }
    __syncthreads();
    const int yo = (c4 * 2) ^ ((rr & 7) << 4);
    const u32 za = *(const u32*)(T + rr * 544 + yo);
    const u32 zb = *(const u32*)(T + rr * 544 + yo + 4);
    const float w0 = u0 + bf2f(za & 0xffffu);
    const float w1 = u1 + bf2f(za >> 16);
    const float w2 = u2 + bf2f(zb & 0xffffu);
    const float w3 = u3 + bf2f(zb >> 16);
    float pp0 = w0 * SDF[c4]       + w1 * SDF[c4 + 1]       + w2 * SDF[c4 + 2]       + w3 * SDF[c4 + 3];
    float pp1 = w0 * SDF[128 + c4] + w1 * SDF[128 + c4 + 1] + w2 * SDF[128 + c4 + 2] + w3 * SDF[128 + c4 + 3];
    float pp2 = w0 * SDF[256 + c4] + w1 * SDF[256 + c4 + 1] + w2 * SDF[256 + c4 + 2] + w3 * SDF[256 + c4 + 3];
    float pp3 = w0 * SDF[384 + c4] + w1 * SDF[384 + c4 + 1] + w2 * SDF[384 + c4 + 2] + w3 * SDF[384 + c4 + 3];
#pragma unroll
    for (int o = 1; o < 32; o <<= 1) {
      pp0 += __shfl_xor(pp0, o); pp1 += __shfl_xor(pp1, o);
      pp2 += __shfl_xor(pp2, o); pp3 += __shfl_xor(pp3, o);
    }
    if (cq == 0) {
      f4 ov = {pp0 + SDB[0], pp1 + SDB[1], pp2 + SDB[2], pp3 + SDB[3]};
      *(f4*)(a.out + ((long)s * 128 + g * 16 + rr) * 4) = ov;
    }
  }
}

// bids: 0-63 gru0 | 64-95 gru1 | 96-103 gru2 | 104-167 d0ln | 168-175 b0 | 176-183 b1
__global__ void __launch_bounds__(512, 2) mega(MegaArgs a) {
  __shared__ __align__(16) char sm[33280];
  const int bid = blockIdx.x;
  if (bid < 64) {
    const int group = bid & 7, slab = bid >> 3;
    gru0_scan(a.w0ih, a.w0hh, a.b0ih, a.b0hh, a.xb, a.hcat, group, slab,
              a.hbuf0 + group * 4096, a.hbuf0 + 32768 + group * 4096,
              a.flg + group * 128, sm);
  } else if (bid < 96) {
    const int id = bid - 64, G = id & 3, slab = id >> 2;
    gru_scan<256, 128, 32, 32, 8, 8, 0>(a.w1ih, a.w1hh, a.b1ih, a.b1hh, a.xd2,
        a.hcat, 896, 512 + slab * 32, G, slab,
        a.hbuf1 + G * 4096, a.hbuf1 + 16384 + G * 4096,
        a.flg + 1024 + G * 128, sm);
  } else if (bid < 104) {
    const int g = bid - 96;
    gru_scan<128, 64, 16, 128, 8, 0, 1>(a.w2ih, a.w2hh, a.b2ih, a.b2hh, a.xd4,
        a.hcat, 896, 768, g, 0, nullptr, nullptr,
        a.flg + 2048 + g * 16, sm);
  } else if (bid < 168) {
    const int id = bid - 104;
    d0ln_scan(a, id & 7, id >> 3, sm);
  } else if (bid < 176) {
    b0_scan(a, bid - 168, sm);
  } else {
    b1_scan(a, bid - 176, sm);
  }
}

// x -> bf16 full / ::2 / ::4 copies, plus upsample-folded d0 weight
__global__ void __launch_bounds__(256) prep(const float* __restrict__ x,
    u16* __restrict__ xb, u16* __restrict__ xd2, u16* __restrict__ xd4,
    const float* __restrict__ d0w, u16* __restrict__ d0wf) {
  const int b = blockIdx.x;
  if (b < 16384) {
    const long t = b * 256L + threadIdx.x;
    const f4 aa = ((const f4*)x)[t * 2];
    const f4 cc = ((const f4*)x)[t * 2 + 1];
    const u16 u0 = f2bf(aa[0]), u1 = f2bf(aa[1]), u2 = f2bf(aa[2]), u3 = f2bf(aa[3]);
    const u16 u4 = f2bf(cc[0]), u5 = f2bf(cc[1]), u6 = f2bf(cc[2]), u7 = f2bf(cc[3]);
    short8 s8; s8[0]=(short)u0; s8[1]=(short)u1; s8[2]=(short)u2; s8[3]=(short)u3;
    s8[4]=(short)u4; s8[5]=(short)u5; s8[6]=(short)u6; s8[7]=(short)u7;
    *(short8*)(xb + t * 8) = s8;
    const long row = t >> 5; const int ch = (int)(t & 31);
    *(u32*)(xd2 + row * 128 + ch * 4)     = (u32)u0 | ((u32)u2 << 16);
    *(u32*)(xd2 + row * 128 + ch * 4 + 2) = (u32)u4 | ((u32)u6 << 16);
    *(u32*)(xd4 + row * 64 + ch * 2)      = (u32)u0 | ((u32)u4 << 16);
  } else {
    const int idx = (b - 16384) * 256 + threadIdx.x;
    const int o = idx / 896, c = idx % 896;
    float v;
    if (c < 512) v = d0w[o * 1536 + c];
    else if (c < 768) { const int j = c - 512; v = d0w[o * 1536 + 512 + 2 * j] + d0w[o * 1536 + 513 + 2 * j]; }
    else { const int j = c - 768; const float* p = d0w + o * 1536 + 1024 + 4 * j; v = p[0] + p[1] + p[2] + p[3]; }
    d0wf[idx] = f2bf(v);
  }
}

extern "C" void kernel_launch(void* const* d_in, const int* in_sizes, int n_in,
                              void* d_out, int out_size, void* d_ws, size_t ws_size,
                              hipStream_t stream) {
  char* ws = (char*)d_ws;
  const float* x     = (const float*)d_in[0];
  const float* g0wih = (const float*)d_in[1];
  const float* g0whh = (const float*)d_in[2];
  const float* g0bih = (const float*)d_in[3];
  const float* g0bhh = (const float*)d_in[4];
  const float* g1wih = (const float*)d_in[5];
  const float* g1whh = (const float*)d_in[6];
  const float* g1bih = (const float*)d_in[7];
  const float* g1bhh = (const float*)d_in[8];
  const float* g2wih = (const float*)d_in[9];
  const float* g2whh = (const float*)d_in[10];
  const float* g2bih = (const float*)d_in[11];
  const float* g2bhh = (const float*)d_in[12];
  const float* d0w   = (const float*)d_in[13];
  const float* d0b   = (const float*)d_in[14];
  const float* ln0g  = (const float*)d_in[15];
  const float* ln0b  = (const float*)d_in[16];
  const float* b0wih = (const float*)d_in[17];
  const float* b0whh = (const float*)d_in[18];
  const float* b0bih = (const float*)d_in[19];
  const float* b0bhh = (const float*)d_in[20];
  const float* ln1g  = (const float*)d_in[21];
  const float* ln1b  = (const float*)d_in[22];
  const float* b1wih = (const float*)d_in[23];
  const float* b1whh = (const float*)d_in[24];
  const float* b1bih = (const float*)d_in[25];
  const float* b1bhh = (const float*)d_in[26];
  const float* dfw   = (const float*)d_in[27];
  const float* dfb   = (const float*)d_in[28];

  MegaArgs a;
  a.w0ih = g0wih; a.w0hh = g0whh; a.b0ih = g0bih; a.b0hh = g0bhh;
  a.w1ih = g1wih; a.w1hh = g1whh; a.b1ih = g1bih; a.b1hh = g1bhh;
  a.w2ih = g2wih; a.w2hh = g2whh; a.b2ih = g2bih; a.b2hh = g2bhh;
  a.xb  = (u16*)(ws + OFF_XB);
  a.xd2 = (u16*)(ws + OFF_XD2);
  a.xd4 = (u16*)(ws + OFF_XD4);
  a.hcat = (u16*)(ws + OFF_HCAT);
  a.lnb  = (u16*)(ws + OFF_LNB);
  a.h0r  = (u32*)(ws + OFF_H0R);
  a.y0r  = (u32*)(ws + OFF_Y0R);
  a.hbuf0 = (u32*)(ws + OFF_HB0);
  a.hbuf1 = (u32*)(ws + OFF_HB1);
  a.flg   = (u32*)(ws + OFF_FLG);
  a.d0wf  = (u16*)(ws + OFF_D0WF);
  a.d0b = d0b; a.ln0g = ln0g; a.ln0b = ln0b;
  a.c0wih = b0wih; a.c0whh = b0whh; a.c0bih = b0bih; a.c0bhh = b0bhh;
  a.ln1g = ln1g; a.ln1b = ln1b;
  a.c1wih = b1wih; a.c1whh = b1whh; a.c1bih = b1bih; a.c1bhh = b1bhh;
  a.dfw = dfw; a.dfb = dfb;
  a.out = (float*)d_out;

  // zero h publish parities + all flags/acks
  hipMemsetAsync(ws + OFF_HB0, 0, (size_t)(OFF_D0WF - OFF_HB0), stream);

  prep<<<16832, 256, 0, stream>>>(x, (u16*)(ws + OFF_XB), (u16*)(ws + OFF_XD2),
                                  (u16*)(ws + OFF_XD4), d0w, (u16*)(ws + OFF_D0WF));

  mega<<<184, 512, 0, stream>>>(a);
}

// Round 13
// 4567.722 us; speedup vs baseline: 6.2303x; 1.0842x over previous
//
#include <hip/hip_runtime.h>

typedef unsigned int u32;
typedef unsigned short u16;
typedef __attribute__((ext_vector_type(8))) short short8;
typedef __attribute__((ext_vector_type(4))) float f4;

#define MFMA16 __builtin_amdgcn_mfma_f32_16x16x32_bf16
#define ALOAD(p)    __hip_atomic_load((p), __ATOMIC_RELAXED, __HIP_MEMORY_SCOPE_AGENT)
#define ASTORE(p,v) __hip_atomic_store((p), (v), __ATOMIC_RELAXED, __HIP_MEMORY_SCOPE_AGENT)

// ---------- workspace layout (bytes) ----------
#define OFF_XB    0LL            // x bf16 (67,108,864)
#define OFF_XD2   67108864LL     // x[::2] bf16 (33,554,432)
#define OFF_XD4   100663296LL    // x[::4] bf16 (16,777,216)
#define OFF_HCAT  117440512LL    // concat bf16 (234,881,024) producers ASTORE, d0ln reads
#define OFF_LNB   352321536LL    // ln0 out bf16 (33,554,432) d0ln -> b0
#define OFF_H0R   385875968LL    // h0 fp32 ring, 512 steps (33,554,432) d0ln -> b1
#define OFF_Y0R   419430400LL    // y0 ring 4 par x 8 g x 16x128 bf16 (131,072) b0 -> b1
#define OFF_HB0   419561472LL    // gru0 h publish 2 par (262,144)
#define OFF_HB1   419823616LL    // gru1 h publish 2 par (131,072)
#define OFF_FLG   419954688LL    // flags (65,536)
#define OFF_D0WF  420020224LL    // folded d0 weight bf16 (229,376)
// flag u32 idx: gru0 g*128+slab*16 | gru1 1024+G*128+slab*16 | gru2 2048+g*16
//               d0f 4096+g*1024+s | y0f 12544+g*16 | b1ack 12800+g*16
// Visibility contract (r13): producer flag s+1 => h-publish[s] visible.
//   hcat[s] visible only at flag >= s+2 (hcat stores drain lazily; in-order
//   vmcnt retirement forces them retired by the next step's h-stage waits).

__device__ __forceinline__ u16 f2bf(float f) {
  u32 u = __float_as_uint(f);
  return (u16)((u + 0x7fffu + ((u >> 16) & 1u)) >> 16);   // RNE
}
__device__ __forceinline__ float bf2f(u32 b) { return __uint_as_float(b << 16); }
__device__ __forceinline__ float sigm(float x) { return __builtin_amdgcn_rcpf(1.f + __expf(-x)); }
__device__ __forceinline__ float tanh_(float x) { return 1.f - 2.f * __builtin_amdgcn_rcpf(1.f + __expf(2.f * x)); }

__device__ __forceinline__ short8 cvt8(const float* p) {
  short8 r;
#pragma unroll
  for (int j = 0; j < 8; ++j) r[j] = (short)f2bf(p[j]);
  return r;
}

// =====================================================================
// Generic fused GRU scan. Wave-role branches SCALARIZED (MFMA ignores
// EXEC). GH: column-split group, 2-parity peer publish + flag handshake.
// PUB: solo WG publishing its output. r13 drain:
//   [h-publish ASTOREs] sb [hcat ASTOREs] sb [x-prefetch ALOADs] sb
//   s_waitcnt vmcnt(MAXP*4 + NX)   // waits publishes ONLY (in-order)
//   raw s_barrier; flag = s+1.
// hcat[s] retires under the next step (consumers use flag >= s+2).
// =====================================================================
template<int KH, int KX, int BT, int CSPAN, int WAVES, int GROUP_WGS, int PUB>
__device__ __forceinline__ void gru_scan(
    const float* __restrict__ wih, const float* __restrict__ whh,
    const float* __restrict__ bih, const float* __restrict__ bhh,
    const u16* __restrict__ xsrc,
    u16* __restrict__ outp, const int outPitch, const int outColBase,
    const int group, const int slab,
    u32* __restrict__ hbA, u32* __restrict__ hbB, u32* __restrict__ flags,
    char* sm)
{
  constexpr int H = KH;
  constexpr int KT = (KH + KX) / 32;
  constexpr int KH32 = KH / 32;
  constexpr int PITCH = (KH + KX) * 2 + 32;
  constexpr int CT_N = CSPAN / 16;
  constexpr int NTILES = (BT / 16) * CT_N;
  constexpr int MAXP = (NTILES + WAVES - 1) / WAVES;
  constexpr int NT = WAVES * 64;
  constexpr int NX = (BT * KX / 2) / NT;
  constexpr int NH = (BT * KH / 2) / NT;
  constexpr bool GH = (GROUP_WGS > 0);

  const int tid = threadIdx.x;
  const int l = tid & 63;
  const int wv = __builtin_amdgcn_readfirstlane(tid >> 6);  // SCALAR wave id
  const int lr = l & 15;
  const int lh = l >> 4;
  const long srow0 = group * BT;

  short8 Br[MAXP][KT], Bz[MAXP][KT], Bn[MAXP][KT];
  float bb0[MAXP], bb1[MAXP], bb2[MAXP], bb3[MAXP];
  float hk[MAXP][4];
#pragma unroll
  for (int p = 0; p < MAXP; ++p) {
    const int tp = wv + WAVES * p;
    const int tpc = (tp < NTILES) ? tp : 0;
    const int ct = tpc % CT_N;
    const int gcol = slab * CSPAN + ct * 16 + lr;
#pragma unroll
    for (int t = 0; t < KT; ++t) {
      const int k = t * 32 + lh * 8;
      if (t < KH32) {
        Br[p][t] = cvt8(whh + (long)(0 * H + gcol) * KH + k);
        Bz[p][t] = cvt8(whh + (long)(1 * H + gcol) * KH + k);
        Bn[p][t] = cvt8(whh + (long)(2 * H + gcol) * KH + k);
      } else {
        const int kx = k - KH;
        Br[p][t] = cvt8(wih + (long)(0 * H + gcol) * KX + kx);
        Bz[p][t] = cvt8(wih + (long)(1 * H + gcol) * KX + kx);
        Bn[p][t] = cvt8(wih + (long)(2 * H + gcol) * KX + kx);
      }
    }
    bb0[p] = bih[0 * H + gcol] + bhh[0 * H + gcol];
    bb1[p] = bih[1 * H + gcol] + bhh[1 * H + gcol];
    bb2[p] = bih[2 * H + gcol];
    bb3[p] = bhh[2 * H + gcol];
    hk[p][0] = hk[p][1] = hk[p][2] = hk[p][3] = 0.f;
  }

  if constexpr (!GH) {
#pragma unroll
    for (int i = 0; i < (BT * KH / 2 + NT - 1) / NT; ++i) {
      const int idx = tid + NT * i;
      if (idx < BT * KH / 2) {
        const int r = idx / (KH / 2), d = idx % (KH / 2);
        *(u32*)(sm + r * PITCH + ((d * 4) ^ ((r & 7) << 4))) = 0u;
      }
    }
  }

  u32 xr[NX];
#pragma unroll
  for (int i = 0; i < NX; ++i) {
    const int idx = tid + NT * i;
    const int r = idx / (KX / 2), d = idx % (KX / 2);
    xr[i] = *(const u32*)(xsrc + (srow0 + r) * KX + d * 2);
  }

  for (int s = 0; s < 1024; ++s) {
    if constexpr (GH) {
      if (wv == 0) {
        const u32 tgt = (u32)s;
        for (;;) {
          const u32 f = (l < GROUP_WGS) ? ALOAD(flags + l * 16) : tgt;
          if (__all(f >= tgt)) break;
        }
      }
      __builtin_amdgcn_s_barrier();   // raw: nothing to drain here
    }
#pragma unroll
    for (int i = 0; i < NX; ++i) {
      const int idx = tid + NT * i;
      const int r = idx / (KX / 2), d = idx % (KX / 2);
      *(u32*)(sm + r * PITCH + ((KH * 2 + d * 4) ^ ((r & 7) << 4))) = xr[i];
    }
    if constexpr (GH) {
      const u32* hb = (s & 1) ? hbB : hbA;
#pragma unroll
      for (int i = 0; i < NH; ++i) {
        const int idx = tid + NT * i;
        const int r = idx / (KH / 2), d = idx % (KH / 2);
        const u32 v = ALOAD(hb + r * (KH / 2) + d);
        *(u32*)(sm + r * PITCH + ((d * 4) ^ ((r & 7) << 4))) = v;
      }
    }
    // (x prefetch for s+1 issued in the handshake, post-publish)
    if constexpr (!(GH || PUB)) {
      if (s + 1 < 1024) {
#pragma unroll
        for (int i = 0; i < NX; ++i) {
          const int idx = tid + NT * i;
          const int r = idx / (KX / 2), d = idx % (KX / 2);
          xr[i] = *(const u32*)(xsrc + ((s + 1) * 128L + srow0 + r) * KX + d * 2);
        }
      }
    }
    __syncthreads();

    u32 hnew[MAXP][4];
#pragma unroll
    for (int p = 0; p < MAXP; ++p) {
      const int tp = wv + WAVES * p;
      if (tp < NTILES) {
        const int mt = tp / CT_N;
        f4 ar = {0.f, 0.f, 0.f, 0.f}; f4 az = ar, anh = ar, anx = ar;
#pragma unroll
        for (int t = 0; t < KT; ++t) {
          const int row = mt * 16 + lr;
          const short8 a = *(const short8*)(sm + row * PITCH +
                              ((t * 64 + lh * 16) ^ ((row & 7) << 4)));
          ar = MFMA16(a, Br[p][t], ar, 0, 0, 0);
          az = MFMA16(a, Bz[p][t], az, 0, 0, 0);
          if (t < KH32) anh = MFMA16(a, Bn[p][t], anh, 0, 0, 0);
          else          anx = MFMA16(a, Bn[p][t], anx, 0, 0, 0);
        }
#pragma unroll
        for (int q = 0; q < 4; ++q) {
          const float rg = sigm(ar[q] + bb0[p]);
          const float zg = sigm(az[q] + bb1[p]);
          const float ng = tanh_(anx[q] + bb2[p] + rg * (anh[q] + bb3[p]));
          const float h = (1.f - zg) * ng + zg * hk[p][q];
          hk[p][q] = h;
          hnew[p][q] = f2bf(h);
        }
      }
    }
    if constexpr (!GH) __syncthreads();

    // ---- write phase: pack, publish batch first, hcat batch second ----
    u32 pkv[MAXP][4];
#pragma unroll
    for (int p = 0; p < MAXP; ++p) {
      const int tp = wv + WAVES * p;
      if (tp < NTILES) {
        const int mt = tp / CT_N, ct = tp % CT_N;
        const int c = ct * 16 + lr;
#pragma unroll
        for (int q = 0; q < 4; ++q) {
          const u32 nb = (u32)__shfl_xor((int)hnew[p][q], 1);
          pkv[p][q] = (hnew[p][q] & 0xffffu) | (nb << 16);
          if ((l & 1) == 0) {
            const int b = mt * 16 + lh * 4 + q;
            if constexpr (GH) {
              u32* hbn = ((s + 1) & 1) ? hbB : hbA;
              ASTORE(hbn + b * (KH / 2) + (slab * CSPAN + c) / 2, pkv[p][q]);
            } else {
              *(u32*)(sm + b * PITCH + ((c * 2) ^ ((b & 7) << 4))) = pkv[p][q];
            }
          }
        }
      }
    }
    __builtin_amdgcn_sched_barrier(0);
#pragma unroll
    for (int p = 0; p < MAXP; ++p) {
      const int tp = wv + WAVES * p;
      if (tp < NTILES) {
        const int mt = tp / CT_N, ct = tp % CT_N;
        const int c = ct * 16 + lr;
#pragma unroll
        for (int q = 0; q < 4; ++q) {
          if ((l & 1) == 0) {
            const int b = mt * 16 + lh * 4 + q;
            u32* oa = (u32*)(outp + (s * 128L + srow0 + b) * outPitch + outColBase + c);
            if constexpr (GH || PUB) ASTORE(oa, pkv[p][q]); else *oa = pkv[p][q];
          }
        }
      }
    }
    if constexpr (GH) {
      // drain publishes only: leave hcat (MAXP*4) + prefetch (NX) in flight
      __builtin_amdgcn_sched_barrier(0);
      if (s + 1 < 1024) {
#pragma unroll
        for (int i = 0; i < NX; ++i) {
          const int idx = tid + NT * i;
          const int r = idx / (KX / 2), d = idx % (KX / 2);
          xr[i] = ALOAD((const u32*)(xsrc + ((s + 1) * 128L + srow0 + r) * KX + d * 2));
        }
        __builtin_amdgcn_sched_barrier(0);
        asm volatile("s_waitcnt vmcnt(%0)" :: "i"(MAXP * 4 + NX) : "memory");
      } else {
        asm volatile("s_waitcnt vmcnt(0)" ::: "memory");
      }
      __builtin_amdgcn_s_barrier();
      if (tid == 0) ASTORE(flags + slab * 16, (u32)(s + 1));
    } else if constexpr (PUB) {
      // output IS the publish: must be ack'd before flag (vmcnt(NX))
      __builtin_amdgcn_sched_barrier(0);
      if (s + 1 < 1024) {
#pragma unroll
        for (int i = 0; i < NX; ++i) {
          const int idx = tid + NT * i;
          const int r = idx / (KX / 2), d = idx % (KX / 2);
          xr[i] = ALOAD((const u32*)(xsrc + ((s + 1) * 128L + srow0 + r) * KX + d * 2));
        }
        __builtin_amdgcn_sched_barrier(0);
        asm volatile("s_waitcnt vmcnt(%0)" :: "i"(NX) : "memory");
      } else {
        asm volatile("s_waitcnt vmcnt(0)" ::: "memory");
      }
      __builtin_amdgcn_s_barrier();
      if (tid == 0) ASTORE(flags, (u32)(s + 1));
    }
  }
}

// =====================================================================
// gru0 (H=512, Kin=256): GATE-SPLIT scan + r13 drain (publishes first,
// hcat lazily; vmcnt(8) = 4 hcat + 4 prefetch left in flight).
// =====================================================================
__device__ __forceinline__ void gru0_scan(
    const float* __restrict__ wih, const float* __restrict__ whh,
    const float* __restrict__ bih, const float* __restrict__ bhh,
    const u16* __restrict__ x, u16* __restrict__ outp,
    const int group, const int slab,
    u32* __restrict__ hbA, u32* __restrict__ hbB, u32* __restrict__ flags,
    char* sm)
{
  constexpr int PITCH = 1568;
  const int tid = threadIdx.x;
  const int l = tid & 63;
  const int wv = __builtin_amdgcn_readfirstlane(tid >> 6);
  const int lr = l & 15, lh = l >> 4;
  const int ct = wv & 3, gg = wv >> 2;
  const long srow0 = group * 16;
  const int gcol = slab * 64 + ct * 16 + lr;
  f4* red = (f4*)(sm + 25088);

  short8 W0[24], W1[16];
#pragma unroll
  for (int t = 0; t < 24; ++t) {
    const int k = t * 32 + lh * 8;
    if (t < 16) W0[t] = cvt8(whh + (long)(gg * 512 + gcol) * 512 + k);
    else        W0[t] = cvt8(wih + (long)(gg * 512 + gcol) * 256 + (k - 512));
  }
  if (gg == 0) {
#pragma unroll
    for (int t = 0; t < 16; ++t)
      W1[t] = cvt8(whh + (long)(2 * 512 + gcol) * 512 + t * 32 + lh * 8);
  } else {
#pragma unroll
    for (int t = 0; t < 8; ++t)
      W1[t] = cvt8(wih + (long)(2 * 512 + gcol) * 256 + t * 32 + lh * 8);
  }
  const float bb0 = bih[0 * 512 + gcol] + bhh[0 * 512 + gcol];
  const float bb1 = bih[1 * 512 + gcol] + bhh[1 * 512 + gcol];
  const float bb2 = bih[2 * 512 + gcol];
  const float bb3 = bhh[2 * 512 + gcol];
  float hk[4] = {0.f, 0.f, 0.f, 0.f};

  u32 xr[4];
#pragma unroll
  for (int i = 0; i < 4; ++i) {
    const int idx = tid + 512 * i;
    const int r = idx >> 7, d = idx & 127;
    xr[i] = *(const u32*)(x + (srow0 + r) * 256 + d * 2);
  }

  for (int s = 0; s < 1024; ++s) {
    if (wv == 0) {
      const u32 tgt = (u32)s;
      for (;;) {
        const u32 f = (l < 8) ? ALOAD(flags + l * 16) : tgt;
        if (__all(f >= tgt)) break;
      }
    }
    __builtin_amdgcn_s_barrier();   // raw: nothing to drain here
#pragma unroll
    for (int i = 0; i < 4; ++i) {
      const int idx = tid + 512 * i;
      const int r = idx >> 7, d = idx & 127;
      *(u32*)(sm + r * PITCH + ((1024 + d * 4) ^ ((r & 7) << 4))) = xr[i];
    }
    {
      const u32* hb = (s & 1) ? hbB : hbA;
#pragma unroll
      for (int i = 0; i < 8; ++i) {
        const int idx = tid + 512 * i;
        const int r = idx >> 8, d = idx & 255;
        const u32 v = ALOAD(hb + r * 256 + d);
        *(u32*)(sm + r * PITCH + ((d * 4) ^ ((r & 7) << 4))) = v;
      }
    }
    __syncthreads();

    f4 a0 = {0.f, 0.f, 0.f, 0.f}, a1 = a0;
    if (gg == 0) {
#pragma unroll
      for (int t = 0; t < 24; ++t) {
        const short8 a = *(const short8*)(sm + lr * PITCH +
                            ((t * 64 + lh * 16) ^ ((lr & 7) << 4)));
        a0 = MFMA16(a, W0[t], a0, 0, 0, 0);
        if (t < 16) a1 = MFMA16(a, W1[t], a1, 0, 0, 0);
      }
    } else {
#pragma unroll
      for (int t = 0; t < 24; ++t) {
        const short8 a = *(const short8*)(sm + lr * PITCH +
                            ((t * 64 + lh * 16) ^ ((lr & 7) << 4)));
        a0 = MFMA16(a, W0[t], a0, 0, 0, 0);
        if (t >= 16) a1 = MFMA16(a, W1[t - 16], a1, 0, 0, 0);
      }
      red[(ct * 2 + 0) * 64 + l] = a0;
      red[(ct * 2 + 1) * 64 + l] = a1;
    }
    __syncthreads();
    u32 pkv[4];
    if (gg == 0) {
      const f4 paz  = red[(ct * 2 + 0) * 64 + l];
      const f4 panx = red[(ct * 2 + 1) * 64 + l];
      u32 hnew[4];
#pragma unroll
      for (int q = 0; q < 4; ++q) {
        const float rg = sigm(a0[q] + bb0);
        const float zg = sigm(paz[q] + bb1);
        const float ng = tanh_(panx[q] + bb2 + rg * (a1[q] + bb3));
        const float h = (1.f - zg) * ng + zg * hk[q];
        hk[q] = h;
        hnew[q] = f2bf(h);
      }
      u32* hbn = ((s + 1) & 1) ? hbB : hbA;
#pragma unroll
      for (int q = 0; q < 4; ++q) {                       // publish batch
        const u32 nb = (u32)__shfl_xor((int)hnew[q], 1);
        pkv[q] = (hnew[q] & 0xffffu) | (nb << 16);
        if ((l & 1) == 0) {
          const int b = lh * 4 + q;
          const int c = ct * 16 + lr;
          ASTORE(hbn + b * 256 + (slab * 64 + c) / 2, pkv[q]);
        }
      }
      __builtin_amdgcn_sched_barrier(0);
#pragma unroll
      for (int q = 0; q < 4; ++q) {                       // hcat batch (lazy)
        if ((l & 1) == 0) {
          const int b = lh * 4 + q;
          const int c = ct * 16 + lr;
          ASTORE((u32*)(outp + (s * 128L + srow0 + b) * 896 + slab * 64 + c), pkv[q]);
        }
      }
    }
    // drain publishes only: leave 4 hcat + 4 prefetch in flight
    __builtin_amdgcn_sched_barrier(0);
    if (s + 1 < 1024) {
#pragma unroll
      for (int i = 0; i < 4; ++i) {
        const int idx = tid + 512 * i;
        const int r = idx >> 7, d = idx & 127;
        xr[i] = ALOAD((const u32*)(x + ((s + 1) * 128L + srow0 + r) * 256 + d * 2));
      }
      __builtin_amdgcn_sched_barrier(0);
      asm volatile("s_waitcnt vmcnt(8)" ::: "memory");
    } else {
      asm volatile("s_waitcnt vmcnt(0)" ::: "memory");
    }
    __builtin_amdgcn_s_barrier();
    if (tid == 0) ASTORE(flags + slab * 16, (u32)(s + 1));
  }
}

struct MegaArgs {
  const float *w0ih, *w0hh, *b0ih, *b0hh;
  const float *w1ih, *w1hh, *b1ih, *b1hh;
  const float *w2ih, *w2hh, *b2ih, *b2hh;
  const u16 *xb, *xd2, *xd4;
  u16 *hcat, *lnb;
  u32 *h0r, *y0r, *hbuf0, *hbuf1, *flg;
  const u16 *d0wf; const float *d0b;
  const float *ln0g, *ln0b;
  const float *c0wih, *c0whh, *c0bih, *c0bhh;
  const float *ln1g, *ln1b;
  const float *c1wih, *c1whh, *c1bih, *c1bhh;
  const float *dfw, *dfb;
  float* out;
};

// =====================================================================
// d0+LN0 trailing WG (g, p): steps s = p, p+8, ... 8-way step-parallel.
// r13: gru0/gru1 flags polled to s+2 (hcat[s] visibility), gru2 to s+1.
// =====================================================================
__device__ __forceinline__ void d0ln_scan(const MegaArgs& a, const int g,
                                          const int p, char* sm)
{
  const int tid = threadIdx.x;
  const int l = tid & 63;
  const int wv = __builtin_amdgcn_readfirstlane(tid >> 6);
  const int lr = l & 15, lh = l >> 4;
  const int dcol = wv * 16 + lr;
  u16* sA = (u16*)sm;                       // [16][40]
  float* part = (float*)(sm + 1536);        // [16][8][2]
  float* rowstat = (float*)(sm + 3584);     // [16][2]

  short8 Dw[28];
#pragma unroll
  for (int t = 0; t < 28; ++t)
    Dw[t] = *(const short8*)(a.d0wf + (long)dcol * 896 + t * 32 + lh * 8);
  const float dbias = a.d0b[dcol];
  const float lg = a.ln0g[dcol], lb = a.ln0b[dcol];

  const u32* hcat32 = (const u32*)a.hcat;
  u32* lnb32 = (u32*)a.lnb;
  const u32* pollp;
  if (l < 8)        pollp = a.flg + g * 128 + l * 16;
  else if (l < 16)  pollp = a.flg + 1024 + (g >> 1) * 128 + (l - 8) * 16;
  else if (l == 16) pollp = a.flg + 2048 + g * 16;
  else              pollp = a.flg + 12800 + g * 16;   // b1 ack (h0 ring WAR)
  const int stg = (tid < 256);
  const int sr = tid >> 4, sc = tid & 15;

  for (int s = p; s < 1024; s += 8) {
    if (wv == 0) {
      const u32 t01 = (u32)((s + 2 < 1024) ? s + 2 : 1024);  // hcat[s] visible
      const u32 t2  = (u32)(s + 1);
      for (;;) {
        int ok = 1;
        if (l < 16)       ok = (ALOAD(pollp) >= t01);
        else if (l == 16) ok = (ALOAD(pollp) >= t2);
        else if (l == 17) ok = (ALOAD(pollp) + 512 >= t2);   // ack >= s-511
        if (__all(ok)) break;
        __builtin_amdgcn_s_sleep(32);
      }
    }
    __syncthreads();
    const long rowbase = (long)s * 128 + g * 16;
    f4 acc = {0.f, 0.f, 0.f, 0.f};
    u32 vst = 0;
    if (stg) vst = ALOAD(hcat32 + (rowbase + sr) * 448 + sc);
    for (int kt = 0; kt < 28; ++kt) {
      u32 vnext = 0;
      if (kt + 1 < 28 && stg)
        vnext = ALOAD(hcat32 + (rowbase + sr) * 448 + (kt + 1) * 16 + sc);
      __syncthreads();
      if (stg) *(u32*)((char*)sA + sr * 80 + sc * 4) = vst;
      __syncthreads();
      const short8 af = *(const short8*)((char*)sA + lr * 80 + lh * 16);
      acc = MFMA16(af, Dw[kt], acc, 0, 0, 0);
      vst = vnext;
    }
    float v[4];
#pragma unroll
    for (int q = 0; q < 4; ++q) { const float xv = acc[q] + dbias; v[q] = xv > 0.f ? xv : 0.f; }
#pragma unroll
    for (int q = 0; q < 4; ++q) {
      float s1 = v[q], s2 = v[q] * v[q];
#pragma unroll
      for (int o = 1; o < 16; o <<= 1) { s1 += __shfl_xor(s1, o); s2 += __shfl_xor(s2, o); }
      if (lr == 0) {
        const int row = lh * 4 + q;
        part[(row * 8 + wv) * 2] = s1;
        part[(row * 8 + wv) * 2 + 1] = s2;
      }
    }
    __syncthreads();
    if (tid < 16) {
      float S1 = 0.f, S2 = 0.f;
#pragma unroll
      for (int w = 0; w < 8; ++w) { S1 += part[(tid * 8 + w) * 2]; S2 += part[(tid * 8 + w) * 2 + 1]; }
      const float m = S1 * 0.0078125f;
      const float rs = rsqrtf(S2 * 0.0078125f - m * m + 1e-5f);
      rowstat[tid * 2] = m; rowstat[tid * 2 + 1] = rs;
    }
    __syncthreads();
#pragma unroll
    for (int q = 0; q < 4; ++q) {
      const int row = lh * 4 + q;
      const float m = rowstat[row * 2], rs = rowstat[row * 2 + 1];
      const u16 lnq = f2bf((v[q] - m) * rs * lg + lb);
      const u32 nb = (u32)__shfl_xor((int)(u32)lnq, 1);
      if ((l & 1) == 0)
        ASTORE(lnb32 + (rowbase + row) * 64 + (dcol >> 1), ((u32)lnq & 0xffffu) | (nb << 16));
      ASTORE(a.h0r + ((long)(s & 511) * 128 + g * 16 + row) * 128 + dcol,
             __float_as_uint(v[q]));
    }
    asm volatile("s_waitcnt vmcnt(0)" ::: "memory");
    __syncthreads();
    if (tid == 0) ASTORE(a.flg + 4096 + g * 1024 + s, 1u);
  }
}

// ---- b0: trailing serial block-GRU (consumes lnbuf, publishes y0 ring) ----
__device__ __forceinline__ void b0_scan(const MegaArgs& a, const int g, char* sm)
{
  const int tid = threadIdx.x, l = tid & 63;
  const int wv = __builtin_amdgcn_readfirstlane(tid >> 6);
  const int lr = l & 15, lh = l >> 4;
  const int gcol = wv * 16 + lr;
  char* T = sm;
  short8 Br[8], Bz[8], Bn[8];
#pragma unroll
  for (int t = 0; t < 8; ++t) {
    const int k = t * 32 + lh * 8;
    if (t < 4) {
      Br[t] = cvt8(a.c0whh + (long)(0 * 128 + gcol) * 128 + k);
      Bz[t] = cvt8(a.c0whh + (long)(1 * 128 + gcol) * 128 + k);
      Bn[t] = cvt8(a.c0whh + (long)(2 * 128 + gcol) * 128 + k);
    } else {
      const int kx = k - 128;
      Br[t] = cvt8(a.c0wih + (long)(0 * 128 + gcol) * 128 + kx);
      Bz[t] = cvt8(a.c0wih + (long)(1 * 128 + gcol) * 128 + kx);
      Bn[t] = cvt8(a.c0wih + (long)(2 * 128 + gcol) * 128 + kx);
    }
  }
  const float b0v = a.c0bih[gcol] + a.c0bhh[gcol];
  const float b1v = a.c0bih[128 + gcol] + a.c0bhh[128 + gcol];
  const float b2v = a.c0bih[256 + gcol];
  const float b3v = a.c0bhh[256 + gcol];
  float hk[4] = {0.f, 0.f, 0.f, 0.f};
#pragma unroll
  for (int i = 0; i < 2; ++i) {
    const int idx = tid + 512 * i; const int r = idx >> 6, d = idx & 63;
    *(u32*)(T + r * 544 + ((d * 4) ^ ((r & 7) << 4))) = 0u;
  }
  const u32* lnb32 = (const u32*)a.lnb;
  const u32* d0fp = a.flg + 4096 + g * 1024;
  const u32* ackp = a.flg + 12800 + g * 16;
  u32* myf = a.flg + 12544 + g * 16;
  __syncthreads();
  for (int s = 0; s < 1024; ++s) {
    if (wv == 0) {
      for (;;) {
        u32 f = 1u;
        if (l == 0)      f = ALOAD(d0fp + s);
        else if (l == 1) f = (ALOAD(ackp) + 3 >= (u32)s) ? 1u : 0u;  // y0 ring WAR
        if (__all(f >= 1u)) break;
        __builtin_amdgcn_s_sleep(4);
      }
    }
    __syncthreads();
#pragma unroll
    for (int i = 0; i < 2; ++i) {
      const int idx = tid + 512 * i; const int r = idx >> 6, d = idx & 63;
      const u32 xv = ALOAD(lnb32 + ((long)s * 128 + g * 16 + r) * 64 + d);
      *(u32*)(T + r * 544 + ((256 + d * 4) ^ ((r & 7) << 4))) = xv;
    }
    __syncthreads();
    f4 ar = {0.f, 0.f, 0.f, 0.f}; f4 az = ar, anh = ar, anx = ar;
#pragma unroll
    for (int t = 0; t < 8; ++t) {
      const short8 aa = *(const short8*)(T + lr * 544 + ((t * 64 + lh * 16) ^ ((lr & 7) << 4)));
      ar = MFMA16(aa, Br[t], ar, 0, 0, 0);
      az = MFMA16(aa, Bz[t], az, 0, 0, 0);
      if (t < 4) anh = MFMA16(aa, Bn[t], anh, 0, 0, 0);
      else       anx = MFMA16(aa, Bn[t], anx, 0, 0, 0);
    }
    u32 hnew[4];
#pragma unroll
    for (int q = 0; q < 4; ++q) {
      const float rg = sigm(ar[q] + b0v);
      const float zg = sigm(az[q] + b1v);
      const float ng = tanh_(anx[q] + b2v + rg * (anh[q] + b3v));
      const float h = (1.f - zg) * ng + zg * hk[q];
      hk[q] = h; hnew[q] = f2bf(h);
    }
    __syncthreads();
#pragma unroll
    for (int q = 0; q < 4; ++q) {
      const u32 nb = (u32)__shfl_xor((int)hnew[q], 1);
      if ((l & 1) == 0) {
        const u32 pk = (hnew[q] & 0xffffu) | (nb << 16);
        const int b = lh * 4 + q, c = wv * 16 + lr;
        *(u32*)(T + b * 544 + ((c * 2) ^ ((b & 7) << 4))) = pk;
        ASTORE(a.y0r + ((s & 3) * 8 + g) * 1024 + b * 64 + (c >> 1), pk);
      }
    }
    asm volatile("s_waitcnt vmcnt(0)" ::: "memory");
    __syncthreads();
    if (tid == 0) ASTORE(myf, (u32)(s + 1));
  }
}

// ---- b1: LN1(h0+y0) -> GRU -> final dense -> out; acks y0/h0 rings ----
__device__ __forceinline__ void b1_scan(const MegaArgs& a, const int g, char* sm)
{
  const int tid = threadIdx.x, l = tid & 63;
  const int wv = __builtin_amdgcn_readfirstlane(tid >> 6);
  const int lr = l & 15, lh = l >> 4;
  const int gcol = wv * 16 + lr;
  char* T = sm;
  float* SDF = (float*)(sm + 8704);
  float* SDB = (float*)(sm + 10752);
  short8 Br[8], Bz[8], Bn[8];
#pragma unroll
  for (int t = 0; t < 8; ++t) {
    const int k = t * 32 + lh * 8;
    if (t < 4) {
      Br[t] = cvt8(a.c1whh + (long)(0 * 128 + gcol) * 128 + k);
      Bz[t] = cvt8(a.c1whh + (long)(1 * 128 + gcol) * 128 + k);
      Bn[t] = cvt8(a.c1whh + (long)(2 * 128 + gcol) * 128 + k);
    } else {
      const int kx = k - 128;
      Br[t] = cvt8(a.c1wih + (long)(0 * 128 + gcol) * 128 + kx);
      Bz[t] = cvt8(a.c1wih + (long)(1 * 128 + gcol) * 128 + kx);
      Bn[t] = cvt8(a.c1wih + (long)(2 * 128 + gcol) * 128 + kx);
    }
  }
  const float b0v = a.c1bih[gcol] + a.c1bhh[gcol];
  const float b1v = a.c1bih[128 + gcol] + a.c1bhh[128 + gcol];
  const float b2v = a.c1bih[256 + gcol];
  const float b3v = a.c1bhh[256 + gcol];
  float hk[4] = {0.f, 0.f, 0.f, 0.f};
#pragma unroll
  for (int i = 0; i < 2; ++i) {
    const int idx = tid + 512 * i; const int r = idx >> 6, d = idx & 63;
    *(u32*)(T + r * 544 + ((d * 4) ^ ((r & 7) << 4))) = 0u;
  }
  SDF[tid] = a.dfw[tid];
  if (tid < 4) SDB[tid] = a.dfb[tid];
  const int rr = tid >> 5, cq = tid & 31, c4 = cq * 4;
  const float g1a = a.ln1g[c4], g1b = a.ln1g[c4 + 1], g1c = a.ln1g[c4 + 2], g1d = a.ln1g[c4 + 3];
  const float h1a = a.ln1b[c4], h1b = a.ln1b[c4 + 1], h1c = a.ln1b[c4 + 2], h1d = a.ln1b[c4 + 3];
  const u32* y0fp = a.flg + 12544 + g * 16;
  u32* ackp = a.flg + 12800 + g * 16;
  __syncthreads();
  for (int s = 0; s < 1024; ++s) {
    if (wv == 0) {
      const u32 tgt = (u32)(s + 1);
      for (;;) {
        const u32 f = (l == 0) ? ALOAD(y0fp) : tgt;
        if (__all(f >= tgt)) break;
        __builtin_amdgcn_s_sleep(4);
      }
    }
    __syncthreads();
    const u32 ya = ALOAD(a.y0r + ((s & 3) * 8 + g) * 1024 + rr * 64 + cq * 2);
    const u32 yb = ALOAD(a.y0r + ((s & 3) * 8 + g) * 1024 + rr * 64 + cq * 2 + 1);
    const long hbase = ((long)(s & 511) * 128 + g * 16 + rr) * 128 + c4;
    const float p0 = __uint_as_float(ALOAD(a.h0r + hbase));
    const float p1 = __uint_as_float(ALOAD(a.h0r + hbase + 1));
    const float p2 = __uint_as_float(ALOAD(a.h0r + hbase + 2));
    const float p3 = __uint_as_float(ALOAD(a.h0r + hbase + 3));
    const float u0 = p0 + bf2f(ya & 0xffffu);
    const float u1 = p1 + bf2f(ya >> 16);
    const float u2 = p2 + bf2f(yb & 0xffffu);
    const float u3 = p3 + bf2f(yb >> 16);
    float s1 = u0 + u1 + u2 + u3;
    float s2 = u0 * u0 + u1 * u1 + u2 * u2 + u3 * u3;
#pragma unroll
    for (int o = 1; o < 32; o <<= 1) { s1 += __shfl_xor(s1, o); s2 += __shfl_xor(s2, o); }
    const float m = s1 * 0.0078125f;
    const float rs = rsqrtf(s2 * 0.0078125f - m * m + 1e-5f);
    const u32 q0 = (u32)f2bf((u0 - m) * rs * g1a + h1a) |
                   ((u32)f2bf((u1 - m) * rs * g1b + h1b) << 16);
    const u32 q1 = (u32)f2bf((u2 - m) * rs * g1c + h1c) |
                   ((u32)f2bf((u3 - m) * rs * g1d + h1d) << 16);
    char* xa = T + rr * 544 + ((256 + cq * 8) ^ ((rr & 7) << 4));
    *(u32*)xa = q0;
    *(u32*)(xa + 4) = q1;
    __syncthreads();
    if (tid == 0) ASTORE(ackp, (u32)(s + 1));   // y0 + h0[s] consumed
    f4 ar = {0.f, 0.f, 0.f, 0.f}; f4 az = ar, anh = ar, anx = ar;
#pragma unroll
    for (int t = 0; t < 8; ++t) {
      const short8 aa = *(const short8*)(T + lr * 544 + ((t * 64 + lh * 16) ^ ((lr & 7) << 4)));
      ar = MFMA16(aa, Br[t], ar, 0, 0, 0);
      az = MFMA16(aa, Bz[t], az, 0, 0, 0);
      if (t < 4) anh = MFMA16(aa, Bn[t], anh, 0, 0, 0);
      else       anx = MFMA16(aa, Bn[t], anx, 0, 0, 0);
    }
    u32 hnew[4];
#pragma unroll
    for (int q = 0; q < 4; ++q) {
      const float rg = sigm(ar[q] + b0v);
      const float zg = sigm(az[q] + b1v);
      const float ng = tanh_(anx[q] + b2v + rg * (anh[q] + b3v));
      const float h = (1.f - zg) * ng + zg * hk[q];
      hk[q] = h; hnew[q] = f2bf(h);
    }
    __syncthreads();
#pragma unroll
    for (int q = 0; q < 4; ++q) {
      const u32 nb = (u32)__shfl_xor((int)hnew[q], 1);
      if ((l & 1) == 0) {
        const u32 pk = (hnew[q] & 0xffffu) | (nb << 16);
        const int b = lh * 4 + q, c = wv * 16 + lr;
        *(u32*)(T + b * 544 + ((c * 2) ^ ((b & 7) << 4))) = pk;
      }
    }
    __syncthreads();
    const int yo = (c4 * 2) ^ ((rr & 7) << 4);
    const u32 za = *(const u32*)(T + rr * 544 + yo);
    const u32 zb = *(const u32*)(T + rr * 544 + yo + 4);
    const float w0 = u0 + bf2f(za & 0xffffu);
    const float w1 = u1 + bf2f(za >> 16);
    const float w2 = u2 + bf2f(zb & 0xffffu);
    const float w3 = u3 + bf2f(zb >> 16);
    float pp0 = w0 * SDF[c4]       + w1 * SDF[c4 + 1]       + w2 * SDF[c4 + 2]       + w3 * SDF[c4 + 3];
    float pp1 = w0 * SDF[128 + c4] + w1 * SDF[128 + c4 + 1] + w2 * SDF[128 + c4 + 2] + w3 * SDF[128 + c4 + 3];
    float pp2 = w0 * SDF[256 + c4] + w1 * SDF[256 + c4 + 1] + w2 * SDF[256 + c4 + 2] + w3 * SDF[256 + c4 + 3];
    float pp3 = w0 * SDF[384 + c4] + w1 * SDF[384 + c4 + 1] + w2 * SDF[384 + c4 + 2] + w3 * SDF[384 + c4 + 3];
#pragma unroll
    for (int o = 1; o < 32; o <<= 1) {
      pp0 += __shfl_xor(pp0, o); pp1 += __shfl_xor(pp1, o);
      pp2 += __shfl_xor(pp2, o); pp3 += __shfl_xor(pp3, o);
    }
    if (cq == 0) {
      f4 ov = {pp0 + SDB[0], pp1 + SDB[1], pp2 + SDB[2], pp3 + SDB[3]};
      *(f4*)(a.out + ((long)s * 128 + g * 16 + rr) * 4) = ov;
    }
  }
}

// bids: 0-63 gru0 | 64-95 gru1 | 96-103 gru2 | 104-167 d0ln | 168-175 b0 | 176-183 b1
__global__ void __launch_bounds__(512, 2) mega(MegaArgs a) {
  __shared__ __align__(16) char sm[33280];
  const int bid = blockIdx.x;
  if (bid < 64) {
    const int group = bid & 7, slab = bid >> 3;
    gru0_scan(a.w0ih, a.w0hh, a.b0ih, a.b0hh, a.xb, a.hcat, group, slab,
              a.hbuf0 + group * 4096, a.hbuf0 + 32768 + group * 4096,
              a.flg + group * 128, sm);
  } else if (bid < 96) {
    const int id = bid - 64, G = id & 3, slab = id >> 2;
    gru_scan<256, 128, 32, 32, 8, 8, 0>(a.w1ih, a.w1hh, a.b1ih, a.b1hh, a.xd2,
        a.hcat, 896, 512 + slab * 32, G, slab,
        a.hbuf1 + G * 4096, a.hbuf1 + 16384 + G * 4096,
        a.flg + 1024 + G * 128, sm);
  } else if (bid < 104) {
    const int g = bid - 96;
    gru_scan<128, 64, 16, 128, 8, 0, 1>(a.w2ih, a.w2hh, a.b2ih, a.b2hh, a.xd4,
        a.hcat, 896, 768, g, 0, nullptr, nullptr,
        a.flg + 2048 + g * 16, sm);
  } else if (bid < 168) {
    const int id = bid - 104;
    d0ln_scan(a, id & 7, id >> 3, sm);
  } else if (bid < 176) {
    b0_scan(a, bid - 168, sm);
  } else {
    b1_scan(a, bid - 176, sm);
  }
}

// x -> bf16 full / ::2 / ::4 copies, plus upsample-folded d0 weight
__global__ void __launch_bounds__(256) prep(const float* __restrict__ x,
    u16* __restrict__ xb, u16* __restrict__ xd2, u16* __restrict__ xd4,
    const float* __restrict__ d0w, u16* __restrict__ d0wf) {
  const int b = blockIdx.x;
  if (b < 16384) {
    const long t = b * 256L + threadIdx.x;
    const f4 aa = ((const f4*)x)[t * 2];
    const f4 cc = ((const f4*)x)[t * 2 + 1];
    const u16 u0 = f2bf(aa[0]), u1 = f2bf(aa[1]), u2 = f2bf(aa[2]), u3 = f2bf(aa[3]);
    const u16 u4 = f2bf(cc[0]), u5 = f2bf(cc[1]), u6 = f2bf(cc[2]), u7 = f2bf(cc[3]);
    short8 s8; s8[0]=(short)u0; s8[1]=(short)u1; s8[2]=(short)u2; s8[3]=(short)u3;
    s8[4]=(short)u4; s8[5]=(short)u5; s8[6]=(short)u6; s8[7]=(short)u7;
    *(short8*)(xb + t * 8) = s8;
    const long row = t >> 5; const int ch = (int)(t & 31);
    *(u32*)(xd2 + row * 128 + ch * 4)     = (u32)u0 | ((u32)u2 << 16);
    *(u32*)(xd2 + row * 128 + ch * 4 + 2) = (u32)u4 | ((u32)u6 << 16);
    *(u32*)(xd4 + row * 64 + ch * 2)      = (u32)u0 | ((u32)u4 << 16);
  } else {
    const int idx = (b - 16384) * 256 + threadIdx.x;
    const int o = idx / 896, c = idx % 896;
    float v;
    if (c < 512) v = d0w[o * 1536 + c];
    else if (c < 768) { const int j = c - 512; v = d0w[o * 1536 + 512 + 2 * j] + d0w[o * 1536 + 513 + 2 * j]; }
    else { const int j = c - 768; const float* p = d0w + o * 1536 + 1024 + 4 * j; v = p[0] + p[1] + p[2] + p[3]; }
    d0wf[idx] = f2bf(v);
  }
}

extern "C" void kernel_launch(void* const* d_in, const int* in_sizes, int n_in,
                              void* d_out, int out_size, void* d_ws, size_t ws_size,
                              hipStream_t stream) {
  char* ws = (char*)d_ws;
  const float* x     = (const float*)d_in[0];
  const float* g0wih = (const float*)d_in[1];
  const float* g0whh = (const float*)d_in[2];
  const float* g0bih = (const float*)d_in[3];
  const float* g0bhh = (const float*)d_in[4];
  const float* g1wih = (const float*)d_in[5];
  const float* g1whh = (const float*)d_in[6];
  const float* g1bih = (const float*)d_in[7];
  const float* g1bhh = (const float*)d_in[8];
  const float* g2wih = (const float*)d_in[9];
  const float* g2whh = (const float*)d_in[10];
  const float* g2bih = (const float*)d_in[11];
  const float* g2bhh = (const float*)d_in[12];
  const float* d0w   = (const float*)d_in[13];
  const float* d0b   = (const float*)d_in[14];
  const float* ln0g  = (const float*)d_in[15];
  const float* ln0b  = (const float*)d_in[16];
  const float* b0wih = (const float*)d_in[17];
  const float* b0whh = (const float*)d_in[18];
  const float* b0bih = (const float*)d_in[19];
  const float* b0bhh = (const float*)d_in[20];
  const float* ln1g  = (const float*)d_in[21];
  const float* ln1b  = (const float*)d_in[22];
  const float* b1wih = (const float*)d_in[23];
  const float* b1whh = (const float*)d_in[24];
  const float* b1bih = (const float*)d_in[25];
  const float* b1bhh = (const float*)d_in[26];
  const float* dfw   = (const float*)d_in[27];
  const float* dfb   = (const float*)d_in[28];

  MegaArgs a;
  a.w0ih = g0wih; a.w0hh = g0whh; a.b0ih = g0bih; a.b0hh = g0bhh;
  a.w1ih = g1wih; a.w1hh = g1whh; a.b1ih = g1bih; a.b1hh = g1bhh;
  a.w2ih = g2wih; a.w2hh = g2whh; a.b2ih = g2bih; a.b2hh = g2bhh;
  a.xb  = (u16*)(ws + OFF_XB);
  a.xd2 = (u16*)(ws + OFF_XD2);
  a.xd4 = (u16*)(ws + OFF_XD4);
  a.hcat = (u16*)(ws + OFF_HCAT);
  a.lnb  = (u16*)(ws + OFF_LNB);
  a.h0r  = (u32*)(ws + OFF_H0R);
  a.y0r  = (u32*)(ws + OFF_Y0R);
  a.hbuf0 = (u32*)(ws + OFF_HB0);
  a.hbuf1 = (u32*)(ws + OFF_HB1);
  a.flg   = (u32*)(ws + OFF_FLG);
  a.d0wf  = (u16*)(ws + OFF_D0WF);
  a.d0b = d0b; a.ln0g = ln0g; a.ln0b = ln0b;
  a.c0wih = b0wih; a.c0whh = b0whh; a.c0bih = b0bih; a.c0bhh = b0bhh;
  a.ln1g = ln1g; a.ln1b = ln1b;
  a.c1wih = b1wih; a.c1whh = b1whh; a.c1bih = b1bih; a.c1bhh = b1bhh;
  a.dfw = dfw; a.dfb = dfb;
  a.out = (float*)d_out;

  // zero h publish parities + all flags/acks
  hipMemsetAsync(ws + OFF_HB0, 0, (size_t)(OFF_D0WF - OFF_HB0), stream);

  prep<<<16832, 256, 0, stream>>>(x, (u16*)(ws + OFF_XB), (u16*)(ws + OFF_XD2),
                                  (u16*)(ws + OFF_XD4), d0w, (u16*)(ws + OFF_D0WF));

  mega<<<184, 512, 0, stream>>>(a);
}

// Round 14
// 4540.837 us; speedup vs baseline: 6.2672x; 1.0059x over previous
//
#include <hip/hip_runtime.h>

typedef unsigned int u32;
typedef unsigned short u16;
typedef __attribute__((ext_vector_type(8))) short short8;
typedef __attribute__((ext_vector_type(4))) float f4;

#define MFMA16 __builtin_amdgcn_mfma_f32_16x16x32_bf16
#define ALOAD(p)    __hip_atomic_load((p), __ATOMIC_RELAXED, __HIP_MEMORY_SCOPE_AGENT)
#define ASTORE(p,v) __hip_atomic_store((p), (v), __ATOMIC_RELAXED, __HIP_MEMORY_SCOPE_AGENT)

// ---------- workspace layout (bytes) ----------
#define OFF_XB    0LL            // x bf16 (67,108,864)
#define OFF_XD2   67108864LL     // x[::2] bf16 (33,554,432)
#define OFF_XD4   100663296LL    // x[::4] bf16 (16,777,216)
#define OFF_HCAT  117440512LL    // concat bf16 (234,881,024) producers ASTORE, d0ln reads
#define OFF_LNB   352321536LL    // ln0 out bf16 (33,554,432) d0ln -> b0
#define OFF_H0R   385875968LL    // h0 fp32 ring, 512 steps (33,554,432) d0ln -> b1
#define OFF_Y0R   419430400LL    // y0 ring 4 par x 8 g x 16x128 bf16 (131,072) b0 -> b1
#define OFF_HB0   419561472LL    // gru0 h publish 2 par (262,144)
#define OFF_HB1   419823616LL    // gru1 h publish 2 par (131,072)
#define OFF_FLG   419954688LL    // flags (65,536)
#define OFF_D0WF  420020224LL    // folded d0 weight bf16 (229,376)
// flag u32 idx: gru0 g*128+slab*16 | gru1 1024+G*128+slab*16 | gru2 2048+g*16
//               d0f 4096+g*1024+s | y0f 12544+g*16 | b1ack 12800+g*16
// Visibility contract: producer flag s+1 => h-publish[s] visible.
//   hcat[s] visible only at flag >= s+2 (lazy hcat drain; in-order vmcnt).

__device__ __forceinline__ u16 f2bf(float f) {
  u32 u = __float_as_uint(f);
  return (u16)((u + 0x7fffu + ((u >> 16) & 1u)) >> 16);   // RNE
}
__device__ __forceinline__ float bf2f(u32 b) { return __uint_as_float(b << 16); }
__device__ __forceinline__ float sigm(float x) { return __builtin_amdgcn_rcpf(1.f + __expf(-x)); }
__device__ __forceinline__ float tanh_(float x) { return 1.f - 2.f * __builtin_amdgcn_rcpf(1.f + __expf(2.f * x)); }

__device__ __forceinline__ short8 cvt8(const float* p) {
  short8 r;
#pragma unroll
  for (int j = 0; j < 8; ++j) r[j] = (short)f2bf(p[j]);
  return r;
}

// =====================================================================
// Generic fused GRU scan (r13-proven; gru1 GH path + gru2 PUB path).
// =====================================================================
template<int KH, int KX, int BT, int CSPAN, int WAVES, int GROUP_WGS, int PUB>
__device__ __forceinline__ void gru_scan(
    const float* __restrict__ wih, const float* __restrict__ whh,
    const float* __restrict__ bih, const float* __restrict__ bhh,
    const u16* __restrict__ xsrc,
    u16* __restrict__ outp, const int outPitch, const int outColBase,
    const int group, const int slab,
    u32* __restrict__ hbA, u32* __restrict__ hbB, u32* __restrict__ flags,
    char* sm)
{
  constexpr int H = KH;
  constexpr int KT = (KH + KX) / 32;
  constexpr int KH32 = KH / 32;
  constexpr int PITCH = (KH + KX) * 2 + 32;
  constexpr int CT_N = CSPAN / 16;
  constexpr int NTILES = (BT / 16) * CT_N;
  constexpr int MAXP = (NTILES + WAVES - 1) / WAVES;
  constexpr int NT = WAVES * 64;
  constexpr int NX = (BT * KX / 2) / NT;
  constexpr int NH = (BT * KH / 2) / NT;
  constexpr bool GH = (GROUP_WGS > 0);

  const int tid = threadIdx.x;
  const int l = tid & 63;
  const int wv = __builtin_amdgcn_readfirstlane(tid >> 6);  // SCALAR wave id
  const int lr = l & 15;
  const int lh = l >> 4;
  const long srow0 = group * BT;

  short8 Br[MAXP][KT], Bz[MAXP][KT], Bn[MAXP][KT];
  float bb0[MAXP], bb1[MAXP], bb2[MAXP], bb3[MAXP];
  float hk[MAXP][4];
#pragma unroll
  for (int p = 0; p < MAXP; ++p) {
    const int tp = wv + WAVES * p;
    const int tpc = (tp < NTILES) ? tp : 0;
    const int ct = tpc % CT_N;
    const int gcol = slab * CSPAN + ct * 16 + lr;
#pragma unroll
    for (int t = 0; t < KT; ++t) {
      const int k = t * 32 + lh * 8;
      if (t < KH32) {
        Br[p][t] = cvt8(whh + (long)(0 * H + gcol) * KH + k);
        Bz[p][t] = cvt8(whh + (long)(1 * H + gcol) * KH + k);
        Bn[p][t] = cvt8(whh + (long)(2 * H + gcol) * KH + k);
      } else {
        const int kx = k - KH;
        Br[p][t] = cvt8(wih + (long)(0 * H + gcol) * KX + kx);
        Bz[p][t] = cvt8(wih + (long)(1 * H + gcol) * KX + kx);
        Bn[p][t] = cvt8(wih + (long)(2 * H + gcol) * KX + kx);
      }
    }
    bb0[p] = bih[0 * H + gcol] + bhh[0 * H + gcol];
    bb1[p] = bih[1 * H + gcol] + bhh[1 * H + gcol];
    bb2[p] = bih[2 * H + gcol];
    bb3[p] = bhh[2 * H + gcol];
    hk[p][0] = hk[p][1] = hk[p][2] = hk[p][3] = 0.f;
  }

  if constexpr (!GH) {
#pragma unroll
    for (int i = 0; i < (BT * KH / 2 + NT - 1) / NT; ++i) {
      const int idx = tid + NT * i;
      if (idx < BT * KH / 2) {
        const int r = idx / (KH / 2), d = idx % (KH / 2);
        *(u32*)(sm + r * PITCH + ((d * 4) ^ ((r & 7) << 4))) = 0u;
      }
    }
  }

  u32 xr[NX];
#pragma unroll
  for (int i = 0; i < NX; ++i) {
    const int idx = tid + NT * i;
    const int r = idx / (KX / 2), d = idx % (KX / 2);
    xr[i] = *(const u32*)(xsrc + (srow0 + r) * KX + d * 2);
  }

  for (int s = 0; s < 1024; ++s) {
    if constexpr (GH) {
      if (wv == 0) {
        const u32 tgt = (u32)s;
        for (;;) {
          const u32 f = (l < GROUP_WGS) ? ALOAD(flags + l * 16) : tgt;
          if (__all(f >= tgt)) break;
        }
      }
      __builtin_amdgcn_s_barrier();   // raw: nothing to drain here
    }
#pragma unroll
    for (int i = 0; i < NX; ++i) {
      const int idx = tid + NT * i;
      const int r = idx / (KX / 2), d = idx % (KX / 2);
      *(u32*)(sm + r * PITCH + ((KH * 2 + d * 4) ^ ((r & 7) << 4))) = xr[i];
    }
    if constexpr (GH) {
      const u32* hb = (s & 1) ? hbB : hbA;
#pragma unroll
      for (int i = 0; i < NH; ++i) {
        const int idx = tid + NT * i;
        const int r = idx / (KH / 2), d = idx % (KH / 2);
        const u32 v = ALOAD(hb + r * (KH / 2) + d);
        *(u32*)(sm + r * PITCH + ((d * 4) ^ ((r & 7) << 4))) = v;
      }
    }
    if constexpr (!(GH || PUB)) {
      if (s + 1 < 1024) {
#pragma unroll
        for (int i = 0; i < NX; ++i) {
          const int idx = tid + NT * i;
          const int r = idx / (KX / 2), d = idx % (KX / 2);
          xr[i] = *(const u32*)(xsrc + ((s + 1) * 128L + srow0 + r) * KX + d * 2);
        }
      }
    }
    __syncthreads();

    u32 hnew[MAXP][4];
#pragma unroll
    for (int p = 0; p < MAXP; ++p) {
      const int tp = wv + WAVES * p;
      if (tp < NTILES) {
        const int mt = tp / CT_N;
        f4 ar = {0.f, 0.f, 0.f, 0.f}; f4 az = ar, anh = ar, anx = ar;
#pragma unroll
        for (int t = 0; t < KT; ++t) {
          const int row = mt * 16 + lr;
          const short8 a = *(const short8*)(sm + row * PITCH +
                              ((t * 64 + lh * 16) ^ ((row & 7) << 4)));
          ar = MFMA16(a, Br[p][t], ar, 0, 0, 0);
          az = MFMA16(a, Bz[p][t], az, 0, 0, 0);
          if (t < KH32) anh = MFMA16(a, Bn[p][t], anh, 0, 0, 0);
          else          anx = MFMA16(a, Bn[p][t], anx, 0, 0, 0);
        }
#pragma unroll
        for (int q = 0; q < 4; ++q) {
          const float rg = sigm(ar[q] + bb0[p]);
          const float zg = sigm(az[q] + bb1[p]);
          const float ng = tanh_(anx[q] + bb2[p] + rg * (anh[q] + bb3[p]));
          const float h = (1.f - zg) * ng + zg * hk[p][q];
          hk[p][q] = h;
          hnew[p][q] = f2bf(h);
        }
      }
    }
    if constexpr (!GH) __syncthreads();

    u32 pkv[MAXP][4];
#pragma unroll
    for (int p = 0; p < MAXP; ++p) {
      const int tp = wv + WAVES * p;
      if (tp < NTILES) {
        const int mt = tp / CT_N, ct = tp % CT_N;
        const int c = ct * 16 + lr;
#pragma unroll
        for (int q = 0; q < 4; ++q) {
          const u32 nb = (u32)__shfl_xor((int)hnew[p][q], 1);
          pkv[p][q] = (hnew[p][q] & 0xffffu) | (nb << 16);
          if ((l & 1) == 0) {
            const int b = mt * 16 + lh * 4 + q;
            if constexpr (GH) {
              u32* hbn = ((s + 1) & 1) ? hbB : hbA;
              ASTORE(hbn + b * (KH / 2) + (slab * CSPAN + c) / 2, pkv[p][q]);
            } else {
              *(u32*)(sm + b * PITCH + ((c * 2) ^ ((b & 7) << 4))) = pkv[p][q];
            }
          }
        }
      }
    }
    __builtin_amdgcn_sched_barrier(0);
#pragma unroll
    for (int p = 0; p < MAXP; ++p) {
      const int tp = wv + WAVES * p;
      if (tp < NTILES) {
        const int mt = tp / CT_N, ct = tp % CT_N;
        const int c = ct * 16 + lr;
#pragma unroll
        for (int q = 0; q < 4; ++q) {
          if ((l & 1) == 0) {
            const int b = mt * 16 + lh * 4 + q;
            u32* oa = (u32*)(outp + (s * 128L + srow0 + b) * outPitch + outColBase + c);
            if constexpr (GH || PUB) ASTORE(oa, pkv[p][q]); else *oa = pkv[p][q];
          }
        }
      }
    }
    if constexpr (GH) {
      __builtin_amdgcn_sched_barrier(0);
      if (s + 1 < 1024) {
#pragma unroll
        for (int i = 0; i < NX; ++i) {
          const int idx = tid + NT * i;
          const int r = idx / (KX / 2), d = idx % (KX / 2);
          xr[i] = ALOAD((const u32*)(xsrc + ((s + 1) * 128L + srow0 + r) * KX + d * 2));
        }
        __builtin_amdgcn_sched_barrier(0);
        asm volatile("s_waitcnt vmcnt(%0)" :: "i"(MAXP * 4 + NX) : "memory");
      } else {
        asm volatile("s_waitcnt vmcnt(0)" ::: "memory");
      }
      __builtin_amdgcn_s_barrier();
      if (tid == 0) ASTORE(flags + slab * 16, (u32)(s + 1));
    } else if constexpr (PUB) {
      __builtin_amdgcn_sched_barrier(0);
      if (s + 1 < 1024) {
#pragma unroll
        for (int i = 0; i < NX; ++i) {
          const int idx = tid + NT * i;
          const int r = idx / (KX / 2), d = idx % (KX / 2);
          xr[i] = ALOAD((const u32*)(xsrc + ((s + 1) * 128L + srow0 + r) * KX + d * 2));
        }
        __builtin_amdgcn_sched_barrier(0);
        asm volatile("s_waitcnt vmcnt(%0)" :: "i"(NX) : "memory");
      } else {
        asm volatile("s_waitcnt vmcnt(0)" ::: "memory");
      }
      __builtin_amdgcn_s_barrier();
      if (tid == 0) ASTORE(flags, (u32)(s + 1));
    }
  }
}

// =====================================================================
// gru0 (H=512, Kin=256), r14 step structure:
//  B: x-part MFMAs (t=16..23; x staged last step) — runs DURING peers'
//     flag wait window.
//  C: issue x[s+1] prefetch; per-wave poll of own slab's flag (wave w
//     <-> slab w): early slabs' loads overlap late slabs' flags.
//  D: per-wave load of own slab's h[s] -> LDS; lgkm + raw barrier.
//  F: h-part MFMAs (t=0..15); gg1 red export; lgkm + raw barrier.
//  G: gg0 gates + publish + lazy hcat; ALL stage x[s+1];
//     vmcnt(4) lgkmcnt(0) (publish ack'd; hcat+0 in flight);
//     raw barrier; flag = s+1.
// 3 barriers/step (was 4); poll decentralized; x stage off the chain.
// Accumulation order within chains: x-part first (numeric reorder only).
// =====================================================================
__device__ __forceinline__ void gru0_scan(
    const float* __restrict__ wih, const float* __restrict__ whh,
    const float* __restrict__ bih, const float* __restrict__ bhh,
    const u16* __restrict__ x, u16* __restrict__ outp,
    const int group, const int slab,
    u32* __restrict__ hbA, u32* __restrict__ hbB, u32* __restrict__ flags,
    char* sm)
{
  constexpr int PITCH = 1568;
  const int tid = threadIdx.x;
  const int l = tid & 63;
  const int wv = __builtin_amdgcn_readfirstlane(tid >> 6);
  const int lr = l & 15, lh = l >> 4;
  const int ct = wv & 3, gg = wv >> 2;
  const long srow0 = group * 16;
  const int gcol = slab * 64 + ct * 16 + lr;
  f4* red = (f4*)(sm + 25088);

  short8 W0[24], W1[16];
#pragma unroll
  for (int t = 0; t < 24; ++t) {
    const int k = t * 32 + lh * 8;
    if (t < 16) W0[t] = cvt8(whh + (long)(gg * 512 + gcol) * 512 + k);
    else        W0[t] = cvt8(wih + (long)(gg * 512 + gcol) * 256 + (k - 512));
  }
  if (gg == 0) {
#pragma unroll
    for (int t = 0; t < 16; ++t)
      W1[t] = cvt8(whh + (long)(2 * 512 + gcol) * 512 + t * 32 + lh * 8);
  } else {
#pragma unroll
    for (int t = 0; t < 8; ++t)
      W1[t] = cvt8(wih + (long)(2 * 512 + gcol) * 256 + t * 32 + lh * 8);
  }
  const float bb0 = bih[0 * 512 + gcol] + bhh[0 * 512 + gcol];
  const float bb1 = bih[1 * 512 + gcol] + bhh[1 * 512 + gcol];
  const float bb2 = bih[2 * 512 + gcol];
  const float bb3 = bhh[2 * 512 + gcol];
  float hk[4] = {0.f, 0.f, 0.f, 0.f};

  u32 xr[4];
#pragma unroll
  for (int i = 0; i < 4; ++i) {
    const int idx = tid + 512 * i;
    const int r = idx >> 7, d = idx & 127;
    xr[i] = *(const u32*)(x + (srow0 + r) * 256 + d * 2);
  }
  // pre-stage x[0]
#pragma unroll
  for (int i = 0; i < 4; ++i) {
    const int idx = tid + 512 * i;
    const int r = idx >> 7, d = idx & 127;
    *(u32*)(sm + r * PITCH + ((1024 + d * 4) ^ ((r & 7) << 4))) = xr[i];
  }
  __syncthreads();

  for (int s = 0; s < 1024; ++s) {
    // ---- B: x-part MFMAs (t = 16..23) ----
    f4 a0 = {0.f, 0.f, 0.f, 0.f}, a1 = a0;
    if (gg == 0) {
#pragma unroll
      for (int t = 16; t < 24; ++t) {
        const short8 a = *(const short8*)(sm + lr * PITCH +
                            ((t * 64 + lh * 16) ^ ((lr & 7) << 4)));
        a0 = MFMA16(a, W0[t], a0, 0, 0, 0);
      }
    } else {
#pragma unroll
      for (int t = 16; t < 24; ++t) {
        const short8 a = *(const short8*)(sm + lr * PITCH +
                            ((t * 64 + lh * 16) ^ ((lr & 7) << 4)));
        a0 = MFMA16(a, W0[t], a0, 0, 0, 0);
        a1 = MFMA16(a, W1[t - 16], a1, 0, 0, 0);
      }
    }
    // ---- C: prefetch x[s+1]; per-wave poll own slab flag >= s ----
    if (s + 1 < 1024) {
#pragma unroll
      for (int i = 0; i < 4; ++i) {
        const int idx = tid + 512 * i;
        const int r = idx >> 7, d = idx & 127;
        xr[i] = ALOAD((const u32*)(x + ((s + 1) * 128L + srow0 + r) * 256 + d * 2));
      }
    }
    for (;;) {
      const u32 f = ALOAD(flags + wv * 16);
      if (__builtin_amdgcn_readfirstlane(f) >= (u32)s) break;
    }
    // ---- D: per-wave load own slab's h[s] -> LDS ----
    {
      const u32* hb = (s & 1) ? hbB : hbA;
#pragma unroll
      for (int i = 0; i < 8; ++i) {
        const int idx = l + 64 * i;
        const int r = idx >> 5, d = idx & 31;
        const u32 v = ALOAD(hb + r * 256 + wv * 32 + d);
        *(u32*)(sm + r * PITCH + ((wv * 128 + d * 4) ^ ((r & 7) << 4))) = v;
      }
    }
    asm volatile("s_waitcnt lgkmcnt(0)" ::: "memory");
    __builtin_amdgcn_sched_barrier(0);
    __builtin_amdgcn_s_barrier();                       // E
    __builtin_amdgcn_sched_barrier(0);
    // ---- F: h-part MFMAs (t = 0..15) ----
    if (gg == 0) {
#pragma unroll
      for (int t = 0; t < 16; ++t) {
        const short8 a = *(const short8*)(sm + lr * PITCH +
                            ((t * 64 + lh * 16) ^ ((lr & 7) << 4)));
        a0 = MFMA16(a, W0[t], a0, 0, 0, 0);
        a1 = MFMA16(a, W1[t], a1, 0, 0, 0);
      }
    } else {
#pragma unroll
      for (int t = 0; t < 16; ++t) {
        const short8 a = *(const short8*)(sm + lr * PITCH +
                            ((t * 64 + lh * 16) ^ ((lr & 7) << 4)));
        a0 = MFMA16(a, W0[t], a0, 0, 0, 0);
      }
      red[(ct * 2 + 0) * 64 + l] = a0;                  // az
      red[(ct * 2 + 1) * 64 + l] = a1;                  // anx
    }
    asm volatile("s_waitcnt lgkmcnt(0)" ::: "memory");
    __builtin_amdgcn_sched_barrier(0);
    __builtin_amdgcn_s_barrier();                       // R
    __builtin_amdgcn_sched_barrier(0);
    // ---- G: gates + publish + lazy hcat; stage x[s+1]; drain; flag ----
    u32 pkv[4];
    if (gg == 0) {
      const f4 paz  = red[(ct * 2 + 0) * 64 + l];
      const f4 panx = red[(ct * 2 + 1) * 64 + l];
      u32 hnew[4];
#pragma unroll
      for (int q = 0; q < 4; ++q) {
        const float rg = sigm(a0[q] + bb0);
        const float zg = sigm(paz[q] + bb1);
        const float ng = tanh_(panx[q] + bb2 + rg * (a1[q] + bb3));
        const float h = (1.f - zg) * ng + zg * hk[q];
        hk[q] = h;
        hnew[q] = f2bf(h);
      }
      u32* hbn = ((s + 1) & 1) ? hbB : hbA;
#pragma unroll
      for (int q = 0; q < 4; ++q) {                     // publish batch
        const u32 nb = (u32)__shfl_xor((int)hnew[q], 1);
        pkv[q] = (hnew[q] & 0xffffu) | (nb << 16);
        if ((l & 1) == 0) {
          const int b = lh * 4 + q;
          const int c = ct * 16 + lr;
          ASTORE(hbn + b * 256 + (slab * 64 + c) / 2, pkv[q]);
        }
      }
      __builtin_amdgcn_sched_barrier(0);
#pragma unroll
      for (int q = 0; q < 4; ++q) {                     // hcat batch (lazy)
        if ((l & 1) == 0) {
          const int b = lh * 4 + q;
          const int c = ct * 16 + lr;
          ASTORE((u32*)(outp + (s * 128L + srow0 + b) * 896 + slab * 64 + c), pkv[q]);
        }
      }
    }
    __builtin_amdgcn_sched_barrier(0);
    if (s + 1 < 1024) {
      // stage x[s+1] (x region dead since phase B); consumes prefetch
#pragma unroll
      for (int i = 0; i < 4; ++i) {
        const int idx = tid + 512 * i;
        const int r = idx >> 7, d = idx & 127;
        *(u32*)(sm + r * PITCH + ((1024 + d * 4) ^ ((r & 7) << 4))) = xr[i];
      }
      __builtin_amdgcn_sched_barrier(0);
      asm volatile("s_waitcnt vmcnt(4) lgkmcnt(0)" ::: "memory");
    } else {
      asm volatile("s_waitcnt vmcnt(0) lgkmcnt(0)" ::: "memory");
    }
    __builtin_amdgcn_s_barrier();                       // END
    __builtin_amdgcn_sched_barrier(0);
    if (tid == 0) ASTORE(flags + slab * 16, (u32)(s + 1));
  }
}

struct MegaArgs {
  const float *w0ih, *w0hh, *b0ih, *b0hh;
  const float *w1ih, *w1hh, *b1ih, *b1hh;
  const float *w2ih, *w2hh, *b2ih, *b2hh;
  const u16 *xb, *xd2, *xd4;
  u16 *hcat, *lnb;
  u32 *h0r, *y0r, *hbuf0, *hbuf1, *flg;
  const u16 *d0wf; const float *d0b;
  const float *ln0g, *ln0b;
  const float *c0wih, *c0whh, *c0bih, *c0bhh;
  const float *ln1g, *ln1b;
  const float *c1wih, *c1whh, *c1bih, *c1bhh;
  const float *dfw, *dfb;
  float* out;
};

// =====================================================================
// d0+LN0 trailing WG (g, p): steps s = p, p+8, ... (r13-proven; lag-2).
// =====================================================================
__device__ __forceinline__ void d0ln_scan(const MegaArgs& a, const int g,
                                          const int p, char* sm)
{
  const int tid = threadIdx.x;
  const int l = tid & 63;
  const int wv = __builtin_amdgcn_readfirstlane(tid >> 6);
  const int lr = l & 15, lh = l >> 4;
  const int dcol = wv * 16 + lr;
  u16* sA = (u16*)sm;                       // [16][40]
  float* part = (float*)(sm + 1536);        // [16][8][2]
  float* rowstat = (float*)(sm + 3584);     // [16][2]

  short8 Dw[28];
#pragma unroll
  for (int t = 0; t < 28; ++t)
    Dw[t] = *(const short8*)(a.d0wf + (long)dcol * 896 + t * 32 + lh * 8);
  const float dbias = a.d0b[dcol];
  const float lg = a.ln0g[dcol], lb = a.ln0b[dcol];

  const u32* hcat32 = (const u32*)a.hcat;
  u32* lnb32 = (u32*)a.lnb;
  const u32* pollp;
  if (l < 8)        pollp = a.flg + g * 128 + l * 16;
  else if (l < 16)  pollp = a.flg + 1024 + (g >> 1) * 128 + (l - 8) * 16;
  else if (l == 16) pollp = a.flg + 2048 + g * 16;
  else              pollp = a.flg + 12800 + g * 16;   // b1 ack (h0 ring WAR)
  const int stg = (tid < 256);
  const int sr = tid >> 4, sc = tid & 15;

  for (int s = p; s < 1024; s += 8) {
    if (wv == 0) {
      const u32 t01 = (u32)((s + 2 < 1024) ? s + 2 : 1024);  // hcat[s] visible
      const u32 t2  = (u32)(s + 1);
      for (;;) {
        int ok = 1;
        if (l < 16)       ok = (ALOAD(pollp) >= t01);
        else if (l == 16) ok = (ALOAD(pollp) >= t2);
        else if (l == 17) ok = (ALOAD(pollp) + 512 >= t2);   // ack >= s-511
        if (__all(ok)) break;
        __builtin_amdgcn_s_sleep(32);
      }
    }
    __syncthreads();
    const long rowbase = (long)s * 128 + g * 16;
    f4 acc = {0.f, 0.f, 0.f, 0.f};
    u32 vst = 0;
    if (stg) vst = ALOAD(hcat32 + (rowbase + sr) * 448 + sc);
    for (int kt = 0; kt < 28; ++kt) {
      u32 vnext = 0;
      if (kt + 1 < 28 && stg)
        vnext = ALOAD(hcat32 + (rowbase + sr) * 448 + (kt + 1) * 16 + sc);
      __syncthreads();
      if (stg) *(u32*)((char*)sA + sr * 80 + sc * 4) = vst;
      __syncthreads();
      const short8 af = *(const short8*)((char*)sA + lr * 80 + lh * 16);
      acc = MFMA16(af, Dw[kt], acc, 0, 0, 0);
      vst = vnext;
    }
    float v[4];
#pragma unroll
    for (int q = 0; q < 4; ++q) { const float xv = acc[q] + dbias; v[q] = xv > 0.f ? xv : 0.f; }
#pragma unroll
    for (int q = 0; q < 4; ++q) {
      float s1 = v[q], s2 = v[q] * v[q];
#pragma unroll
      for (int o = 1; o < 16; o <<= 1) { s1 += __shfl_xor(s1, o); s2 += __shfl_xor(s2, o); }
      if (lr == 0) {
        const int row = lh * 4 + q;
        part[(row * 8 + wv) * 2] = s1;
        part[(row * 8 + wv) * 2 + 1] = s2;
      }
    }
    __syncthreads();
    if (tid < 16) {
      float S1 = 0.f, S2 = 0.f;
#pragma unroll
      for (int w = 0; w < 8; ++w) { S1 += part[(tid * 8 + w) * 2]; S2 += part[(tid * 8 + w) * 2 + 1]; }
      const float m = S1 * 0.0078125f;
      const float rs = rsqrtf(S2 * 0.0078125f - m * m + 1e-5f);
      rowstat[tid * 2] = m; rowstat[tid * 2 + 1] = rs;
    }
    __syncthreads();
#pragma unroll
    for (int q = 0; q < 4; ++q) {
      const int row = lh * 4 + q;
      const float m = rowstat[row * 2], rs = rowstat[row * 2 + 1];
      const u16 lnq = f2bf((v[q] - m) * rs * lg + lb);
      const u32 nb = (u32)__shfl_xor((int)(u32)lnq, 1);
      if ((l & 1) == 0)
        ASTORE(lnb32 + (rowbase + row) * 64 + (dcol >> 1), ((u32)lnq & 0xffffu) | (nb << 16));
      ASTORE(a.h0r + ((long)(s & 511) * 128 + g * 16 + row) * 128 + dcol,
             __float_as_uint(v[q]));
    }
    asm volatile("s_waitcnt vmcnt(0)" ::: "memory");
    __syncthreads();
    if (tid == 0) ASTORE(a.flg + 4096 + g * 1024 + s, 1u);
  }
}

// ---- b0: trailing serial block-GRU (consumes lnbuf, publishes y0 ring) ----
__device__ __forceinline__ void b0_scan(const MegaArgs& a, const int g, char* sm)
{
  const int tid = threadIdx.x, l = tid & 63;
  const int wv = __builtin_amdgcn_readfirstlane(tid >> 6);
  const int lr = l & 15, lh = l >> 4;
  const int gcol = wv * 16 + lr;
  char* T = sm;
  short8 Br[8], Bz[8], Bn[8];
#pragma unroll
  for (int t = 0; t < 8; ++t) {
    const int k = t * 32 + lh * 8;
    if (t < 4) {
      Br[t] = cvt8(a.c0whh + (long)(0 * 128 + gcol) * 128 + k);
      Bz[t] = cvt8(a.c0whh + (long)(1 * 128 + gcol) * 128 + k);
      Bn[t] = cvt8(a.c0whh + (long)(2 * 128 + gcol) * 128 + k);
    } else {
      const int kx = k - 128;
      Br[t] = cvt8(a.c0wih + (long)(0 * 128 + gcol) * 128 + kx);
      Bz[t] = cvt8(a.c0wih + (long)(1 * 128 + gcol) * 128 + kx);
      Bn[t] = cvt8(a.c0wih + (long)(2 * 128 + gcol) * 128 + kx);
    }
  }
  const float b0v = a.c0bih[gcol] + a.c0bhh[gcol];
  const float b1v = a.c0bih[128 + gcol] + a.c0bhh[128 + gcol];
  const float b2v = a.c0bih[256 + gcol];
  const float b3v = a.c0bhh[256 + gcol];
  float hk[4] = {0.f, 0.f, 0.f, 0.f};
#pragma unroll
  for (int i = 0; i < 2; ++i) {
    const int idx = tid + 512 * i; const int r = idx >> 6, d = idx & 63;
    *(u32*)(T + r * 544 + ((d * 4) ^ ((r & 7) << 4))) = 0u;
  }
  const u32* lnb32 = (const u32*)a.lnb;
  const u32* d0fp = a.flg + 4096 + g * 1024;
  const u32* ackp = a.flg + 12800 + g * 16;
  u32* myf = a.flg + 12544 + g * 16;
  __syncthreads();
  for (int s = 0; s < 1024; ++s) {
    if (wv == 0) {
      for (;;) {
        u32 f = 1u;
        if (l == 0)      f = ALOAD(d0fp + s);
        else if (l == 1) f = (ALOAD(ackp) + 3 >= (u32)s) ? 1u : 0u;  // y0 ring WAR
        if (__all(f >= 1u)) break;
        __builtin_amdgcn_s_sleep(4);
      }
    }
    __syncthreads();
#pragma unroll
    for (int i = 0; i < 2; ++i) {
      const int idx = tid + 512 * i; const int r = idx >> 6, d = idx & 63;
      const u32 xv = ALOAD(lnb32 + ((long)s * 128 + g * 16 + r) * 64 + d);
      *(u32*)(T + r * 544 + ((256 + d * 4) ^ ((r & 7) << 4))) = xv;
    }
    __syncthreads();
    f4 ar = {0.f, 0.f, 0.f, 0.f}; f4 az = ar, anh = ar, anx = ar;
#pragma unroll
    for (int t = 0; t < 8; ++t) {
      const short8 aa = *(const short8*)(T + lr * 544 + ((t * 64 + lh * 16) ^ ((lr & 7) << 4)));
      ar = MFMA16(aa, Br[t], ar, 0, 0, 0);
      az = MFMA16(aa, Bz[t], az, 0, 0, 0);
      if (t < 4) anh = MFMA16(aa, Bn[t], anh, 0, 0, 0);
      else       anx = MFMA16(aa, Bn[t], anx, 0, 0, 0);
    }
    u32 hnew[4];
#pragma unroll
    for (int q = 0; q < 4; ++q) {
      const float rg = sigm(ar[q] + b0v);
      const float zg = sigm(az[q] + b1v);
      const float ng = tanh_(anx[q] + b2v + rg * (anh[q] + b3v));
      const float h = (1.f - zg) * ng + zg * hk[q];
      hk[q] = h; hnew[q] = f2bf(h);
    }
    __syncthreads();
#pragma unroll
    for (int q = 0; q < 4; ++q) {
      const u32 nb = (u32)__shfl_xor((int)hnew[q], 1);
      if ((l & 1) == 0) {
        const u32 pk = (hnew[q] & 0xffffu) | (nb << 16);
        const int b = lh * 4 + q, c = wv * 16 + lr;
        *(u32*)(T + b * 544 + ((c * 2) ^ ((b & 7) << 4))) = pk;
        ASTORE(a.y0r + ((s & 3) * 8 + g) * 1024 + b * 64 + (c >> 1), pk);
      }
    }
    asm volatile("s_waitcnt vmcnt(0)" ::: "memory");
    __syncthreads();
    if (tid == 0) ASTORE(myf, (u32)(s + 1));
  }
}

// ---- b1: LN1(h0+y0) -> GRU -> final dense -> out; acks y0/h0 rings ----
__device__ __forceinline__ void b1_scan(const MegaArgs& a, const int g, char* sm)
{
  const int tid = threadIdx.x, l = tid & 63;
  const int wv = __builtin_amdgcn_readfirstlane(tid >> 6);
  const int lr = l & 15, lh = l >> 4;
  const int gcol = wv * 16 + lr;
  char* T = sm;
  float* SDF = (float*)(sm + 8704);
  float* SDB = (float*)(sm + 10752);
  short8 Br[8], Bz[8], Bn[8];
#pragma unroll
  for (int t = 0; t < 8; ++t) {
    const int k = t * 32 + lh * 8;
    if (t < 4) {
      Br[t] = cvt8(a.c1whh + (long)(0 * 128 + gcol) * 128 + k);
      Bz[t] = cvt8(a.c1whh + (long)(1 * 128 + gcol) * 128 + k);
      Bn[t] = cvt8(a.c1whh + (long)(2 * 128 + gcol) * 128 + k);
    } else {
      const int kx = k - 128;
      Br[t] = cvt8(a.c1wih + (long)(0 * 128 + gcol) * 128 + kx);
      Bz[t] = cvt8(a.c1wih + (long)(1 * 128 + gcol) * 128 + kx);
      Bn[t] = cvt8(a.c1wih + (long)(2 * 128 + gcol) * 128 + kx);
    }
  }
  const float b0v = a.c1bih[gcol] + a.c1bhh[gcol];
  const float b1v = a.c1bih[128 + gcol] + a.c1bhh[128 + gcol];
  const float b2v = a.c1bih[256 + gcol];
  const float b3v = a.c1bhh[256 + gcol];
  float hk[4] = {0.f, 0.f, 0.f, 0.f};
#pragma unroll
  for (int i = 0; i < 2; ++i) {
    const int idx = tid + 512 * i; const int r = idx >> 6, d = idx & 63;
    *(u32*)(T + r * 544 + ((d * 4) ^ ((r & 7) << 4))) = 0u;
  }
  SDF[tid] = a.dfw[tid];
  if (tid < 4) SDB[tid] = a.dfb[tid];
  const int rr = tid >> 5, cq = tid & 31, c4 = cq * 4;
  const float g1a = a.ln1g[c4], g1b = a.ln1g[c4 + 1], g1c = a.ln1g[c4 + 2], g1d = a.ln1g[c4 + 3];
  const float h1a = a.ln1b[c4], h1b = a.ln1b[c4 + 1], h1c = a.ln1b[c4 + 2], h1d = a.ln1b[c4 + 3];
  const u32* y0fp = a.flg + 12544 + g * 16;
  u32* ackp = a.flg + 12800 + g * 16;
  __syncthreads();
  for (int s = 0; s < 1024; ++s) {
    if (wv == 0) {
      const u32 tgt = (u32)(s + 1);
      for (;;) {
        const u32 f = (l == 0) ? ALOAD(y0fp) : tgt;
        if (__all(f >= tgt)) break;
        __builtin_amdgcn_s_sleep(4);
      }
    }
    __syncthreads();
    const u32 ya = ALOAD(a.y0r + ((s & 3) * 8 + g) * 1024 + rr * 64 + cq * 2);
    const u32 yb = ALOAD(a.y0r + ((s & 3) * 8 + g) * 1024 + rr * 64 + cq * 2 + 1);
    const long hbase = ((long)(s & 511) * 128 + g * 16 + rr) * 128 + c4;
    const float p0 = __uint_as_float(ALOAD(a.h0r + hbase));
    const float p1 = __uint_as_float(ALOAD(a.h0r + hbase + 1));
    const float p2 = __uint_as_float(ALOAD(a.h0r + hbase + 2));
    const float p3 = __uint_as_float(ALOAD(a.h0r + hbase + 3));
    const float u0 = p0 + bf2f(ya & 0xffffu);
    const float u1 = p1 + bf2f(ya >> 16);
    const float u2 = p2 + bf2f(yb & 0xffffu);
    const float u3 = p3 + bf2f(yb >> 16);
    float s1 = u0 + u1 + u2 + u3;
    float s2 = u0 * u0 + u1 * u1 + u2 * u2 + u3 * u3;
#pragma unroll
    for (int o = 1; o < 32; o <<= 1) { s1 += __shfl_xor(s1, o); s2 += __shfl_xor(s2, o); }
    const float m = s1 * 0.0078125f;
    const float rs = rsqrtf(s2 * 0.0078125f - m * m + 1e-5f);
    const u32 q0 = (u32)f2bf((u0 - m) * rs * g1a + h1a) |
                   ((u32)f2bf((u1 - m) * rs * g1b + h1b) << 16);
    const u32 q1 = (u32)f2bf((u2 - m) * rs * g1c + h1c) |
                   ((u32)f2bf((u3 - m) * rs * g1d + h1d) << 16);
    char* xa = T + rr * 544 + ((256 + cq * 8) ^ ((rr & 7) << 4));
    *(u32*)xa = q0;
    *(u32*)(xa + 4) = q1;
    __syncthreads();
    if (tid == 0) ASTORE(ackp, (u32)(s + 1));   // y0 + h0[s] consumed
    f4 ar = {0.f, 0.f, 0.f, 0.f}; f4 az = ar, anh = ar, anx = ar;
#pragma unroll
    for (int t = 0; t < 8; ++t) {
      const short8 aa = *(const short8*)(T + lr * 544 + ((t * 64 + lh * 16) ^ ((lr & 7) << 4)));
      ar = MFMA16(aa, Br[t], ar, 0, 0, 0);
      az = MFMA16(aa, Bz[t], az, 0, 0, 0);
      if (t < 4) anh = MFMA16(aa, Bn[t], anh, 0, 0, 0);
      else       anx = MFMA16(aa, Bn[t], anx, 0, 0, 0);
    }
    u32 hnew[4];
#pragma unroll
    for (int q = 0; q < 4; ++q) {
      const float rg = sigm(ar[q] + b0v);
      const float zg = sigm(az[q] + b1v);
      const float ng = tanh_(anx[q] + b2v + rg * (anh[q] + b3v));
      const float h = (1.f - zg) * ng + zg * hk[q];
      hk[q] = h; hnew[q] = f2bf(h);
    }
    __syncthreads();
#pragma unroll
    for (int q = 0; q < 4; ++q) {
      const u32 nb = (u32)__shfl_xor((int)hnew[q], 1);
      if ((l & 1) == 0) {
        const u32 pk = (hnew[q] & 0xffffu) | (nb << 16);
        const int b = lh * 4 + q, c = wv * 16 + lr;
        *(u32*)(T + b * 544 + ((c * 2) ^ ((b & 7) << 4))) = pk;
      }
    }
    __syncthreads();
    const int yo = (c4 * 2) ^ ((rr & 7) << 4);
    const u32 za = *(const u32*)(T + rr * 544 + yo);
    const u32 zb = *(const u32*)(T + rr * 544 + yo + 4);
    const float w0 = u0 + bf2f(za & 0xffffu);
    const float w1 = u1 + bf2f(za >> 16);
    const float w2 = u2 + bf2f(zb & 0xffffu);
    const float w3 = u3 + bf2f(zb >> 16);
    float pp0 = w0 * SDF[c4]       + w1 * SDF[c4 + 1]       + w2 * SDF[c4 + 2]       + w3 * SDF[c4 + 3];
    float pp1 = w0 * SDF[128 + c4] + w1 * SDF[128 + c4 + 1] + w2 * SDF[128 + c4 + 2] + w3 * SDF[128 + c4 + 3];
    float pp2 = w0 * SDF[256 + c4] + w1 * SDF[256 + c4 + 1] + w2 * SDF[256 + c4 + 2] + w3 * SDF[256 + c4 + 3];
    float pp3 = w0 * SDF[384 + c4] + w1 * SDF[384 + c4 + 1] + w2 * SDF[384 + c4 + 2] + w3 * SDF[384 + c4 + 3];
#pragma unroll
    for (int o = 1; o < 32; o <<= 1) {
      pp0 += __shfl_xor(pp0, o); pp1 += __shfl_xor(pp1, o);
      pp2 += __shfl_xor(pp2, o); pp3 += __shfl_xor(pp3, o);
    }
    if (cq == 0) {
      f4 ov = {pp0 + SDB[0], pp1 + SDB[1], pp2 + SDB[2], pp3 + SDB[3]};
      *(f4*)(a.out + ((long)s * 128 + g * 16 + rr) * 4) = ov;
    }
  }
}

// bids: 0-63 gru0 | 64-95 gru1 | 96-103 gru2 | 104-167 d0ln | 168-175 b0 | 176-183 b1
__global__ void __launch_bounds__(512, 2) mega(MegaArgs a) {
  __shared__ __align__(16) char sm[33280];
  const int bid = blockIdx.x;
  if (bid < 64) {
    const int group = bid & 7, slab = bid >> 3;
    gru0_scan(a.w0ih, a.w0hh, a.b0ih, a.b0hh, a.xb, a.hcat, group, slab,
              a.hbuf0 + group * 4096, a.hbuf0 + 32768 + group * 4096,
              a.flg + group * 128, sm);
  } else if (bid < 96) {
    const int id = bid - 64, G = id & 3, slab = id >> 2;
    gru_scan<256, 128, 32, 32, 8, 8, 0>(a.w1ih, a.w1hh, a.b1ih, a.b1hh, a.xd2,
        a.hcat, 896, 512 + slab * 32, G, slab,
        a.hbuf1 + G * 4096, a.hbuf1 + 16384 + G * 4096,
        a.flg + 1024 + G * 128, sm);
  } else if (bid < 104) {
    const int g = bid - 96;
    gru_scan<128, 64, 16, 128, 8, 0, 1>(a.w2ih, a.w2hh, a.b2ih, a.b2hh, a.xd4,
        a.hcat, 896, 768, g, 0, nullptr, nullptr,
        a.flg + 2048 + g * 16, sm);
  } else if (bid < 168) {
    const int id = bid - 104;
    d0ln_scan(a, id & 7, id >> 3, sm);
  } else if (bid < 176) {
    b0_scan(a, bid - 168, sm);
  } else {
    b1_scan(a, bid - 176, sm);
  }
}

// x -> bf16 full / ::2 / ::4 copies, plus upsample-folded d0 weight
__global__ void __launch_bounds__(256) prep(const float* __restrict__ x,
    u16* __restrict__ xb, u16* __restrict__ xd2, u16* __restrict__ xd4,
    const float* __restrict__ d0w, u16* __restrict__ d0wf) {
  const int b = blockIdx.x;
  if (b < 16384) {
    const long t = b * 256L + threadIdx.x;
    const f4 aa = ((const f4*)x)[t * 2];
    const f4 cc = ((const f4*)x)[t * 2 + 1];
    const u16 u0 = f2bf(aa[0]), u1 = f2bf(aa[1]), u2 = f2bf(aa[2]), u3 = f2bf(aa[3]);
    const u16 u4 = f2bf(cc[0]), u5 = f2bf(cc[1]), u6 = f2bf(cc[2]), u7 = f2bf(cc[3]);
    short8 s8; s8[0]=(short)u0; s8[1]=(short)u1; s8[2]=(short)u2; s8[3]=(short)u3;
    s8[4]=(short)u4; s8[5]=(short)u5; s8[6]=(short)u6; s8[7]=(short)u7;
    *(short8*)(xb + t * 8) = s8;
    const long row = t >> 5; const int ch = (int)(t & 31);
    *(u32*)(xd2 + row * 128 + ch * 4)     = (u32)u0 | ((u32)u2 << 16);
    *(u32*)(xd2 + row * 128 + ch * 4 + 2) = (u32)u4 | ((u32)u6 << 16);
    *(u32*)(xd4 + row * 64 + ch * 2)      = (u32)u0 | ((u32)u4 << 16);
  } else {
    const int idx = (b - 16384) * 256 + threadIdx.x;
    const int o = idx / 896, c = idx % 896;
    float v;
    if (c < 512) v = d0w[o * 1536 + c];
    else if (c < 768) { const int j = c - 512; v = d0w[o * 1536 + 512 + 2 * j] + d0w[o * 1536 + 513 + 2 * j]; }
    else { const int j = c - 768; const float* p = d0w + o * 1536 + 1024 + 4 * j; v = p[0] + p[1] + p[2] + p[3]; }
    d0wf[idx] = f2bf(v);
  }
}

extern "C" void kernel_launch(void* const* d_in, const int* in_sizes, int n_in,
                              void* d_out, int out_size, void* d_ws, size_t ws_size,
                              hipStream_t stream) {
  char* ws = (char*)d_ws;
  const float* x     = (const float*)d_in[0];
  const float* g0wih = (const float*)d_in[1];
  const float* g0whh = (const float*)d_in[2];
  const float* g0bih = (const float*)d_in[3];
  const float* g0bhh = (const float*)d_in[4];
  const float* g1wih = (const float*)d_in[5];
  const float* g1whh = (const float*)d_in[6];
  const float* g1bih = (const float*)d_in[7];
  const float* g1bhh = (const float*)d_in[8];
  const float* g2wih = (const float*)d_in[9];
  const float* g2whh = (const float*)d_in[10];
  const float* g2bih = (const float*)d_in[11];
  const float* g2bhh = (const float*)d_in[12];
  const float* d0w   = (const float*)d_in[13];
  const float* d0b   = (const float*)d_in[14];
  const float* ln0g  = (const float*)d_in[15];
  const float* ln0b  = (const float*)d_in[16];
  const float* b0wih = (const float*)d_in[17];
  const float* b0whh = (const float*)d_in[18];
  const float* b0bih = (const float*)d_in[19];
  const float* b0bhh = (const float*)d_in[20];
  const float* ln1g  = (const float*)d_in[21];
  const float* ln1b  = (const float*)d_in[22];
  const float* b1wih = (const float*)d_in[23];
  const float* b1whh = (const float*)d_in[24];
  const float* b1bih = (const float*)d_in[25];
  const float* b1bhh = (const float*)d_in[26];
  const float* dfw   = (const float*)d_in[27];
  const float* dfb   = (const float*)d_in[28];

  MegaArgs a;
  a.w0ih = g0wih; a.w0hh = g0whh; a.b0ih = g0bih; a.b0hh = g0bhh;
  a.w1ih = g1wih; a.w1hh = g1whh; a.b1ih = g1bih; a.b1hh = g1bhh;
  a.w2ih = g2wih; a.w2hh = g2whh; a.b2ih = g2bih; a.b2hh = g2bhh;
  a.xb  = (u16*)(ws + OFF_XB);
  a.xd2 = (u16*)(ws + OFF_XD2);
  a.xd4 = (u16*)(ws + OFF_XD4);
  a.hcat = (u16*)(ws + OFF_HCAT);
  a.lnb  = (u16*)(ws + OFF_LNB);
  a.h0r  = (u32*)(ws + OFF_H0R);
  a.y0r  = (u32*)(ws + OFF_Y0R);
  a.hbuf0 = (u32*)(ws + OFF_HB0);
  a.hbuf1 = (u32*)(ws + OFF_HB1);
  a.flg   = (u32*)(ws + OFF_FLG);
  a.d0wf  = (u16*)(ws + OFF_D0WF);
  a.d0b = d0b; a.ln0g = ln0g; a.ln0b = ln0b;
  a.c0wih = b0wih; a.c0whh = b0whh; a.c0bih = b0bih; a.c0bhh = b0bhh;
  a.ln1g = ln1g; a.ln1b = ln1b;
  a.c1wih = b1wih; a.c1whh = b1whh; a.c1bih = b1bih; a.c1bhh = b1bhh;
  a.dfw = dfw; a.dfb = dfb;
  a.out = (float*)d_out;

  // zero h publish parities + all flags/acks
  hipMemsetAsync(ws + OFF_HB0, 0, (size_t)(OFF_D0WF - OFF_HB0), stream);

  prep<<<16832, 256, 0, stream>>>(x, (u16*)(ws + OFF_XB), (u16*)(ws + OFF_XD2),
                                  (u16*)(ws + OFF_XD4), d0w, (u16*)(ws + OFF_D0WF));

  mega<<<184, 512, 0, stream>>>(a);
}

// Round 15
// 4540.138 us; speedup vs baseline: 6.2681x; 1.0002x over previous
//
#include <hip/hip_runtime.h>

typedef unsigned int u32;
typedef unsigned short u16;
typedef __attribute__((ext_vector_type(8))) short short8;
typedef __attribute__((ext_vector_type(4))) float f4;

#define MFMA16 __builtin_amdgcn_mfma_f32_16x16x32_bf16
#define ALOAD(p)    __hip_atomic_load((p), __ATOMIC_RELAXED, __HIP_MEMORY_SCOPE_AGENT)
#define ASTORE(p,v) __hip_atomic_store((p), (v), __ATOMIC_RELAXED, __HIP_MEMORY_SCOPE_AGENT)

// ---------- workspace layout (bytes) ----------
#define OFF_XB    0LL            // x bf16 (67,108,864)
#define OFF_XD2   67108864LL     // x[::2] bf16 (33,554,432)
#define OFF_XD4   100663296LL    // x[::4] bf16 (16,777,216)
#define OFF_HCAT  117440512LL    // concat bf16 (234,881,024) producers ASTORE, d0ln reads
#define OFF_LNB   352321536LL    // ln0 out bf16 (33,554,432) d0ln -> b0
#define OFF_H0R   385875968LL    // h0 fp32 ring, 512 steps (33,554,432) d0ln -> b1
#define OFF_Y0R   419430400LL    // y0 ring 4 par x 8 g x 16x128 bf16 (131,072) b0 -> b1
#define OFF_HB0   419561472LL    // gru0 h publish 2 par (262,144)
#define OFF_HB1   419823616LL    // gru1 h publish 2 par (131,072)
#define OFF_FLG   419954688LL    // flags (65,536)
#define OFF_D0WF  420020224LL    // folded d0 weight bf16 (229,376)
// flag u32 idx: gru0 g*128+slab*16 | gru1 1024+G*128+slab*16 | gru2 2048+g*16
//               d0f 4096+g*1024+s | y0f 12544+g*16 | b1ack 12800+g*16
// Visibility contract: producer flag s+1 => h-publish[s] visible.
//   hcat[s] visible only at flag >= s+2 (lazy hcat drain; in-order vmcnt).

__device__ __forceinline__ u16 f2bf(float f) {
  u32 u = __float_as_uint(f);
  return (u16)((u + 0x7fffu + ((u >> 16) & 1u)) >> 16);   // RNE
}
__device__ __forceinline__ float bf2f(u32 b) { return __uint_as_float(b << 16); }
__device__ __forceinline__ float sigm(float x) { return __builtin_amdgcn_rcpf(1.f + __expf(-x)); }
__device__ __forceinline__ float tanh_(float x) { return 1.f - 2.f * __builtin_amdgcn_rcpf(1.f + __expf(2.f * x)); }

__device__ __forceinline__ short8 cvt8(const float* p) {
  short8 r;
#pragma unroll
  for (int j = 0; j < 8; ++j) r[j] = (short)f2bf(p[j]);
  return r;
}

// =====================================================================
// Generic fused GRU scan (r13-proven; gru1 GH path + gru2 PUB path).
// =====================================================================
template<int KH, int KX, int BT, int CSPAN, int WAVES, int GROUP_WGS, int PUB>
__device__ __forceinline__ void gru_scan(
    const float* __restrict__ wih, const float* __restrict__ whh,
    const float* __restrict__ bih, const float* __restrict__ bhh,
    const u16* __restrict__ xsrc,
    u16* __restrict__ outp, const int outPitch, const int outColBase,
    const int group, const int slab,
    u32* __restrict__ hbA, u32* __restrict__ hbB, u32* __restrict__ flags,
    char* sm)
{
  constexpr int H = KH;
  constexpr int KT = (KH + KX) / 32;
  constexpr int KH32 = KH / 32;
  constexpr int PITCH = (KH + KX) * 2 + 32;
  constexpr int CT_N = CSPAN / 16;
  constexpr int NTILES = (BT / 16) * CT_N;
  constexpr int MAXP = (NTILES + WAVES - 1) / WAVES;
  constexpr int NT = WAVES * 64;
  constexpr int NX = (BT * KX / 2) / NT;
  constexpr int NH = (BT * KH / 2) / NT;
  constexpr bool GH = (GROUP_WGS > 0);

  const int tid = threadIdx.x;
  const int l = tid & 63;
  const int wv = __builtin_amdgcn_readfirstlane(tid >> 6);  // SCALAR wave id
  const int lr = l & 15;
  const int lh = l >> 4;
  const long srow0 = group * BT;

  short8 Br[MAXP][KT], Bz[MAXP][KT], Bn[MAXP][KT];
  float bb0[MAXP], bb1[MAXP], bb2[MAXP], bb3[MAXP];
  float hk[MAXP][4];
#pragma unroll
  for (int p = 0; p < MAXP; ++p) {
    const int tp = wv + WAVES * p;
    const int tpc = (tp < NTILES) ? tp : 0;
    const int ct = tpc % CT_N;
    const int gcol = slab * CSPAN + ct * 16 + lr;
#pragma unroll
    for (int t = 0; t < KT; ++t) {
      const int k = t * 32 + lh * 8;
      if (t < KH32) {
        Br[p][t] = cvt8(whh + (long)(0 * H + gcol) * KH + k);
        Bz[p][t] = cvt8(whh + (long)(1 * H + gcol) * KH + k);
        Bn[p][t] = cvt8(whh + (long)(2 * H + gcol) * KH + k);
      } else {
        const int kx = k - KH;
        Br[p][t] = cvt8(wih + (long)(0 * H + gcol) * KX + kx);
        Bz[p][t] = cvt8(wih + (long)(1 * H + gcol) * KX + kx);
        Bn[p][t] = cvt8(wih + (long)(2 * H + gcol) * KX + kx);
      }
    }
    bb0[p] = bih[0 * H + gcol] + bhh[0 * H + gcol];
    bb1[p] = bih[1 * H + gcol] + bhh[1 * H + gcol];
    bb2[p] = bih[2 * H + gcol];
    bb3[p] = bhh[2 * H + gcol];
    hk[p][0] = hk[p][1] = hk[p][2] = hk[p][3] = 0.f;
  }

  if constexpr (!GH) {
#pragma unroll
    for (int i = 0; i < (BT * KH / 2 + NT - 1) / NT; ++i) {
      const int idx = tid + NT * i;
      if (idx < BT * KH / 2) {
        const int r = idx / (KH / 2), d = idx % (KH / 2);
        *(u32*)(sm + r * PITCH + ((d * 4) ^ ((r & 7) << 4))) = 0u;
      }
    }
  }

  u32 xr[NX];
#pragma unroll
  for (int i = 0; i < NX; ++i) {
    const int idx = tid + NT * i;
    const int r = idx / (KX / 2), d = idx % (KX / 2);
    xr[i] = *(const u32*)(xsrc + (srow0 + r) * KX + d * 2);
  }

  for (int s = 0; s < 1024; ++s) {
    if constexpr (GH) {
      if (wv == 0) {
        const u32 tgt = (u32)s;
        for (;;) {
          const u32 f = (l < GROUP_WGS) ? ALOAD(flags + l * 16) : tgt;
          if (__all(f >= tgt)) break;
        }
      }
      __builtin_amdgcn_s_barrier();   // raw: nothing to drain here
    }
#pragma unroll
    for (int i = 0; i < NX; ++i) {
      const int idx = tid + NT * i;
      const int r = idx / (KX / 2), d = idx % (KX / 2);
      *(u32*)(sm + r * PITCH + ((KH * 2 + d * 4) ^ ((r & 7) << 4))) = xr[i];
    }
    if constexpr (GH) {
      const u32* hb = (s & 1) ? hbB : hbA;
#pragma unroll
      for (int i = 0; i < NH; ++i) {
        const int idx = tid + NT * i;
        const int r = idx / (KH / 2), d = idx % (KH / 2);
        const u32 v = ALOAD(hb + r * (KH / 2) + d);
        *(u32*)(sm + r * PITCH + ((d * 4) ^ ((r & 7) << 4))) = v;
      }
    }
    if constexpr (!(GH || PUB)) {
      if (s + 1 < 1024) {
#pragma unroll
        for (int i = 0; i < NX; ++i) {
          const int idx = tid + NT * i;
          const int r = idx / (KX / 2), d = idx % (KX / 2);
          xr[i] = *(const u32*)(xsrc + ((s + 1) * 128L + srow0 + r) * KX + d * 2);
        }
      }
    }
    __syncthreads();

    u32 hnew[MAXP][4];
#pragma unroll
    for (int p = 0; p < MAXP; ++p) {
      const int tp = wv + WAVES * p;
      if (tp < NTILES) {
        const int mt = tp / CT_N;
        f4 ar = {0.f, 0.f, 0.f, 0.f}; f4 az = ar, anh = ar, anx = ar;
#pragma unroll
        for (int t = 0; t < KT; ++t) {
          const int row = mt * 16 + lr;
          const short8 a = *(const short8*)(sm + row * PITCH +
                              ((t * 64 + lh * 16) ^ ((row & 7) << 4)));
          ar = MFMA16(a, Br[p][t], ar, 0, 0, 0);
          az = MFMA16(a, Bz[p][t], az, 0, 0, 0);
          if (t < KH32) anh = MFMA16(a, Bn[p][t], anh, 0, 0, 0);
          else          anx = MFMA16(a, Bn[p][t], anx, 0, 0, 0);
        }
#pragma unroll
        for (int q = 0; q < 4; ++q) {
          const float rg = sigm(ar[q] + bb0[p]);
          const float zg = sigm(az[q] + bb1[p]);
          const float ng = tanh_(anx[q] + bb2[p] + rg * (anh[q] + bb3[p]));
          const float h = (1.f - zg) * ng + zg * hk[p][q];
          hk[p][q] = h;
          hnew[p][q] = f2bf(h);
        }
      }
    }
    if constexpr (!GH) __syncthreads();

    u32 pkv[MAXP][4];
#pragma unroll
    for (int p = 0; p < MAXP; ++p) {
      const int tp = wv + WAVES * p;
      if (tp < NTILES) {
        const int mt = tp / CT_N, ct = tp % CT_N;
        const int c = ct * 16 + lr;
#pragma unroll
        for (int q = 0; q < 4; ++q) {
          const u32 nb = (u32)__shfl_xor((int)hnew[p][q], 1);
          pkv[p][q] = (hnew[p][q] & 0xffffu) | (nb << 16);
          if ((l & 1) == 0) {
            const int b = mt * 16 + lh * 4 + q;
            if constexpr (GH) {
              u32* hbn = ((s + 1) & 1) ? hbB : hbA;
              ASTORE(hbn + b * (KH / 2) + (slab * CSPAN + c) / 2, pkv[p][q]);
            } else {
              *(u32*)(sm + b * PITCH + ((c * 2) ^ ((b & 7) << 4))) = pkv[p][q];
            }
          }
        }
      }
    }
    __builtin_amdgcn_sched_barrier(0);
#pragma unroll
    for (int p = 0; p < MAXP; ++p) {
      const int tp = wv + WAVES * p;
      if (tp < NTILES) {
        const int mt = tp / CT_N, ct = tp % CT_N;
        const int c = ct * 16 + lr;
#pragma unroll
        for (int q = 0; q < 4; ++q) {
          if ((l & 1) == 0) {
            const int b = mt * 16 + lh * 4 + q;
            u32* oa = (u32*)(outp + (s * 128L + srow0 + b) * outPitch + outColBase + c);
            if constexpr (GH || PUB) ASTORE(oa, pkv[p][q]); else *oa = pkv[p][q];
          }
        }
      }
    }
    if constexpr (GH) {
      __builtin_amdgcn_sched_barrier(0);
      if (s + 1 < 1024) {
#pragma unroll
        for (int i = 0; i < NX; ++i) {
          const int idx = tid + NT * i;
          const int r = idx / (KX / 2), d = idx % (KX / 2);
          xr[i] = ALOAD((const u32*)(xsrc + ((s + 1) * 128L + srow0 + r) * KX + d * 2));
        }
        __builtin_amdgcn_sched_barrier(0);
        asm volatile("s_waitcnt vmcnt(%0)" :: "i"(MAXP * 4 + NX) : "memory");
      } else {
        asm volatile("s_waitcnt vmcnt(0)" ::: "memory");
      }
      __builtin_amdgcn_s_barrier();
      if (tid == 0) ASTORE(flags + slab * 16, (u32)(s + 1));
    } else if constexpr (PUB) {
      __builtin_amdgcn_sched_barrier(0);
      if (s + 1 < 1024) {
#pragma unroll
        for (int i = 0; i < NX; ++i) {
          const int idx = tid + NT * i;
          const int r = idx / (KX / 2), d = idx % (KX / 2);
          xr[i] = ALOAD((const u32*)(xsrc + ((s + 1) * 128L + srow0 + r) * KX + d * 2));
        }
        __builtin_amdgcn_sched_barrier(0);
        asm volatile("s_waitcnt vmcnt(%0)" :: "i"(NX) : "memory");
      } else {
        asm volatile("s_waitcnt vmcnt(0)" ::: "memory");
      }
      __builtin_amdgcn_s_barrier();
      if (tid == 0) ASTORE(flags, (u32)(s + 1));
    }
  }
}

// =====================================================================
// gru0 (H=512, Kin=256), r14 step structure:
//  B: x-part MFMAs (t=16..23; x staged last step) — runs DURING peers'
//     flag wait window.
//  C: issue x[s+1] prefetch; per-wave poll of own slab's flag (wave w
//     <-> slab w): early slabs' loads overlap late slabs' flags.
//  D: per-wave load of own slab's h[s] -> LDS; lgkm + raw barrier.
//  F: h-part MFMAs (t=0..15); gg1 red export; lgkm + raw barrier.
//  G: gg0 gates + publish + lazy hcat; ALL stage x[s+1];
//     vmcnt(4) lgkmcnt(0) (publish ack'd; hcat+0 in flight);
//     raw barrier; flag = s+1.
// 3 barriers/step (was 4); poll decentralized; x stage off the chain.
// Accumulation order within chains: x-part first (numeric reorder only).
// =====================================================================
__device__ __forceinline__ void gru0_scan(
    const float* __restrict__ wih, const float* __restrict__ whh,
    const float* __restrict__ bih, const float* __restrict__ bhh,
    const u16* __restrict__ x, u16* __restrict__ outp,
    const int group, const int slab,
    u32* __restrict__ hbA, u32* __restrict__ hbB, u32* __restrict__ flags,
    char* sm)
{
  constexpr int PITCH = 1568;
  const int tid = threadIdx.x;
  const int l = tid & 63;
  const int wv = __builtin_amdgcn_readfirstlane(tid >> 6);
  const int lr = l & 15, lh = l >> 4;
  const int ct = wv & 3, gg = wv >> 2;
  const long srow0 = group * 16;
  const int gcol = slab * 64 + ct * 16 + lr;
  f4* red = (f4*)(sm + 25088);

  short8 W0[24], W1[16];
#pragma unroll
  for (int t = 0; t < 24; ++t) {
    const int k = t * 32 + lh * 8;
    if (t < 16) W0[t] = cvt8(whh + (long)(gg * 512 + gcol) * 512 + k);
    else        W0[t] = cvt8(wih + (long)(gg * 512 + gcol) * 256 + (k - 512));
  }
  if (gg == 0) {
#pragma unroll
    for (int t = 0; t < 16; ++t)
      W1[t] = cvt8(whh + (long)(2 * 512 + gcol) * 512 + t * 32 + lh * 8);
  } else {
#pragma unroll
    for (int t = 0; t < 8; ++t)
      W1[t] = cvt8(wih + (long)(2 * 512 + gcol) * 256 + t * 32 + lh * 8);
  }
  const float bb0 = bih[0 * 512 + gcol] + bhh[0 * 512 + gcol];
  const float bb1 = bih[1 * 512 + gcol] + bhh[1 * 512 + gcol];
  const float bb2 = bih[2 * 512 + gcol];
  const float bb3 = bhh[2 * 512 + gcol];
  float hk[4] = {0.f, 0.f, 0.f, 0.f};

  u32 xr[4];
#pragma unroll
  for (int i = 0; i < 4; ++i) {
    const int idx = tid + 512 * i;
    const int r = idx >> 7, d = idx & 127;
    xr[i] = *(const u32*)(x + (srow0 + r) * 256 + d * 2);
  }
  // pre-stage x[0]
#pragma unroll
  for (int i = 0; i < 4; ++i) {
    const int idx = tid + 512 * i;
    const int r = idx >> 7, d = idx & 127;
    *(u32*)(sm + r * PITCH + ((1024 + d * 4) ^ ((r & 7) << 4))) = xr[i];
  }
  __syncthreads();

  for (int s = 0; s < 1024; ++s) {
    // ---- B: x-part MFMAs (t = 16..23) ----
    f4 a0 = {0.f, 0.f, 0.f, 0.f}, a1 = a0;
    if (gg == 0) {
#pragma unroll
      for (int t = 16; t < 24; ++t) {
        const short8 a = *(const short8*)(sm + lr * PITCH +
                            ((t * 64 + lh * 16) ^ ((lr & 7) << 4)));
        a0 = MFMA16(a, W0[t], a0, 0, 0, 0);
      }
    } else {
#pragma unroll
      for (int t = 16; t < 24; ++t) {
        const short8 a = *(const short8*)(sm + lr * PITCH +
                            ((t * 64 + lh * 16) ^ ((lr & 7) << 4)));
        a0 = MFMA16(a, W0[t], a0, 0, 0, 0);
        a1 = MFMA16(a, W1[t - 16], a1, 0, 0, 0);
      }
    }
    // ---- C: prefetch x[s+1]; per-wave poll own slab flag >= s ----
    if (s + 1 < 1024) {
#pragma unroll
      for (int i = 0; i < 4; ++i) {
        const int idx = tid + 512 * i;
        const int r = idx >> 7, d = idx & 127;
        xr[i] = ALOAD((const u32*)(x + ((s + 1) * 128L + srow0 + r) * 256 + d * 2));
      }
    }
    for (;;) {
      const u32 f = ALOAD(flags + wv * 16);
      if (__builtin_amdgcn_readfirstlane(f) >= (u32)s) break;
    }
    // ---- D: per-wave load own slab's h[s] -> LDS ----
    {
      const u32* hb = (s & 1) ? hbB : hbA;
#pragma unroll
      for (int i = 0; i < 8; ++i) {
        const int idx = l + 64 * i;
        const int r = idx >> 5, d = idx & 31;
        const u32 v = ALOAD(hb + r * 256 + wv * 32 + d);
        *(u32*)(sm + r * PITCH + ((wv * 128 + d * 4) ^ ((r & 7) << 4))) = v;
      }
    }
    asm volatile("s_waitcnt lgkmcnt(0)" ::: "memory");
    __builtin_amdgcn_sched_barrier(0);
    __builtin_amdgcn_s_barrier();                       // E
    __builtin_amdgcn_sched_barrier(0);
    // ---- F: h-part MFMAs (t = 0..15) ----
    if (gg == 0) {
#pragma unroll
      for (int t = 0; t < 16; ++t) {
        const short8 a = *(const short8*)(sm + lr * PITCH +
                            ((t * 64 + lh * 16) ^ ((lr & 7) << 4)));
        a0 = MFMA16(a, W0[t], a0, 0, 0, 0);
        a1 = MFMA16(a, W1[t], a1, 0, 0, 0);
      }
    } else {
#pragma unroll
      for (int t = 0; t < 16; ++t) {
        const short8 a = *(const short8*)(sm + lr * PITCH +
                            ((t * 64 + lh * 16) ^ ((lr & 7) << 4)));
        a0 = MFMA16(a, W0[t], a0, 0, 0, 0);
      }
      red[(ct * 2 + 0) * 64 + l] = a0;                  // az
      red[(ct * 2 + 1) * 64 + l] = a1;                  // anx
    }
    asm volatile("s_waitcnt lgkmcnt(0)" ::: "memory");
    __builtin_amdgcn_sched_barrier(0);
    __builtin_amdgcn_s_barrier();                       // R
    __builtin_amdgcn_sched_barrier(0);
    // ---- G: gates + publish + lazy hcat; stage x[s+1]; drain; flag ----
    u32 pkv[4];
    if (gg == 0) {
      const f4 paz  = red[(ct * 2 + 0) * 64 + l];
      const f4 panx = red[(ct * 2 + 1) * 64 + l];
      u32 hnew[4];
#pragma unroll
      for (int q = 0; q < 4; ++q) {
        const float rg = sigm(a0[q] + bb0);
        const float zg = sigm(paz[q] + bb1);
        const float ng = tanh_(panx[q] + bb2 + rg * (a1[q] + bb3));
        const float h = (1.f - zg) * ng + zg * hk[q];
        hk[q] = h;
        hnew[q] = f2bf(h);
      }
      u32* hbn = ((s + 1) & 1) ? hbB : hbA;
#pragma unroll
      for (int q = 0; q < 4; ++q) {                     // publish batch
        const u32 nb = (u32)__shfl_xor((int)hnew[q], 1);
        pkv[q] = (hnew[q] & 0xffffu) | (nb << 16);
        if ((l & 1) == 0) {
          const int b = lh * 4 + q;
          const int c = ct * 16 + lr;
          ASTORE(hbn + b * 256 + (slab * 64 + c) / 2, pkv[q]);
        }
      }
      __builtin_amdgcn_sched_barrier(0);
#pragma unroll
      for (int q = 0; q < 4; ++q) {                     // hcat batch (lazy)
        if ((l & 1) == 0) {
          const int b = lh * 4 + q;
          const int c = ct * 16 + lr;
          ASTORE((u32*)(outp + (s * 128L + srow0 + b) * 896 + slab * 64 + c), pkv[q]);
        }
      }
    }
    __builtin_amdgcn_sched_barrier(0);
    if (s + 1 < 1024) {
      // stage x[s+1] (x region dead since phase B); consumes prefetch
#pragma unroll
      for (int i = 0; i < 4; ++i) {
        const int idx = tid + 512 * i;
        const int r = idx >> 7, d = idx & 127;
        *(u32*)(sm + r * PITCH + ((1024 + d * 4) ^ ((r & 7) << 4))) = xr[i];
      }
      __builtin_amdgcn_sched_barrier(0);
      asm volatile("s_waitcnt vmcnt(4) lgkmcnt(0)" ::: "memory");
    } else {
      asm volatile("s_waitcnt vmcnt(0) lgkmcnt(0)" ::: "memory");
    }
    __builtin_amdgcn_s_barrier();                       // END
    __builtin_amdgcn_sched_barrier(0);
    if (tid == 0) ASTORE(flags + slab * 16, (u32)(s + 1));
  }
}

struct MegaArgs {
  const float *w0ih, *w0hh, *b0ih, *b0hh;
  const float *w1ih, *w1hh, *b1ih, *b1hh;
  const float *w2ih, *w2hh, *b2ih, *b2hh;
  const u16 *xb, *xd2, *xd4;
  u16 *hcat, *lnb;
  u32 *h0r, *y0r, *hbuf0, *hbuf1, *flg;
  const u16 *d0wf; const float *d0b;
  const float *ln0g, *ln0b;
  const float *c0wih, *c0whh, *c0bih, *c0bhh;
  const float *ln1g, *ln1b;
  const float *c1wih, *c1whh, *c1bih, *c1bhh;
  const float *dfw, *dfb;
  float* out;
};

// =====================================================================
// d0+LN0 trailing WG (g, p): steps s = p, p+8, ... (r13-proven; lag-2).
// =====================================================================
__device__ __forceinline__ void d0ln_scan(const MegaArgs& a, const int g,
                                          const int p, char* sm)
{
  const int tid = threadIdx.x;
  const int l = tid & 63;
  const int wv = __builtin_amdgcn_readfirstlane(tid >> 6);
  const int lr = l & 15, lh = l >> 4;
  const int dcol = wv * 16 + lr;
  u16* sA = (u16*)sm;                       // [16][40]
  float* part = (float*)(sm + 1536);        // [16][8][2]
  float* rowstat = (float*)(sm + 3584);     // [16][2]

  short8 Dw[28];
#pragma unroll
  for (int t = 0; t < 28; ++t)
    Dw[t] = *(const short8*)(a.d0wf + (long)dcol * 896 + t * 32 + lh * 8);
  const float dbias = a.d0b[dcol];
  const float lg = a.ln0g[dcol], lb = a.ln0b[dcol];

  const u32* hcat32 = (const u32*)a.hcat;
  u32* lnb32 = (u32*)a.lnb;
  const u32* pollp;
  if (l < 8)        pollp = a.flg + g * 128 + l * 16;
  else if (l < 16)  pollp = a.flg + 1024 + (g >> 1) * 128 + (l - 8) * 16;
  else if (l == 16) pollp = a.flg + 2048 + g * 16;
  else              pollp = a.flg + 12800 + g * 16;   // b1 ack (h0 ring WAR)
  const int stg = (tid < 256);
  const int sr = tid >> 4, sc = tid & 15;

  for (int s = p; s < 1024; s += 8) {
    if (wv == 0) {
      const u32 t01 = (u32)((s + 2 < 1024) ? s + 2 : 1024);  // hcat[s] visible
      const u32 t2  = (u32)(s + 1);
      for (;;) {
        int ok = 1;
        if (l < 16)       ok = (ALOAD(pollp) >= t01);
        else if (l == 16) ok = (ALOAD(pollp) >= t2);
        else if (l == 17) ok = (ALOAD(pollp) + 512 >= t2);   // ack >= s-511
        if (__all(ok)) break;
        __builtin_amdgcn_s_sleep(32);
      }
    }
    __syncthreads();
    const long rowbase = (long)s * 128 + g * 16;
    f4 acc = {0.f, 0.f, 0.f, 0.f};
    u32 vst = 0;
    if (stg) vst = ALOAD(hcat32 + (rowbase + sr) * 448 + sc);
    for (int kt = 0; kt < 28; ++kt) {
      u32 vnext = 0;
      if (kt + 1 < 28 && stg)
        vnext = ALOAD(hcat32 + (rowbase + sr) * 448 + (kt + 1) * 16 + sc);
      __syncthreads();
      if (stg) *(u32*)((char*)sA + sr * 80 + sc * 4) = vst;
      __syncthreads();
      const short8 af = *(const short8*)((char*)sA + lr * 80 + lh * 16);
      acc = MFMA16(af, Dw[kt], acc, 0, 0, 0);
      vst = vnext;
    }
    float v[4];
#pragma unroll
    for (int q = 0; q < 4; ++q) { const float xv = acc[q] + dbias; v[q] = xv > 0.f ? xv : 0.f; }
#pragma unroll
    for (int q = 0; q < 4; ++q) {
      float s1 = v[q], s2 = v[q] * v[q];
#pragma unroll
      for (int o = 1; o < 16; o <<= 1) { s1 += __shfl_xor(s1, o); s2 += __shfl_xor(s2, o); }
      if (lr == 0) {
        const int row = lh * 4 + q;
        part[(row * 8 + wv) * 2] = s1;
        part[(row * 8 + wv) * 2 + 1] = s2;
      }
    }
    __syncthreads();
    if (tid < 16) {
      float S1 = 0.f, S2 = 0.f;
#pragma unroll
      for (int w = 0; w < 8; ++w) { S1 += part[(tid * 8 + w) * 2]; S2 += part[(tid * 8 + w) * 2 + 1]; }
      const float m = S1 * 0.0078125f;
      const float rs = rsqrtf(S2 * 0.0078125f - m * m + 1e-5f);
      rowstat[tid * 2] = m; rowstat[tid * 2 + 1] = rs;
    }
    __syncthreads();
#pragma unroll
    for (int q = 0; q < 4; ++q) {
      const int row = lh * 4 + q;
      const float m = rowstat[row * 2], rs = rowstat[row * 2 + 1];
      const u16 lnq = f2bf((v[q] - m) * rs * lg + lb);
      const u32 nb = (u32)__shfl_xor((int)(u32)lnq, 1);
      if ((l & 1) == 0)
        ASTORE(lnb32 + (rowbase + row) * 64 + (dcol >> 1), ((u32)lnq & 0xffffu) | (nb << 16));
      ASTORE(a.h0r + ((long)(s & 511) * 128 + g * 16 + row) * 128 + dcol,
             __float_as_uint(v[q]));
    }
    asm volatile("s_waitcnt vmcnt(0)" ::: "memory");
    __syncthreads();
    if (tid == 0) ASTORE(a.flg + 4096 + g * 1024 + s, 1u);
  }
}

// ---- b0: trailing serial block-GRU (consumes lnbuf, publishes y0 ring) ----
__device__ __forceinline__ void b0_scan(const MegaArgs& a, const int g, char* sm)
{
  const int tid = threadIdx.x, l = tid & 63;
  const int wv = __builtin_amdgcn_readfirstlane(tid >> 6);
  const int lr = l & 15, lh = l >> 4;
  const int gcol = wv * 16 + lr;
  char* T = sm;
  short8 Br[8], Bz[8], Bn[8];
#pragma unroll
  for (int t = 0; t < 8; ++t) {
    const int k = t * 32 + lh * 8;
    if (t < 4) {
      Br[t] = cvt8(a.c0whh + (long)(0 * 128 + gcol) * 128 + k);
      Bz[t] = cvt8(a.c0whh + (long)(1 * 128 + gcol) * 128 + k);
      Bn[t] = cvt8(a.c0whh + (long)(2 * 128 + gcol) * 128 + k);
    } else {
      const int kx = k - 128;
      Br[t] = cvt8(a.c0wih + (long)(0 * 128 + gcol) * 128 + kx);
      Bz[t] = cvt8(a.c0wih + (long)(1 * 128 + gcol) * 128 + kx);
      Bn[t] = cvt8(a.c0wih + (long)(2 * 128 + gcol) * 128 + kx);
    }
  }
  const float b0v = a.c0bih[gcol] + a.c0bhh[gcol];
  const float b1v = a.c0bih[128 + gcol] + a.c0bhh[128 + gcol];
  const float b2v = a.c0bih[256 + gcol];
  const float b3v = a.c0bhh[256 + gcol];
  float hk[4] = {0.f, 0.f, 0.f, 0.f};
#pragma unroll
  for (int i = 0; i < 2; ++i) {
    const int idx = tid + 512 * i; const int r = idx >> 6, d = idx & 63;
    *(u32*)(T + r * 544 + ((d * 4) ^ ((r & 7) << 4))) = 0u;
  }
  const u32* lnb32 = (const u32*)a.lnb;
  const u32* d0fp = a.flg + 4096 + g * 1024;
  const u32* ackp = a.flg + 12800 + g * 16;
  u32* myf = a.flg + 12544 + g * 16;
  __syncthreads();
  for (int s = 0; s < 1024; ++s) {
    if (wv == 0) {
      for (;;) {
        u32 f = 1u;
        if (l == 0)      f = ALOAD(d0fp + s);
        else if (l == 1) f = (ALOAD(ackp) + 3 >= (u32)s) ? 1u : 0u;  // y0 ring WAR
        if (__all(f >= 1u)) break;
        __builtin_amdgcn_s_sleep(4);
      }
    }
    __syncthreads();
#pragma unroll
    for (int i = 0; i < 2; ++i) {
      const int idx = tid + 512 * i; const int r = idx >> 6, d = idx & 63;
      const u32 xv = ALOAD(lnb32 + ((long)s * 128 + g * 16 + r) * 64 + d);
      *(u32*)(T + r * 544 + ((256 + d * 4) ^ ((r & 7) << 4))) = xv;
    }
    __syncthreads();
    f4 ar = {0.f, 0.f, 0.f, 0.f}; f4 az = ar, anh = ar, anx = ar;
#pragma unroll
    for (int t = 0; t < 8; ++t) {
      const short8 aa = *(const short8*)(T + lr * 544 + ((t * 64 + lh * 16) ^ ((lr & 7) << 4)));
      ar = MFMA16(aa, Br[t], ar, 0, 0, 0);
      az = MFMA16(aa, Bz[t], az, 0, 0, 0);
      if (t < 4) anh = MFMA16(aa, Bn[t], anh, 0, 0, 0);
      else       anx = MFMA16(aa, Bn[t], anx, 0, 0, 0);
    }
    u32 hnew[4];
#pragma unroll
    for (int q = 0; q < 4; ++q) {
      const float rg = sigm(ar[q] + b0v);
      const float zg = sigm(az[q] + b1v);
      const float ng = tanh_(anx[q] + b2v + rg * (anh[q] + b3v));
      const float h = (1.f - zg) * ng + zg * hk[q];
      hk[q] = h; hnew[q] = f2bf(h);
    }
    __syncthreads();
#pragma unroll
    for (int q = 0; q < 4; ++q) {
      const u32 nb = (u32)__shfl_xor((int)hnew[q], 1);
      if ((l & 1) == 0) {
        const u32 pk = (hnew[q] & 0xffffu) | (nb << 16);
        const int b = lh * 4 + q, c = wv * 16 + lr;
        *(u32*)(T + b * 544 + ((c * 2) ^ ((b & 7) << 4))) = pk;
        ASTORE(a.y0r + ((s & 3) * 8 + g) * 1024 + b * 64 + (c >> 1), pk);
      }
    }
    asm volatile("s_waitcnt vmcnt(0)" ::: "memory");
    __syncthreads();
    if (tid == 0) ASTORE(myf, (u32)(s + 1));
  }
}

// ---- b1: LN1(h0+y0) -> GRU -> final dense -> out; acks y0/h0 rings ----
__device__ __forceinline__ void b1_scan(const MegaArgs& a, const int g, char* sm)
{
  const int tid = threadIdx.x, l = tid & 63;
  const int wv = __builtin_amdgcn_readfirstlane(tid >> 6);
  const int lr = l & 15, lh = l >> 4;
  const int gcol = wv * 16 + lr;
  char* T = sm;
  float* SDF = (float*)(sm + 8704);
  float* SDB = (float*)(sm + 10752);
  short8 Br[8], Bz[8], Bn[8];
#pragma unroll
  for (int t = 0; t < 8; ++t) {
    const int k = t * 32 + lh * 8;
    if (t < 4) {
      Br[t] = cvt8(a.c1whh + (long)(0 * 128 + gcol) * 128 + k);
      Bz[t] = cvt8(a.c1whh + (long)(1 * 128 + gcol) * 128 + k);
      Bn[t] = cvt8(a.c1whh + (long)(2 * 128 + gcol) * 128 + k);
    } else {
      const int kx = k - 128;
      Br[t] = cvt8(a.c1wih + (long)(0 * 128 + gcol) * 128 + kx);
      Bz[t] = cvt8(a.c1wih + (long)(1 * 128 + gcol) * 128 + kx);
      Bn[t] = cvt8(a.c1wih + (long)(2 * 128 + gcol) * 128 + kx);
    }
  }
  const float b0v = a.c1bih[gcol] + a.c1bhh[gcol];
  const float b1v = a.c1bih[128 + gcol] + a.c1bhh[128 + gcol];
  const float b2v = a.c1bih[256 + gcol];
  const float b3v = a.c1bhh[256 + gcol];
  float hk[4] = {0.f, 0.f, 0.f, 0.f};
#pragma unroll
  for (int i = 0; i < 2; ++i) {
    const int idx = tid + 512 * i; const int r = idx >> 6, d = idx & 63;
    *(u32*)(T + r * 544 + ((d * 4) ^ ((r & 7) << 4))) = 0u;
  }
  SDF[tid] = a.dfw[tid];
  if (tid < 4) SDB[tid] = a.dfb[tid];
  const int rr = tid >> 5, cq = tid & 31, c4 = cq * 4;
  const float g1a = a.ln1g[c4], g1b = a.ln1g[c4 + 1], g1c = a.ln1g[c4 + 2], g1d = a.ln1g[c4 + 3];
  const float h1a = a.ln1b[c4], h1b = a.ln1b[c4 + 1], h1c = a.ln1b[c4 + 2], h1d = a.ln1b[c4 + 3];
  const u32* y0fp = a.flg + 12544 + g * 16;
  u32* ackp = a.flg + 12800 + g * 16;
  __syncthreads();
  for (int s = 0; s < 1024; ++s) {
    if (wv == 0) {
      const u32 tgt = (u32)(s + 1);
      for (;;) {
        const u32 f = (l == 0) ? ALOAD(y0fp) : tgt;
        if (__all(f >= tgt)) break;
        __builtin_amdgcn_s_sleep(4);
      }
    }
    __syncthreads();
    const u32 ya = ALOAD(a.y0r + ((s & 3) * 8 + g) * 1024 + rr * 64 + cq * 2);
    const u32 yb = ALOAD(a.y0r + ((s & 3) * 8 + g) * 1024 + rr * 64 + cq * 2 + 1);
    const long hbase = ((long)(s & 511) * 128 + g * 16 + rr) * 128 + c4;
    const float p0 = __uint_as_float(ALOAD(a.h0r + hbase));
    const float p1 = __uint_as_float(ALOAD(a.h0r + hbase + 1));
    const float p2 = __uint_as_float(ALOAD(a.h0r + hbase + 2));
    const float p3 = __uint_as_float(ALOAD(a.h0r + hbase + 3));
    const float u0 = p0 + bf2f(ya & 0xffffu);
    const float u1 = p1 + bf2f(ya >> 16);
    const float u2 = p2 + bf2f(yb & 0xffffu);
    const float u3 = p3 + bf2f(yb >> 16);
    float s1 = u0 + u1 + u2 + u3;
    float s2 = u0 * u0 + u1 * u1 + u2 * u2 + u3 * u3;
#pragma unroll
    for (int o = 1; o < 32; o <<= 1) { s1 += __shfl_xor(s1, o); s2 += __shfl_xor(s2, o); }
    const float m = s1 * 0.0078125f;
    const float rs = rsqrtf(s2 * 0.0078125f - m * m + 1e-5f);
    const u32 q0 = (u32)f2bf((u0 - m) * rs * g1a + h1a) |
                   ((u32)f2bf((u1 - m) * rs * g1b + h1b) << 16);
    const u32 q1 = (u32)f2bf((u2 - m) * rs * g1c + h1c) |
                   ((u32)f2bf((u3 - m) * rs * g1d + h1d) << 16);
    char* xa = T + rr * 544 + ((256 + cq * 8) ^ ((rr & 7) << 4));
    *(u32*)xa = q0;
    *(u32*)(xa + 4) = q1;
    __syncthreads();
    if (tid == 0) ASTORE(ackp, (u32)(s + 1));   // y0 + h0[s] consumed
    f4 ar = {0.f, 0.f, 0.f, 0.f}; f4 az = ar, anh = ar, anx = ar;
#pragma unroll
    for (int t = 0; t < 8; ++t) {
      const short8 aa = *(const short8*)(T + lr * 544 + ((t * 64 + lh * 16) ^ ((lr & 7) << 4)));
      ar = MFMA16(aa, Br[t], ar, 0, 0, 0);
      az = MFMA16(aa, Bz[t], az, 0, 0, 0);
      if (t < 4) anh = MFMA16(aa, Bn[t], anh, 0, 0, 0);
      else       anx = MFMA16(aa, Bn[t], anx, 0, 0, 0);
    }
    u32 hnew[4];
#pragma unroll
    for (int q = 0; q < 4; ++q) {
      const float rg = sigm(ar[q] + b0v);
      const float zg = sigm(az[q] + b1v);
      const float ng = tanh_(anx[q] + b2v + rg * (anh[q] + b3v));
      const float h = (1.f - zg) * ng + zg * hk[q];
      hk[q] = h; hnew[q] = f2bf(h);
    }
    __syncthreads();
#pragma unroll
    for (int q = 0; q < 4; ++q) {
      const u32 nb = (u32)__shfl_xor((int)hnew[q], 1);
      if ((l & 1) == 0) {
        const u32 pk = (hnew[q] & 0xffffu) | (nb << 16);
        const int b = lh * 4 + q, c = wv * 16 + lr;
        *(u32*)(T + b * 544 + ((c * 2) ^ ((b & 7) << 4))) = pk;
      }
    }
    __syncthreads();
    const int yo = (c4 * 2) ^ ((rr & 7) << 4);
    const u32 za = *(const u32*)(T + rr * 544 + yo);
    const u32 zb = *(const u32*)(T + rr * 544 + yo + 4);
    const float w0 = u0 + bf2f(za & 0xffffu);
    const float w1 = u1 + bf2f(za >> 16);
    const float w2 = u2 + bf2f(zb & 0xffffu);
    const float w3 = u3 + bf2f(zb >> 16);
    float pp0 = w0 * SDF[c4]       + w1 * SDF[c4 + 1]       + w2 * SDF[c4 + 2]       + w3 * SDF[c4 + 3];
    float pp1 = w0 * SDF[128 + c4] + w1 * SDF[128 + c4 + 1] + w2 * SDF[128 + c4 + 2] + w3 * SDF[128 + c4 + 3];
    float pp2 = w0 * SDF[256 + c4] + w1 * SDF[256 + c4 + 1] + w2 * SDF[256 + c4 + 2] + w3 * SDF[256 + c4 + 3];
    float pp3 = w0 * SDF[384 + c4] + w1 * SDF[384 + c4 + 1] + w2 * SDF[384 + c4 + 2] + w3 * SDF[384 + c4 + 3];
#pragma unroll
    for (int o = 1; o < 32; o <<= 1) {
      pp0 += __shfl_xor(pp0, o); pp1 += __shfl_xor(pp1, o);
      pp2 += __shfl_xor(pp2, o); pp3 += __shfl_xor(pp3, o);
    }
    if (cq == 0) {
      f4 ov = {pp0 + SDB[0], pp1 + SDB[1], pp2 + SDB[2], pp3 + SDB[3]};
      *(f4*)(a.out + ((long)s * 128 + g * 16 + rr) * 4) = ov;
    }
  }
}

// bids: 0-63 gru0 | 64-95 gru1 | 96-103 gru2 | 104-167 d0ln | 168-175 b0 | 176-183 b1
__global__ void __launch_bounds__(512, 2) mega(MegaArgs a) {
  __shared__ __align__(16) char sm[33280];
  const int bid = blockIdx.x;
  if (bid < 64) {
    const int group = bid & 7, slab = bid >> 3;
    gru0_scan(a.w0ih, a.w0hh, a.b0ih, a.b0hh, a.xb, a.hcat, group, slab,
              a.hbuf0 + group * 4096, a.hbuf0 + 32768 + group * 4096,
              a.flg + group * 128, sm);
  } else if (bid < 96) {
    const int id = bid - 64, G = id & 3, slab = id >> 2;
    gru_scan<256, 128, 32, 32, 8, 8, 0>(a.w1ih, a.w1hh, a.b1ih, a.b1hh, a.xd2,
        a.hcat, 896, 512 + slab * 32, G, slab,
        a.hbuf1 + G * 4096, a.hbuf1 + 16384 + G * 4096,
        a.flg + 1024 + G * 128, sm);
  } else if (bid < 104) {
    const int g = bid - 96;
    gru_scan<128, 64, 16, 128, 8, 0, 1>(a.w2ih, a.w2hh, a.b2ih, a.b2hh, a.xd4,
        a.hcat, 896, 768, g, 0, nullptr, nullptr,
        a.flg + 2048 + g * 16, sm);
  } else if (bid < 168) {
    const int id = bid - 104;
    d0ln_scan(a, id & 7, id >> 3, sm);
  } else if (bid < 176) {
    b0_scan(a, bid - 168, sm);
  } else {
    b1_scan(a, bid - 176, sm);
  }
}

// x -> bf16 full / ::2 / ::4 copies, plus upsample-folded d0 weight
__global__ void __launch_bounds__(256) prep(const float* __restrict__ x,
    u16* __restrict__ xb, u16* __restrict__ xd2, u16* __restrict__ xd4,
    const float* __restrict__ d0w, u16* __restrict__ d0wf) {
  const int b = blockIdx.x;
  if (b < 16384) {
    const long t = b * 256L + threadIdx.x;
    const f4 aa = ((const f4*)x)[t * 2];
    const f4 cc = ((const f4*)x)[t * 2 + 1];
    const u16 u0 = f2bf(aa[0]), u1 = f2bf(aa[1]), u2 = f2bf(aa[2]), u3 = f2bf(aa[3]);
    const u16 u4 = f2bf(cc[0]), u5 = f2bf(cc[1]), u6 = f2bf(cc[2]), u7 = f2bf(cc[3]);
    short8 s8; s8[0]=(short)u0; s8[1]=(short)u1; s8[2]=(short)u2; s8[3]=(short)u3;
    s8[4]=(short)u4; s8[5]=(short)u5; s8[6]=(short)u6; s8[7]=(short)u7;
    *(short8*)(xb + t * 8) = s8;
    const long row = t >> 5; const int ch = (int)(t & 31);
    *(u32*)(xd2 + row * 128 + ch * 4)     = (u32)u0 | ((u32)u2 << 16);
    *(u32*)(xd2 + row * 128 + ch * 4 + 2) = (u32)u4 | ((u32)u6 << 16);
    *(u32*)(xd4 + row * 64 + ch * 2)      = (u32)u0 | ((u32)u4 << 16);
  } else {
    const int idx = (b - 16384) * 256 + threadIdx.x;
    const int o = idx / 896, c = idx % 896;
    float v;
    if (c < 512) v = d0w[o * 1536 + c];
    else if (c < 768) { const int j = c - 512; v = d0w[o * 1536 + 512 + 2 * j] + d0w[o * 1536 + 513 + 2 * j]; }
    else { const int j = c - 768; const float* p = d0w + o * 1536 + 1024 + 4 * j; v = p[0] + p[1] + p[2] + p[3]; }
    d0wf[idx] = f2bf(v);
  }
}

extern "C" void kernel_launch(void* const* d_in, const int* in_sizes, int n_in,
                              void* d_out, int out_size, void* d_ws, size_t ws_size,
                              hipStream_t stream) {
  char* ws = (char*)d_ws;
  const float* x     = (const float*)d_in[0];
  const float* g0wih = (const float*)d_in[1];
  const float* g0whh = (const float*)d_in[2];
  const float* g0bih = (const float*)d_in[3];
  const float* g0bhh = (const float*)d_in[4];
  const float* g1wih = (const float*)d_in[5];
  const float* g1whh = (const float*)d_in[6];
  const float* g1bih = (const float*)d_in[7];
  const float* g1bhh = (const float*)d_in[8];
  const float* g2wih = (const float*)d_in[9];
  const float* g2whh = (const float*)d_in[10];
  const float* g2bih = (const float*)d_in[11];
  const float* g2bhh = (const float*)d_in[12];
  const float* d0w   = (const float*)d_in[13];
  const float* d0b   = (const float*)d_in[14];
  const float* ln0g  = (const float*)d_in[15];
  const float* ln0b  = (const float*)d_in[16];
  const float* b0wih = (const float*)d_in[17];
  const float* b0whh = (const float*)d_in[18];
  const float* b0bih = (const float*)d_in[19];
  const float* b0bhh = (const float*)d_in[20];
  const float* ln1g  = (const float*)d_in[21];
  const float* ln1b  = (const float*)d_in[22];
  const float* b1wih = (const float*)d_in[23];
  const float* b1whh = (const float*)d_in[24];
  const float* b1bih = (const float*)d_in[25];
  const float* b1bhh = (const float*)d_in[26];
  const float* dfw   = (const float*)d_in[27];
  const float* dfb   = (const float*)d_in[28];

  MegaArgs a;
  a.w0ih = g0wih; a.w0hh = g0whh; a.b0ih = g0bih; a.b0hh = g0bhh;
  a.w1ih = g1wih; a.w1hh = g1whh; a.b1ih = g1bih; a.b1hh = g1bhh;
  a.w2ih = g2wih; a.w2hh = g2whh; a.b2ih = g2bih; a.b2hh = g2bhh;
  a.xb  = (u16*)(ws + OFF_XB);
  a.xd2 = (u16*)(ws + OFF_XD2);
  a.xd4 = (u16*)(ws + OFF_XD4);
  a.hcat = (u16*)(ws + OFF_HCAT);
  a.lnb  = (u16*)(ws + OFF_LNB);
  a.h0r  = (u32*)(ws + OFF_H0R);
  a.y0r  = (u32*)(ws + OFF_Y0R);
  a.hbuf0 = (u32*)(ws + OFF_HB0);
  a.hbuf1 = (u32*)(ws + OFF_HB1);
  a.flg   = (u32*)(ws + OFF_FLG);
  a.d0wf  = (u16*)(ws + OFF_D0WF);
  a.d0b = d0b; a.ln0g = ln0g; a.ln0b = ln0b;
  a.c0wih = b0wih; a.c0whh = b0whh; a.c0bih = b0bih; a.c0bhh = b0bhh;
  a.ln1g = ln1g; a.ln1b = ln1b;
  a.c1wih = b1wih; a.c1whh = b1whh; a.c1bih = b1bih; a.c1bhh = b1bhh;
  a.dfw = dfw; a.dfb = dfb;
  a.out = (float*)d_out;

  // zero h publish parities + all flags/acks
  hipMemsetAsync(ws + OFF_HB0, 0, (size_t)(OFF_D0WF - OFF_HB0), stream);

  prep<<<16832, 256, 0, stream>>>(x, (u16*)(ws + OFF_XB), (u16*)(ws + OFF_XD2),
                                  (u16*)(ws + OFF_XD4), d0w, (u16*)(ws + OFF_D0WF));

  mega<<<184, 512, 0, stream>>>(a);
}